// Round 2
// baseline (2739.249 us; speedup 1.0000x reference)
//
#include <hip/hip_runtime.h>
#include <hip/hip_bf16.h>

#define NN  100000
#define D   64
#define KS  20
#define DFF 256
#define EPS 1e-5f

__device__ __forceinline__ float wsum64(float v) {
    v += __shfl_xor(v, 1, 64);
    v += __shfl_xor(v, 2, 64);
    v += __shfl_xor(v, 4, 64);
    v += __shfl_xor(v, 8, 64);
    v += __shfl_xor(v, 16, 64);
    v += __shfl_xor(v, 32, 64);
    return v;
}

// ---------------- K/V projection: Kp = x@Wk+bk, Vp = x@Wv+bv ----------------
__global__ __launch_bounds__(256) void k_proj_kv(
    const float* __restrict__ x,
    const float* __restrict__ Wk, const float* __restrict__ bk,
    const float* __restrict__ Wv, const float* __restrict__ bv,
    float* __restrict__ Kp, float* __restrict__ Vp)
{
    __shared__ float sWk[D * D], sWv[D * D];
    __shared__ float sbk[D], sbv[D];
    for (int i = threadIdx.x; i < D * D; i += 256) { sWk[i] = Wk[i]; sWv[i] = Wv[i]; }
    if (threadIdx.x < D) { sbk[threadIdx.x] = bk[threadIdx.x]; sbv[threadIdx.x] = bv[threadIdx.x]; }
    __syncthreads();
    const int lane = threadIdx.x & 63;
    int w = (blockIdx.x * 256 + threadIdx.x) >> 6;
    const int nw = (gridDim.x * 256) >> 6;
    for (int row = w; row < NN; row += nw) {
        float xv = x[row * D + lane];
        float aK = sbk[lane], aV = sbv[lane];
        #pragma unroll
        for (int d = 0; d < D; ++d) {
            float xd = __shfl(xv, d, 64);
            aK = fmaf(xd, sWk[d * D + lane], aK);
            aV = fmaf(xd, sWv[d * D + lane], aV);
        }
        Kp[row * D + lane] = aK;
        Vp[row * D + lane] = aV;
    }
}

// ---------------- attention + Wo + residual + LN1 ----------------
__global__ __launch_bounds__(256) void k_attn(
    const float* __restrict__ x,
    const float* __restrict__ Kp, const float* __restrict__ Vp,
    const int* __restrict__ samp,
    const float* __restrict__ Wq, const float* __restrict__ bq,
    const float* __restrict__ Wo, const float* __restrict__ bo,
    const float* __restrict__ g1, const float* __restrict__ be1,
    float* __restrict__ hb)
{
    __shared__ float sWq[D * D], sWo[D * D];
    __shared__ float sbq[D], sbo[D], sg1[D], sbe1[D];
    for (int i = threadIdx.x; i < D * D; i += 256) { sWq[i] = Wq[i]; sWo[i] = Wo[i]; }
    if (threadIdx.x < D) {
        sbq[threadIdx.x] = bq[threadIdx.x]; sbo[threadIdx.x] = bo[threadIdx.x];
        sg1[threadIdx.x] = g1[threadIdx.x]; sbe1[threadIdx.x] = be1[threadIdx.x];
    }
    __syncthreads();
    const int lane = threadIdx.x & 63;
    int w = (blockIdx.x * 256 + threadIdx.x) >> 6;
    const int nw = (gridDim.x * 256) >> 6;
    for (int row = w; row < NN; row += nw) {
        float xj = x[row * D + lane];
        int idx_reg = 0;
        if (lane < KS) idx_reg = samp[row * KS + lane];

        // q = x@Wq + bq  (lane j holds q_j; head = j>>4)
        float q = sbq[lane];
        #pragma unroll
        for (int d = 0; d < D; ++d)
            q = fmaf(__shfl(xj, d, 64), sWq[d * D + lane], q);

        // scores: per-head 16-lane dot, scaled by 1/sqrt(16)
        int iks[KS];
        float s[KS];
        #pragma unroll
        for (int k = 0; k < KS; ++k) {
            iks[k] = __shfl(idx_reg, k, 64);
            float p = q * Kp[iks[k] * D + lane];
            p += __shfl_xor(p, 1, 64);
            p += __shfl_xor(p, 2, 64);
            p += __shfl_xor(p, 4, 64);
            p += __shfl_xor(p, 8, 64);
            s[k] = p * 0.25f;
        }
        // softmax over K=20 (redundant across the 16 lanes of each head)
        float m = s[0];
        #pragma unroll
        for (int k = 1; k < KS; ++k) m = fmaxf(m, s[k]);
        float ssum = 0.f;
        #pragma unroll
        for (int k = 0; k < KS; ++k) { s[k] = __expf(s[k] - m); ssum += s[k]; }
        float inv = 1.0f / ssum;

        // out_j = sum_k p_k * Vp[idx_k][j]
        float o = 0.f;
        #pragma unroll
        for (int k = 0; k < KS; ++k)
            o = fmaf(s[k] * inv, Vp[iks[k] * D + lane], o);

        // @Wo + bo, residual, LN1
        float acc = sbo[lane];
        #pragma unroll
        for (int d = 0; d < D; ++d)
            acc = fmaf(__shfl(o, d, 64), sWo[d * D + lane], acc);
        float r = xj + acc;
        float mu = wsum64(r) * (1.f / 64.f);
        float dv = r - mu;
        float var = wsum64(dv * dv) * (1.f / 64.f);
        hb[row * D + lane] = dv * rsqrtf(var + EPS) * sg1[lane] + sbe1[lane];
    }
}

// ---------------- FFN + residual + LN2 (2 rows per wave-iteration) ----------------
__global__ __launch_bounds__(1024) void k_ffn(
    const float* __restrict__ hb,
    const float* __restrict__ W1, const float* __restrict__ bf1,
    const float* __restrict__ W2, const float* __restrict__ bf2,
    const float* __restrict__ g2, const float* __restrict__ be2,
    float* __restrict__ h2)
{
    __shared__ __align__(16) float sW1[D * DFF];
    __shared__ float sW2[DFF * D];
    __shared__ __align__(16) float sbf1[DFF];
    __shared__ float sbf2[D], sg2[D], sbe2[D];
    for (int i = threadIdx.x; i < D * DFF; i += 1024) { sW1[i] = W1[i]; sW2[i] = W2[i]; }
    if (threadIdx.x < DFF) sbf1[threadIdx.x] = bf1[threadIdx.x];
    if (threadIdx.x < D) {
        sbf2[threadIdx.x] = bf2[threadIdx.x];
        sg2[threadIdx.x] = g2[threadIdx.x];
        sbe2[threadIdx.x] = be2[threadIdx.x];
    }
    __syncthreads();
    const int lane = threadIdx.x & 63;
    int w = (blockIdx.x * 1024 + threadIdx.x) >> 6;
    const int nw = (gridDim.x * 1024) >> 6;
    for (int pr = w; pr < NN / 2; pr += nw) {
        const int row0 = pr * 2;
        float h0 = hb[row0 * D + lane];
        float h1 = hb[(row0 + 1) * D + lane];
        float4 a0 = *(const float4*)&sbf1[4 * lane];
        float4 a1 = a0;
        #pragma unroll
        for (int d = 0; d < D; ++d) {
            float4 wv = *(const float4*)&sW1[d * DFF + 4 * lane];
            float b0 = __shfl(h0, d, 64);
            float b1 = __shfl(h1, d, 64);
            a0.x = fmaf(b0, wv.x, a0.x); a0.y = fmaf(b0, wv.y, a0.y);
            a0.z = fmaf(b0, wv.z, a0.z); a0.w = fmaf(b0, wv.w, a0.w);
            a1.x = fmaf(b1, wv.x, a1.x); a1.y = fmaf(b1, wv.y, a1.y);
            a1.z = fmaf(b1, wv.z, a1.z); a1.w = fmaf(b1, wv.w, a1.w);
        }
        // relu; lane L holds t[4L..4L+3]
        float t00 = fmaxf(a0.x, 0.f), t01 = fmaxf(a0.y, 0.f), t02 = fmaxf(a0.z, 0.f), t03 = fmaxf(a0.w, 0.f);
        float t10 = fmaxf(a1.x, 0.f), t11 = fmaxf(a1.y, 0.f), t12 = fmaxf(a1.z, 0.f), t13 = fmaxf(a1.w, 0.f);
        float o0 = sbf2[lane], o1 = o0;
        #pragma unroll
        for (int t = 0; t < DFF; ++t) {
            float wv = sW2[t * D + lane];
            const int sl = t >> 2;
            float s0 = ((t & 3) == 0) ? t00 : ((t & 3) == 1) ? t01 : ((t & 3) == 2) ? t02 : t03;
            float s1 = ((t & 3) == 0) ? t10 : ((t & 3) == 1) ? t11 : ((t & 3) == 2) ? t12 : t13;
            o0 = fmaf(__shfl(s0, sl, 64), wv, o0);
            o1 = fmaf(__shfl(s1, sl, 64), wv, o1);
        }
        {
            float r = h0 + o0;
            float mu = wsum64(r) * (1.f / 64.f);
            float dv = r - mu;
            float var = wsum64(dv * dv) * (1.f / 64.f);
            h2[row0 * D + lane] = dv * rsqrtf(var + EPS) * sg2[lane] + sbe2[lane];
        }
        {
            float r = h1 + o1;
            float mu = wsum64(r) * (1.f / 64.f);
            float dv = r - mu;
            float var = wsum64(dv * dv) * (1.f / 64.f);
            h2[(row0 + 1) * D + lane] = dv * rsqrtf(var + EPS) * sg2[lane] + sbe2[lane];
        }
    }
}

// ---------------- GNN scatter: h_nb[r] += ev * h2[c] ----------------
__global__ __launch_bounds__(256) void k_scatter(
    const float* __restrict__ h2, const int* __restrict__ rows,
    const int* __restrict__ cols, const float* __restrict__ ev,
    float* __restrict__ hnb, int E)
{
    const int lane = threadIdx.x & 63;
    int w = (blockIdx.x * 256 + threadIdx.x) >> 6;
    const int nw = (gridDim.x * 256) >> 6;
    for (int e = w; e < E; e += nw) {
        int r = rows[e], c = cols[e];
        float wt = ev[e];
        float v = h2[c * D + lane] * wt;
        atomicAdd(&hnb[r * D + lane], v);
    }
}

// ---------------- GNN linear + relu + residual + LN -> fp32 out ----------------
__global__ __launch_bounds__(256) void k_gnn(
    const float* __restrict__ h2, const float* __restrict__ hnb,
    const float* __restrict__ Wg, const float* __restrict__ bg,
    const float* __restrict__ gg, const float* __restrict__ bgn,
    float* __restrict__ out)
{
    __shared__ float sWg[2 * D * D];
    __shared__ float sbg[D], sgg[D], sbgn[D];
    for (int i = threadIdx.x; i < 2 * D * D; i += 256) sWg[i] = Wg[i];
    if (threadIdx.x < D) {
        sbg[threadIdx.x] = bg[threadIdx.x];
        sgg[threadIdx.x] = gg[threadIdx.x];
        sbgn[threadIdx.x] = bgn[threadIdx.x];
    }
    __syncthreads();
    const int lane = threadIdx.x & 63;
    int w = (blockIdx.x * 256 + threadIdx.x) >> 6;
    const int nw = (gridDim.x * 256) >> 6;
    for (int row = w; row < NN; row += nw) {
        float a = h2[row * D + lane];
        float b = hnb[row * D + lane];
        float acc = sbg[lane];
        #pragma unroll
        for (int d = 0; d < D; ++d) {
            acc = fmaf(__shfl(a, d, 64), sWg[d * D + lane], acc);
            acc = fmaf(__shfl(b, d, 64), sWg[(D + d) * D + lane], acc);
        }
        float hn = fmaxf(acc, 0.f);
        float r = hn + a;
        float mu = wsum64(r) * (1.f / 64.f);
        float dv = r - mu;
        float var = wsum64(dv * dv) * (1.f / 64.f);
        out[row * D + lane] = dv * rsqrtf(var + EPS) * sgg[lane] + sbgn[lane];
    }
}

// ---------------- attention_samples passthrough (as fp32) ----------------
__global__ __launch_bounds__(256) void k_samples(
    const int* __restrict__ samp, float* __restrict__ out, int n)
{
    int i = blockIdx.x * blockDim.x + threadIdx.x;
    const int stride = gridDim.x * blockDim.x;
    for (; i < n; i += stride) out[i] = (float)samp[i];
}

extern "C" void kernel_launch(void* const* d_in, const int* in_sizes, int n_in,
                              void* d_out, int out_size, void* d_ws, size_t ws_size,
                              hipStream_t stream)
{
    const float* x   = (const float*)d_in[0];
    const int*   rows = (const int*)d_in[1];
    const int*   cols = (const int*)d_in[2];
    const float* ev  = (const float*)d_in[3];
    const int*   samp = (const int*)d_in[4];
    const float* Wq  = (const float*)d_in[5];
    const float* bq  = (const float*)d_in[6];
    const float* Wk  = (const float*)d_in[7];
    const float* bk  = (const float*)d_in[8];
    const float* Wv  = (const float*)d_in[9];
    const float* bv  = (const float*)d_in[10];
    const float* Wo  = (const float*)d_in[11];
    const float* bo  = (const float*)d_in[12];
    const float* g1  = (const float*)d_in[13];
    const float* be1 = (const float*)d_in[14];
    const float* g2  = (const float*)d_in[15];
    const float* be2 = (const float*)d_in[16];
    const float* W1  = (const float*)d_in[17];
    const float* bf1 = (const float*)d_in[18];
    const float* W2  = (const float*)d_in[19];
    const float* bf2 = (const float*)d_in[20];
    const float* Wg  = (const float*)d_in[21];
    const float* bg  = (const float*)d_in[22];
    const float* gg  = (const float*)d_in[23];
    const float* bgn = (const float*)d_in[24];
    const int E = in_sizes[1];

    float* Kp  = (float*)d_ws;                   // buffer 0: Kp, later h2
    float* Vp  = Kp + (size_t)NN * D;            // buffer 1: Vp, later h_nb
    float* hb  = Vp + (size_t)NN * D;            // buffer 2: h (post-LN1)
    float* h2  = Kp;
    float* hnb = Vp;

    float* out = (float*)d_out;

    k_proj_kv<<<2048, 256, 0, stream>>>(x, Wk, bk, Wv, bv, Kp, Vp);
    k_attn<<<4096, 256, 0, stream>>>(x, Kp, Vp, samp, Wq, bq, Wo, bo, g1, be1, hb);
    k_ffn<<<512, 1024, 0, stream>>>(hb, W1, bf1, W2, bf2, g2, be2, h2);
    hipMemsetAsync(hnb, 0, (size_t)NN * D * sizeof(float), stream);
    k_scatter<<<4096, 256, 0, stream>>>(h2, rows, cols, ev, hnb, E);
    k_gnn<<<2048, 256, 0, stream>>>(h2, hnb, Wg, bg, gg, bgn, out);
    k_samples<<<2048, 256, 0, stream>>>(samp, out + (size_t)NN * D, NN * KS);
}

// Round 3
// 1411.345 us; speedup vs baseline: 1.9409x; 1.9409x over previous
//
#include <hip/hip_runtime.h>
#include <hip/hip_bf16.h>

#define NN  100000
#define D   64
#define KS  20
#define DFF 256
#define EPS 1e-5f

typedef __attribute__((ext_vector_type(8))) short bf16x8;
typedef __attribute__((ext_vector_type(4))) float f32x4;

__device__ __forceinline__ short f2b(float f) {
    return __builtin_bit_cast(short, __float2bfloat16(f));
}

__device__ __forceinline__ float wsum64(float v) {
    v += __shfl_xor(v, 1, 64);
    v += __shfl_xor(v, 2, 64);
    v += __shfl_xor(v, 4, 64);
    v += __shfl_xor(v, 8, 64);
    v += __shfl_xor(v, 16, 64);
    v += __shfl_xor(v, 32, 64);
    return v;
}

// 16-lane-group sum (for MFMA C-layout row reductions)
__device__ __forceinline__ float gsum16(float v) {
    v += __shfl_xor(v, 1, 64);
    v += __shfl_xor(v, 2, 64);
    v += __shfl_xor(v, 4, 64);
    v += __shfl_xor(v, 8, 64);
    return v;
}

// ---------------- weight fragment prep (bf16, B-operand layout) ----------------
// B-frag for mfma_f32_16x16x32_bf16: lane l, elem i -> B[k][n],
//   n = nt*16 + (l&15), k = kt*32 + (l>>4)*8 + i
// W1f: 32 frags (f = nt*2 + kt),  W2f: 32 frags (f = nt*8 + kt),
// Wgf: 16 frags (f = nt*4 + kt)
__global__ __launch_bounds__(256) void k_prep(
    const float* __restrict__ W1, const float* __restrict__ W2,
    const float* __restrict__ Wg, short* __restrict__ S)
{
    int idx = blockIdx.x * 256 + threadIdx.x;
    const int total = 16384 + 16384 + 8192;
    for (; idx < total; idx += gridDim.x * 256) {
        float v;
        if (idx < 16384) {
            int f = idx >> 9, rem = idx & 511;
            int l = rem >> 3, i = rem & 7;
            int nt = f >> 1, kt = f & 1;
            int k = kt * 32 + (l >> 4) * 8 + i;
            int n = nt * 16 + (l & 15);
            v = W1[k * DFF + n];
        } else if (idx < 32768) {
            int j = idx - 16384;
            int f = j >> 9, rem = j & 511;
            int l = rem >> 3, i = rem & 7;
            int nt = f >> 3, kt = f & 7;
            int k = kt * 32 + (l >> 4) * 8 + i;
            int n = nt * 16 + (l & 15);
            v = W2[k * D + n];
        } else {
            int j = idx - 32768;
            int f = j >> 9, rem = j & 511;
            int l = rem >> 3, i = rem & 7;
            int nt = f >> 2, kt = f & 3;
            int k = kt * 32 + (l >> 4) * 8 + i;
            int n = nt * 16 + (l & 15);
            v = Wg[k * D + n];
        }
        S[idx] = f2b(v);
    }
}

// ---------------- K/V projection: Kp = x@Wk+bk, Vp = x@Wv+bv ----------------
__global__ __launch_bounds__(256) void k_proj_kv(
    const float* __restrict__ x,
    const float* __restrict__ Wk, const float* __restrict__ bk,
    const float* __restrict__ Wv, const float* __restrict__ bv,
    float* __restrict__ Kp, float* __restrict__ Vp)
{
    __shared__ float sWk[D * D], sWv[D * D];
    __shared__ float sbk[D], sbv[D];
    for (int i = threadIdx.x; i < D * D; i += 256) { sWk[i] = Wk[i]; sWv[i] = Wv[i]; }
    if (threadIdx.x < D) { sbk[threadIdx.x] = bk[threadIdx.x]; sbv[threadIdx.x] = bv[threadIdx.x]; }
    __syncthreads();
    const int lane = threadIdx.x & 63;
    int w = (blockIdx.x * 256 + threadIdx.x) >> 6;
    const int nw = (gridDim.x * 256) >> 6;
    for (int row = w; row < NN; row += nw) {
        float xv = x[row * D + lane];
        float aK = sbk[lane], aV = sbv[lane];
        #pragma unroll
        for (int d = 0; d < D; ++d) {
            float xd = __shfl(xv, d, 64);
            aK = fmaf(xd, sWk[d * D + lane], aK);
            aV = fmaf(xd, sWv[d * D + lane], aV);
        }
        Kp[row * D + lane] = aK;
        Vp[row * D + lane] = aV;
    }
}

// ---------------- attention + Wo + residual + LN1 ----------------
__global__ __launch_bounds__(256) void k_attn(
    const float* __restrict__ x,
    const float* __restrict__ Kp, const float* __restrict__ Vp,
    const int* __restrict__ samp,
    const float* __restrict__ Wq, const float* __restrict__ bq,
    const float* __restrict__ Wo, const float* __restrict__ bo,
    const float* __restrict__ g1, const float* __restrict__ be1,
    float* __restrict__ hb)
{
    __shared__ float sWq[D * D], sWo[D * D];
    __shared__ float sbq[D], sbo[D], sg1[D], sbe1[D];
    for (int i = threadIdx.x; i < D * D; i += 256) { sWq[i] = Wq[i]; sWo[i] = Wo[i]; }
    if (threadIdx.x < D) {
        sbq[threadIdx.x] = bq[threadIdx.x]; sbo[threadIdx.x] = bo[threadIdx.x];
        sg1[threadIdx.x] = g1[threadIdx.x]; sbe1[threadIdx.x] = be1[threadIdx.x];
    }
    __syncthreads();
    const int lane = threadIdx.x & 63;
    int w = (blockIdx.x * 256 + threadIdx.x) >> 6;
    const int nw = (gridDim.x * 256) >> 6;
    for (int row = w; row < NN; row += nw) {
        float xj = x[row * D + lane];
        int idx_reg = 0;
        if (lane < KS) idx_reg = samp[row * KS + lane];

        float q = sbq[lane];
        #pragma unroll
        for (int d = 0; d < D; ++d)
            q = fmaf(__shfl(xj, d, 64), sWq[d * D + lane], q);

        int iks[KS];
        float s[KS];
        #pragma unroll
        for (int k = 0; k < KS; ++k) {
            iks[k] = __shfl(idx_reg, k, 64);
            float p = q * Kp[iks[k] * D + lane];
            p += __shfl_xor(p, 1, 64);
            p += __shfl_xor(p, 2, 64);
            p += __shfl_xor(p, 4, 64);
            p += __shfl_xor(p, 8, 64);
            s[k] = p * 0.25f;
        }
        float m = s[0];
        #pragma unroll
        for (int k = 1; k < KS; ++k) m = fmaxf(m, s[k]);
        float ssum = 0.f;
        #pragma unroll
        for (int k = 0; k < KS; ++k) { s[k] = __expf(s[k] - m); ssum += s[k]; }
        float inv = 1.0f / ssum;

        float o = 0.f;
        #pragma unroll
        for (int k = 0; k < KS; ++k)
            o = fmaf(s[k] * inv, Vp[iks[k] * D + lane], o);

        float acc = sbo[lane];
        #pragma unroll
        for (int d = 0; d < D; ++d)
            acc = fmaf(__shfl(o, d, 64), sWo[d * D + lane], acc);
        float r = xj + acc;
        float mu = wsum64(r) * (1.f / 64.f);
        float dv = r - mu;
        float var = wsum64(dv * dv) * (1.f / 64.f);
        hb[row * D + lane] = dv * rsqrtf(var + EPS) * sg1[lane] + sbe1[lane];
    }
}

// ---------------- FFN via MFMA: relu(hb@W1+b1)@W2+b2, +residual, LN2 ----------------
__global__ __launch_bounds__(256) void k_ffn_mfma(
    const float* __restrict__ hb,
    const short* __restrict__ wf,   // W1 frags at 0, W2 frags at +16384
    const float* __restrict__ bf1, const float* __restrict__ bf2,
    const float* __restrict__ g2, const float* __restrict__ be2,
    float* __restrict__ h2)
{
    __shared__ __align__(16) short Tl[4][16][264];  // per-wave relu(T) staging, padded
    const int lane = threadIdx.x & 63;
    const int wv   = threadIdx.x >> 6;
    const int c0   = lane & 15;
    const int g    = lane >> 4;
    const bf16x8* w1p = (const bf16x8*)wf;
    const bf16x8* w2p = (const bf16x8*)(wf + 16384);

    float b1v[16];
    #pragma unroll
    for (int nt = 0; nt < 16; ++nt) b1v[nt] = bf1[nt * 16 + c0];
    float b2v[4], g2v[4], bev[4];
    #pragma unroll
    for (int nt = 0; nt < 4; ++nt) {
        b2v[nt] = bf2[nt * 16 + c0];
        g2v[nt] = g2[nt * 16 + c0];
        bev[nt] = be2[nt * 16 + c0];
    }

    int wid = (blockIdx.x * 256 + threadIdx.x) >> 6;
    const int nwaves = (gridDim.x * 256) >> 6;
    for (int tile = wid; tile < NN / 16; tile += nwaves) {
        const int row0 = tile * 16;
        // A-frags: A[m][k], m = row0 + (lane&15), k = kt*32 + (lane>>4)*8 + i
        const float* ar = hb + (size_t)(row0 + c0) * D + g * 8;
        bf16x8 a0, a1;
        {
            float4 f0 = *(const float4*)(ar);
            float4 f1 = *(const float4*)(ar + 4);
            float4 f2 = *(const float4*)(ar + 32);
            float4 f3 = *(const float4*)(ar + 36);
            a0[0] = f2b(f0.x); a0[1] = f2b(f0.y); a0[2] = f2b(f0.z); a0[3] = f2b(f0.w);
            a0[4] = f2b(f1.x); a0[5] = f2b(f1.y); a0[6] = f2b(f1.z); a0[7] = f2b(f1.w);
            a1[0] = f2b(f2.x); a1[1] = f2b(f2.y); a1[2] = f2b(f2.z); a1[3] = f2b(f2.w);
            a1[4] = f2b(f3.x); a1[5] = f2b(f3.y); a1[6] = f2b(f3.z); a1[7] = f2b(f3.w);
        }
        // stage 1: T = relu(A@W1 + b1)   [16 x 256]
        f32x4 acc1[16];
        #pragma unroll
        for (int nt = 0; nt < 16; ++nt) {
            float b = b1v[nt];
            f32x4 c = {b, b, b, b};
            c = __builtin_amdgcn_mfma_f32_16x16x32_bf16(a0, w1p[(nt * 2 + 0) * 64 + lane], c, 0, 0, 0);
            c = __builtin_amdgcn_mfma_f32_16x16x32_bf16(a1, w1p[(nt * 2 + 1) * 64 + lane], c, 0, 0, 0);
            acc1[nt] = c;
        }
        // relu -> bf16 T in LDS (C layout: row=(g*4+r), col=nt*16+c0)
        #pragma unroll
        for (int nt = 0; nt < 16; ++nt) {
            #pragma unroll
            for (int r = 0; r < 4; ++r)
                Tl[wv][g * 4 + r][nt * 16 + c0] = f2b(fmaxf(acc1[nt][r], 0.f));
        }
        // stage 2: O = T@W2 + b2   [16 x 64]
        bf16x8 a2[8];
        #pragma unroll
        for (int kt = 0; kt < 8; ++kt)
            a2[kt] = *(const bf16x8*)&Tl[wv][c0][kt * 32 + g * 8];
        f32x4 acc2[4];
        #pragma unroll
        for (int nt = 0; nt < 4; ++nt) {
            float b = b2v[nt];
            f32x4 c = {b, b, b, b};
            #pragma unroll
            for (int kt = 0; kt < 8; ++kt)
                c = __builtin_amdgcn_mfma_f32_16x16x32_bf16(a2[kt], w2p[(nt * 8 + kt) * 64 + lane], c, 0, 0, 0);
            acc2[nt] = c;
        }
        // epilogue: residual + LN2
        const int r0 = row0 + g * 4;
        #pragma unroll
        for (int r = 0; r < 4; ++r) {
            float rv[4];
            float s = 0.f;
            #pragma unroll
            for (int nt = 0; nt < 4; ++nt) {
                rv[nt] = acc2[nt][r] + hb[(size_t)(r0 + r) * D + nt * 16 + c0];
                s += rv[nt];
            }
            s = gsum16(s);
            float mu = s * (1.f / 64.f);
            float q = 0.f;
            #pragma unroll
            for (int nt = 0; nt < 4; ++nt) { float d = rv[nt] - mu; q += d * d; }
            q = gsum16(q);
            float inv = rsqrtf(q * (1.f / 64.f) + EPS);
            #pragma unroll
            for (int nt = 0; nt < 4; ++nt)
                h2[(size_t)(r0 + r) * D + nt * 16 + c0] = (rv[nt] - mu) * inv * g2v[nt] + bev[nt];
        }
    }
}

// ---------------- GNN scatter: h_nb[r] += ev * h2[c] ----------------
__global__ __launch_bounds__(256) void k_scatter(
    const float* __restrict__ h2, const int* __restrict__ rows,
    const int* __restrict__ cols, const float* __restrict__ ev,
    float* __restrict__ hnb, int E)
{
    const int lane = threadIdx.x & 63;
    int w = (blockIdx.x * 256 + threadIdx.x) >> 6;
    const int nw = (gridDim.x * 256) >> 6;
    for (int e = w; e < E; e += nw) {
        int r = rows[e], c = cols[e];
        float wt = ev[e];
        float v = h2[c * D + lane] * wt;
        atomicAdd(&hnb[r * D + lane], v);
    }
}

// ---------------- GNN linear (MFMA) + relu + residual + LN -> fp32 out ----------------
__global__ __launch_bounds__(256) void k_gnn_mfma(
    const float* __restrict__ h2, const float* __restrict__ hnb,
    const short* __restrict__ wgf,
    const float* __restrict__ bg, const float* __restrict__ gg,
    const float* __restrict__ bgn,
    float* __restrict__ out)
{
    const int lane = threadIdx.x & 63;
    const int c0 = lane & 15;
    const int g  = lane >> 4;
    const bf16x8* wp = (const bf16x8*)wgf;

    float bgv[4], ggv[4], bnv[4];
    #pragma unroll
    for (int nt = 0; nt < 4; ++nt) {
        bgv[nt] = bg[nt * 16 + c0];
        ggv[nt] = gg[nt * 16 + c0];
        bnv[nt] = bgn[nt * 16 + c0];
    }

    int wid = (blockIdx.x * 256 + threadIdx.x) >> 6;
    const int nwaves = (gridDim.x * 256) >> 6;
    for (int tile = wid; tile < NN / 16; tile += nwaves) {
        const int row0 = tile * 16;
        const float* ar = h2  + (size_t)(row0 + c0) * D + g * 8;
        const float* br = hnb + (size_t)(row0 + c0) * D + g * 8;
        bf16x8 a[4];
        #pragma unroll
        for (int h = 0; h < 2; ++h) {
            const float* p = (h == 0) ? ar : br;
            #pragma unroll
            for (int kt = 0; kt < 2; ++kt) {
                float4 f0 = *(const float4*)(p + kt * 32);
                float4 f1 = *(const float4*)(p + kt * 32 + 4);
                bf16x8 v;
                v[0] = f2b(f0.x); v[1] = f2b(f0.y); v[2] = f2b(f0.z); v[3] = f2b(f0.w);
                v[4] = f2b(f1.x); v[5] = f2b(f1.y); v[6] = f2b(f1.z); v[7] = f2b(f1.w);
                a[h * 2 + kt] = v;
            }
        }
        f32x4 acc[4];
        #pragma unroll
        for (int nt = 0; nt < 4; ++nt) {
            float b = bgv[nt];
            f32x4 c = {b, b, b, b};
            #pragma unroll
            for (int kt = 0; kt < 4; ++kt)
                c = __builtin_amdgcn_mfma_f32_16x16x32_bf16(a[kt], wp[(nt * 4 + kt) * 64 + lane], c, 0, 0, 0);
            acc[nt] = c;
        }
        const int r0 = row0 + g * 4;
        #pragma unroll
        for (int r = 0; r < 4; ++r) {
            float rv[4];
            float s = 0.f;
            #pragma unroll
            for (int nt = 0; nt < 4; ++nt) {
                float hn = fmaxf(acc[nt][r], 0.f);
                rv[nt] = hn + h2[(size_t)(r0 + r) * D + nt * 16 + c0];
                s += rv[nt];
            }
            s = gsum16(s);
            float mu = s * (1.f / 64.f);
            float q = 0.f;
            #pragma unroll
            for (int nt = 0; nt < 4; ++nt) { float d = rv[nt] - mu; q += d * d; }
            q = gsum16(q);
            float inv = rsqrtf(q * (1.f / 64.f) + EPS);
            #pragma unroll
            for (int nt = 0; nt < 4; ++nt)
                out[(size_t)(r0 + r) * D + nt * 16 + c0] = (rv[nt] - mu) * inv * ggv[nt] + bnv[nt];
        }
    }
}

// ---------------- attention_samples passthrough (as fp32) ----------------
__global__ __launch_bounds__(256) void k_samples(
    const int* __restrict__ samp, float* __restrict__ out, int n)
{
    int i = blockIdx.x * blockDim.x + threadIdx.x;
    const int stride = gridDim.x * blockDim.x;
    for (; i < n; i += stride) out[i] = (float)samp[i];
}

extern "C" void kernel_launch(void* const* d_in, const int* in_sizes, int n_in,
                              void* d_out, int out_size, void* d_ws, size_t ws_size,
                              hipStream_t stream)
{
    const float* x   = (const float*)d_in[0];
    const int*   rows = (const int*)d_in[1];
    const int*   cols = (const int*)d_in[2];
    const float* ev  = (const float*)d_in[3];
    const int*   samp = (const int*)d_in[4];
    const float* Wq  = (const float*)d_in[5];
    const float* bq  = (const float*)d_in[6];
    const float* Wk  = (const float*)d_in[7];
    const float* bk  = (const float*)d_in[8];
    const float* Wv  = (const float*)d_in[9];
    const float* bv  = (const float*)d_in[10];
    const float* Wo  = (const float*)d_in[11];
    const float* bo  = (const float*)d_in[12];
    const float* g1  = (const float*)d_in[13];
    const float* be1 = (const float*)d_in[14];
    const float* g2  = (const float*)d_in[15];
    const float* be2 = (const float*)d_in[16];
    const float* W1  = (const float*)d_in[17];
    const float* bf1 = (const float*)d_in[18];
    const float* W2  = (const float*)d_in[19];
    const float* bf2 = (const float*)d_in[20];
    const float* Wg  = (const float*)d_in[21];
    const float* bg  = (const float*)d_in[22];
    const float* gg  = (const float*)d_in[23];
    const float* bgn = (const float*)d_in[24];
    const int E = in_sizes[1];

    float* Kp  = (float*)d_ws;                   // buffer 0: Kp, later h2
    float* Vp  = Kp + (size_t)NN * D;            // buffer 1: Vp, later h_nb
    float* hb  = Vp + (size_t)NN * D;            // buffer 2: h (post-LN1)
    float* h2  = Kp;
    float* hnb = Vp;

    float* out = (float*)d_out;
    // weight-fragment scratch lives in the samples region of d_out;
    // k_samples overwrites it at the end of every call (deterministic).
    short* S = (short*)(out + (size_t)NN * D);

    k_prep<<<40, 256, 0, stream>>>(W1, W2, Wg, S);
    k_proj_kv<<<2048, 256, 0, stream>>>(x, Wk, bk, Wv, bv, Kp, Vp);
    k_attn<<<4096, 256, 0, stream>>>(x, Kp, Vp, samp, Wq, bq, Wo, bo, g1, be1, hb);
    k_ffn_mfma<<<1563, 256, 0, stream>>>(hb, S, bf1, bf2, g2, be2, h2);
    hipMemsetAsync(hnb, 0, (size_t)NN * D * sizeof(float), stream);
    k_scatter<<<4096, 256, 0, stream>>>(h2, rows, cols, ev, hnb, E);
    k_gnn_mfma<<<1563, 256, 0, stream>>>(h2, hnb, S + 32768, bg, gg, bgn, out);
    k_samples<<<2048, 256, 0, stream>>>(samp, out + (size_t)NN * D, NN * KS);
}

// Round 4
// 1259.980 us; speedup vs baseline: 2.1740x; 1.1201x over previous
//
#include <hip/hip_runtime.h>
#include <hip/hip_bf16.h>

#define NN  100000
#define D   64
#define KS  20
#define DFF 256
#define EPS 1e-5f

typedef __attribute__((ext_vector_type(8))) short bf16x8;
typedef __attribute__((ext_vector_type(4))) float f32x4;

__device__ __forceinline__ short f2b(float f) {
    return __builtin_bit_cast(short, __float2bfloat16(f));
}
__device__ __forceinline__ unsigned short f2bu(float f) {
    return __builtin_bit_cast(unsigned short, __float2bfloat16(f));
}
__device__ __forceinline__ float b2f(unsigned short u) {
    return __builtin_bit_cast(float, ((unsigned)u) << 16);
}

__device__ __forceinline__ float wsum64(float v) {
    v += __shfl_xor(v, 1, 64);
    v += __shfl_xor(v, 2, 64);
    v += __shfl_xor(v, 4, 64);
    v += __shfl_xor(v, 8, 64);
    v += __shfl_xor(v, 16, 64);
    v += __shfl_xor(v, 32, 64);
    return v;
}
__device__ __forceinline__ float gsum16(float v) {
    v += __shfl_xor(v, 1, 64);
    v += __shfl_xor(v, 2, 64);
    v += __shfl_xor(v, 4, 64);
    v += __shfl_xor(v, 8, 64);
    return v;
}

// ---------------- weight fragment prep (bf16, B-operand layout) ----------------
__global__ __launch_bounds__(256) void k_prep(
    const float* __restrict__ W1, const float* __restrict__ W2,
    const float* __restrict__ Wg, short* __restrict__ S)
{
    int idx = blockIdx.x * 256 + threadIdx.x;
    const int total = 16384 + 16384 + 8192;
    for (; idx < total; idx += gridDim.x * 256) {
        float v;
        if (idx < 16384) {
            int f = idx >> 9, rem = idx & 511;
            int l = rem >> 3, i = rem & 7;
            int nt = f >> 1, kt = f & 1;
            int k = kt * 32 + (l >> 4) * 8 + i;
            int n = nt * 16 + (l & 15);
            v = W1[k * DFF + n];
        } else if (idx < 32768) {
            int j = idx - 16384;
            int f = j >> 9, rem = j & 511;
            int l = rem >> 3, i = rem & 7;
            int nt = f >> 3, kt = f & 7;
            int k = kt * 32 + (l >> 4) * 8 + i;
            int n = nt * 16 + (l & 15);
            v = W2[k * D + n];
        } else {
            int j = idx - 32768;
            int f = j >> 9, rem = j & 511;
            int l = rem >> 3, i = rem & 7;
            int nt = f >> 2, kt = f & 3;
            int k = kt * 32 + (l >> 4) * 8 + i;
            int n = nt * 16 + (l & 15);
            v = Wg[k * D + n];
        }
        S[idx] = f2b(v);
    }
}

// ---------------- CSR build: histogram ----------------
__global__ __launch_bounds__(256) void k_hist(
    const int* __restrict__ rows, int* __restrict__ counts, int E)
{
    int i = blockIdx.x * 256 + threadIdx.x;
    for (; i < E; i += gridDim.x * 256) atomicAdd(&counts[rows[i]], 1);
}

// ---------------- CSR build: single-block exclusive scan ----------------
__global__ __launch_bounds__(1024) void k_scan(
    const int* __restrict__ counts, int* __restrict__ offsets, int* __restrict__ cursor)
{
    __shared__ int wsum[16];
    __shared__ int woff[16];
    __shared__ int s_carry, s_total;
    const int tid = threadIdx.x;
    const int lane = tid & 63;
    const int wv = tid >> 6;
    if (tid == 0) s_carry = 0;
    __syncthreads();
    for (int base = 0; base < NN; base += 4096) {
        int i0 = base + tid * 4;
        int c0 = (i0 + 0 < NN) ? counts[i0 + 0] : 0;
        int c1 = (i0 + 1 < NN) ? counts[i0 + 1] : 0;
        int c2 = (i0 + 2 < NN) ? counts[i0 + 2] : 0;
        int c3 = (i0 + 3 < NN) ? counts[i0 + 3] : 0;
        int s = c0 + c1 + c2 + c3;
        int v = s;
        #pragma unroll
        for (int off = 1; off < 64; off <<= 1) {
            int t = __shfl_up(v, off, 64);
            if (lane >= off) v += t;
        }
        if (lane == 63) wsum[wv] = v;
        int texcl = v - s;
        __syncthreads();
        if (wv == 0) {
            int wval = (lane < 16) ? wsum[lane] : 0;
            #pragma unroll
            for (int off = 1; off < 16; off <<= 1) {
                int t = __shfl_up(wval, off, 64);
                if (lane >= off) wval += t;
            }
            if (lane < 16) woff[lane] = wval - wsum[lane];
            if (lane == 15) s_total = wval;
        }
        __syncthreads();
        int basev = s_carry + woff[wv] + texcl;
        int e0 = basev;
        int e1 = e0 + c0;
        int e2 = e1 + c1;
        int e3 = e2 + c2;
        if (i0 + 0 < NN) { offsets[i0 + 0] = e0; cursor[i0 + 0] = e0; }
        if (i0 + 1 < NN) { offsets[i0 + 1] = e1; cursor[i0 + 1] = e1; }
        if (i0 + 2 < NN) { offsets[i0 + 2] = e2; cursor[i0 + 2] = e2; }
        if (i0 + 3 < NN) { offsets[i0 + 3] = e3; cursor[i0 + 3] = e3; }
        __syncthreads();
        if (tid == 0) s_carry += s_total;
        __syncthreads();
    }
    if (threadIdx.x == 0) offsets[NN] = s_carry;
}

// ---------------- CSR build: fill payload (col, weight) grouped by row ----------------
__global__ __launch_bounds__(256) void k_fill(
    const int* __restrict__ rows, const int* __restrict__ cols,
    const float* __restrict__ ev, int* __restrict__ cursor,
    int2* __restrict__ payload, int E)
{
    int i = blockIdx.x * 256 + threadIdx.x;
    for (; i < E; i += gridDim.x * 256) {
        int r = rows[i];
        int pos = atomicAdd(&cursor[r], 1);
        payload[pos] = make_int2(cols[i], __float_as_int(ev[i]));
    }
}

// ---------------- segment gather-reduce: hnb[r] = sum ev * h2b[c]  (bf16 in/out) ----------------
__global__ __launch_bounds__(256) void k_gather(
    const int* __restrict__ offsets, const int2* __restrict__ payload,
    const unsigned short* __restrict__ h2b, unsigned short* __restrict__ hnb)
{
    const int lane = threadIdx.x & 63;
    const int g = lane >> 4, c0 = lane & 15;
    int w = (blockIdx.x * 256 + threadIdx.x) >> 6;
    const int nw = (gridDim.x * 256) >> 6;
    for (int row = w; row < NN; row += nw) {
        const int b = offsets[row], e = offsets[row + 1];
        float ax = 0.f, ay = 0.f, az = 0.f, aw = 0.f;
        for (int i = b + g; i < e; i += 4) {
            int2 p = payload[i];
            float wt = __int_as_float(p.y);
            const ushort4 v = *(const ushort4*)(h2b + (size_t)p.x * 64 + c0 * 4);
            ax = fmaf(b2f(v.x), wt, ax);
            ay = fmaf(b2f(v.y), wt, ay);
            az = fmaf(b2f(v.z), wt, az);
            aw = fmaf(b2f(v.w), wt, aw);
        }
        ax += __shfl_xor(ax, 16, 64); ax += __shfl_xor(ax, 32, 64);
        ay += __shfl_xor(ay, 16, 64); ay += __shfl_xor(ay, 32, 64);
        az += __shfl_xor(az, 16, 64); az += __shfl_xor(az, 32, 64);
        aw += __shfl_xor(aw, 16, 64); aw += __shfl_xor(aw, 32, 64);
        if (g == 0) {
            ushort4 o;
            o.x = f2bu(ax); o.y = f2bu(ay); o.z = f2bu(az); o.w = f2bu(aw);
            *(ushort4*)(hnb + (size_t)row * 64 + c0 * 4) = o;
        }
    }
}

// ---------------- K/V projection ----------------
__global__ __launch_bounds__(256) void k_proj_kv(
    const float* __restrict__ x,
    const float* __restrict__ Wk, const float* __restrict__ bk,
    const float* __restrict__ Wv, const float* __restrict__ bv,
    float* __restrict__ Kp, float* __restrict__ Vp)
{
    __shared__ float sWk[D * D], sWv[D * D];
    __shared__ float sbk[D], sbv[D];
    for (int i = threadIdx.x; i < D * D; i += 256) { sWk[i] = Wk[i]; sWv[i] = Wv[i]; }
    if (threadIdx.x < D) { sbk[threadIdx.x] = bk[threadIdx.x]; sbv[threadIdx.x] = bv[threadIdx.x]; }
    __syncthreads();
    const int lane = threadIdx.x & 63;
    int w = (blockIdx.x * 256 + threadIdx.x) >> 6;
    const int nw = (gridDim.x * 256) >> 6;
    for (int row = w; row < NN; row += nw) {
        float xv = x[row * D + lane];
        float aK = sbk[lane], aV = sbv[lane];
        #pragma unroll
        for (int d = 0; d < D; ++d) {
            float xd = __shfl(xv, d, 64);
            aK = fmaf(xd, sWk[d * D + lane], aK);
            aV = fmaf(xd, sWv[d * D + lane], aV);
        }
        Kp[row * D + lane] = aK;
        Vp[row * D + lane] = aV;
    }
}

// ---------------- attention + Wo + residual + LN1 ----------------
__global__ __launch_bounds__(256) void k_attn(
    const float* __restrict__ x,
    const float* __restrict__ Kp, const float* __restrict__ Vp,
    const int* __restrict__ samp,
    const float* __restrict__ Wq, const float* __restrict__ bq,
    const float* __restrict__ Wo, const float* __restrict__ bo,
    const float* __restrict__ g1, const float* __restrict__ be1,
    float* __restrict__ hb)
{
    __shared__ float sWq[D * D], sWo[D * D];
    __shared__ float sbq[D], sbo[D], sg1[D], sbe1[D];
    for (int i = threadIdx.x; i < D * D; i += 256) { sWq[i] = Wq[i]; sWo[i] = Wo[i]; }
    if (threadIdx.x < D) {
        sbq[threadIdx.x] = bq[threadIdx.x]; sbo[threadIdx.x] = bo[threadIdx.x];
        sg1[threadIdx.x] = g1[threadIdx.x]; sbe1[threadIdx.x] = be1[threadIdx.x];
    }
    __syncthreads();
    const int lane = threadIdx.x & 63;
    int w = (blockIdx.x * 256 + threadIdx.x) >> 6;
    const int nw = (gridDim.x * 256) >> 6;
    for (int row = w; row < NN; row += nw) {
        float xj = x[row * D + lane];
        int idx_reg = 0;
        if (lane < KS) idx_reg = samp[row * KS + lane];

        float q = sbq[lane];
        #pragma unroll
        for (int d = 0; d < D; ++d)
            q = fmaf(__shfl(xj, d, 64), sWq[d * D + lane], q);

        int iks[KS];
        float s[KS];
        #pragma unroll
        for (int k = 0; k < KS; ++k) {
            iks[k] = __shfl(idx_reg, k, 64);
            float p = q * Kp[iks[k] * D + lane];
            p += __shfl_xor(p, 1, 64);
            p += __shfl_xor(p, 2, 64);
            p += __shfl_xor(p, 4, 64);
            p += __shfl_xor(p, 8, 64);
            s[k] = p * 0.25f;
        }
        float m = s[0];
        #pragma unroll
        for (int k = 1; k < KS; ++k) m = fmaxf(m, s[k]);
        float ssum = 0.f;
        #pragma unroll
        for (int k = 0; k < KS; ++k) { s[k] = __expf(s[k] - m); ssum += s[k]; }
        float inv = 1.0f / ssum;

        float o = 0.f;
        #pragma unroll
        for (int k = 0; k < KS; ++k)
            o = fmaf(s[k] * inv, Vp[iks[k] * D + lane], o);

        float acc = sbo[lane];
        #pragma unroll
        for (int d = 0; d < D; ++d)
            acc = fmaf(__shfl(o, d, 64), sWo[d * D + lane], acc);
        float r = xj + acc;
        float mu = wsum64(r) * (1.f / 64.f);
        float dv = r - mu;
        float var = wsum64(dv * dv) * (1.f / 64.f);
        hb[row * D + lane] = dv * rsqrtf(var + EPS) * sg1[lane] + sbe1[lane];
    }
}

// ---------------- FFN via MFMA -> bf16 h2 ----------------
__global__ __launch_bounds__(256) void k_ffn_mfma(
    const float* __restrict__ hb,
    const short* __restrict__ wf,
    const float* __restrict__ bf1, const float* __restrict__ bf2,
    const float* __restrict__ g2, const float* __restrict__ be2,
    unsigned short* __restrict__ h2b)
{
    __shared__ __align__(16) short Tl[4][16][264];
    const int lane = threadIdx.x & 63;
    const int wv   = threadIdx.x >> 6;
    const int c0   = lane & 15;
    const int g    = lane >> 4;
    const bf16x8* w1p = (const bf16x8*)wf;
    const bf16x8* w2p = (const bf16x8*)(wf + 16384);

    float b1v[16];
    #pragma unroll
    for (int nt = 0; nt < 16; ++nt) b1v[nt] = bf1[nt * 16 + c0];
    float b2v[4], g2v[4], bev[4];
    #pragma unroll
    for (int nt = 0; nt < 4; ++nt) {
        b2v[nt] = bf2[nt * 16 + c0];
        g2v[nt] = g2[nt * 16 + c0];
        bev[nt] = be2[nt * 16 + c0];
    }

    int wid = (blockIdx.x * 256 + threadIdx.x) >> 6;
    const int nwaves = (gridDim.x * 256) >> 6;
    for (int tile = wid; tile < NN / 16; tile += nwaves) {
        const int row0 = tile * 16;
        const float* ar = hb + (size_t)(row0 + c0) * D + g * 8;
        bf16x8 a0, a1;
        {
            float4 f0 = *(const float4*)(ar);
            float4 f1 = *(const float4*)(ar + 4);
            float4 f2 = *(const float4*)(ar + 32);
            float4 f3 = *(const float4*)(ar + 36);
            a0[0] = f2b(f0.x); a0[1] = f2b(f0.y); a0[2] = f2b(f0.z); a0[3] = f2b(f0.w);
            a0[4] = f2b(f1.x); a0[5] = f2b(f1.y); a0[6] = f2b(f1.z); a0[7] = f2b(f1.w);
            a1[0] = f2b(f2.x); a1[1] = f2b(f2.y); a1[2] = f2b(f2.z); a1[3] = f2b(f2.w);
            a1[4] = f2b(f3.x); a1[5] = f2b(f3.y); a1[6] = f2b(f3.z); a1[7] = f2b(f3.w);
        }
        f32x4 acc1[16];
        #pragma unroll
        for (int nt = 0; nt < 16; ++nt) {
            float b = b1v[nt];
            f32x4 c = {b, b, b, b};
            c = __builtin_amdgcn_mfma_f32_16x16x32_bf16(a0, w1p[(nt * 2 + 0) * 64 + lane], c, 0, 0, 0);
            c = __builtin_amdgcn_mfma_f32_16x16x32_bf16(a1, w1p[(nt * 2 + 1) * 64 + lane], c, 0, 0, 0);
            acc1[nt] = c;
        }
        #pragma unroll
        for (int nt = 0; nt < 16; ++nt) {
            #pragma unroll
            for (int r = 0; r < 4; ++r)
                Tl[wv][g * 4 + r][nt * 16 + c0] = f2b(fmaxf(acc1[nt][r], 0.f));
        }
        bf16x8 a2[8];
        #pragma unroll
        for (int kt = 0; kt < 8; ++kt)
            a2[kt] = *(const bf16x8*)&Tl[wv][c0][kt * 32 + g * 8];
        f32x4 acc2[4];
        #pragma unroll
        for (int nt = 0; nt < 4; ++nt) {
            float b = b2v[nt];
            f32x4 c = {b, b, b, b};
            #pragma unroll
            for (int kt = 0; kt < 8; ++kt)
                c = __builtin_amdgcn_mfma_f32_16x16x32_bf16(a2[kt], w2p[(nt * 8 + kt) * 64 + lane], c, 0, 0, 0);
            acc2[nt] = c;
        }
        const int r0 = row0 + g * 4;
        #pragma unroll
        for (int r = 0; r < 4; ++r) {
            float rv[4];
            float s = 0.f;
            #pragma unroll
            for (int nt = 0; nt < 4; ++nt) {
                rv[nt] = acc2[nt][r] + hb[(size_t)(r0 + r) * D + nt * 16 + c0];
                s += rv[nt];
            }
            s = gsum16(s);
            float mu = s * (1.f / 64.f);
            float q = 0.f;
            #pragma unroll
            for (int nt = 0; nt < 4; ++nt) { float d = rv[nt] - mu; q += d * d; }
            q = gsum16(q);
            float inv = rsqrtf(q * (1.f / 64.f) + EPS);
            #pragma unroll
            for (int nt = 0; nt < 4; ++nt)
                h2b[(size_t)(r0 + r) * D + nt * 16 + c0] = f2bu((rv[nt] - mu) * inv * g2v[nt] + bev[nt]);
        }
    }
}

// ---------------- GNN linear (MFMA, bf16 inputs) + relu + residual + LN -> fp32 out ----------------
__global__ __launch_bounds__(256) void k_gnn_mfma(
    const unsigned short* __restrict__ h2b, const unsigned short* __restrict__ hnb,
    const short* __restrict__ wgf,
    const float* __restrict__ bg, const float* __restrict__ gg,
    const float* __restrict__ bgn,
    float* __restrict__ out)
{
    const int lane = threadIdx.x & 63;
    const int c0 = lane & 15;
    const int g  = lane >> 4;
    const bf16x8* wp = (const bf16x8*)wgf;

    float bgv[4], ggv[4], bnv[4];
    #pragma unroll
    for (int nt = 0; nt < 4; ++nt) {
        bgv[nt] = bg[nt * 16 + c0];
        ggv[nt] = gg[nt * 16 + c0];
        bnv[nt] = bgn[nt * 16 + c0];
    }

    int wid = (blockIdx.x * 256 + threadIdx.x) >> 6;
    const int nwaves = (gridDim.x * 256) >> 6;
    for (int tile = wid; tile < NN / 16; tile += nwaves) {
        const int row0 = tile * 16;
        bf16x8 a[4];
        #pragma unroll
        for (int kt = 0; kt < 2; ++kt) {
            a[kt]     = *(const bf16x8*)&h2b[(size_t)(row0 + c0) * 64 + kt * 32 + g * 8];
            a[2 + kt] = *(const bf16x8*)&hnb[(size_t)(row0 + c0) * 64 + kt * 32 + g * 8];
        }
        f32x4 acc[4];
        #pragma unroll
        for (int nt = 0; nt < 4; ++nt) {
            float b = bgv[nt];
            f32x4 c = {b, b, b, b};
            #pragma unroll
            for (int kt = 0; kt < 4; ++kt)
                c = __builtin_amdgcn_mfma_f32_16x16x32_bf16(a[kt], wp[(nt * 4 + kt) * 64 + lane], c, 0, 0, 0);
            acc[nt] = c;
        }
        const int r0 = row0 + g * 4;
        #pragma unroll
        for (int r = 0; r < 4; ++r) {
            float rv[4];
            float s = 0.f;
            #pragma unroll
            for (int nt = 0; nt < 4; ++nt) {
                float hn = fmaxf(acc[nt][r], 0.f);
                rv[nt] = hn + b2f(h2b[(size_t)(r0 + r) * 64 + nt * 16 + c0]);
                s += rv[nt];
            }
            s = gsum16(s);
            float mu = s * (1.f / 64.f);
            float q = 0.f;
            #pragma unroll
            for (int nt = 0; nt < 4; ++nt) { float d = rv[nt] - mu; q += d * d; }
            q = gsum16(q);
            float inv = rsqrtf(q * (1.f / 64.f) + EPS);
            #pragma unroll
            for (int nt = 0; nt < 4; ++nt)
                out[(size_t)(r0 + r) * D + nt * 16 + c0] = (rv[nt] - mu) * inv * ggv[nt] + bnv[nt];
        }
    }
}

// ---------------- attention_samples passthrough (as fp32) ----------------
__global__ __launch_bounds__(256) void k_samples(
    const int* __restrict__ samp, float* __restrict__ out, int n)
{
    int i = blockIdx.x * blockDim.x + threadIdx.x;
    const int stride = gridDim.x * blockDim.x;
    for (; i < n; i += stride) out[i] = (float)samp[i];
}

extern "C" void kernel_launch(void* const* d_in, const int* in_sizes, int n_in,
                              void* d_out, int out_size, void* d_ws, size_t ws_size,
                              hipStream_t stream)
{
    const float* x   = (const float*)d_in[0];
    const int*   rows = (const int*)d_in[1];
    const int*   cols = (const int*)d_in[2];
    const float* ev  = (const float*)d_in[3];
    const int*   samp = (const int*)d_in[4];
    const float* Wq  = (const float*)d_in[5];
    const float* bq  = (const float*)d_in[6];
    const float* Wk  = (const float*)d_in[7];
    const float* bk  = (const float*)d_in[8];
    const float* Wv  = (const float*)d_in[9];
    const float* bv  = (const float*)d_in[10];
    const float* Wo  = (const float*)d_in[11];
    const float* bo  = (const float*)d_in[12];
    const float* g1  = (const float*)d_in[13];
    const float* be1 = (const float*)d_in[14];
    const float* g2  = (const float*)d_in[15];
    const float* be2 = (const float*)d_in[16];
    const float* W1  = (const float*)d_in[17];
    const float* bf1 = (const float*)d_in[18];
    const float* W2  = (const float*)d_in[19];
    const float* bf2 = (const float*)d_in[20];
    const float* Wg  = (const float*)d_in[21];
    const float* bg  = (const float*)d_in[22];
    const float* gg  = (const float*)d_in[23];
    const float* bgn = (const float*)d_in[24];
    const int E = in_sizes[1];

    // ws layout: 3 buffers of NN*D floats
    float* buf0 = (float*)d_ws;                   // Kp  -> payload (int2[E])
    float* buf1 = buf0 + (size_t)NN * D;          // Vp  -> [hnb_b bf16 | h2b bf16]
    float* buf2 = buf1 + (size_t)NN * D;          // hb
    float* Kp = buf0;
    float* Vp = buf1;
    float* hb = buf2;
    int2* payload = (int2*)buf0;
    unsigned short* hnb_b = (unsigned short*)buf1;                     // NN*64 shorts
    unsigned short* h2b   = (unsigned short*)(buf1 + (size_t)NN * D / 2); // NN*64 shorts

    float* out = (float*)d_out;
    // scratch in samples region of d_out (rewritten by k_samples each call)
    short* S     = (short*)(out + (size_t)NN * D);   // 40960 shorts
    int* counts  = (int*)(S + 40960);                // NN
    int* offsets = counts + NN;                      // NN+1
    int* cursor  = offsets + NN + 1;                 // NN

    k_prep<<<40, 256, 0, stream>>>(W1, W2, Wg, S);
    hipMemsetAsync(counts, 0, (size_t)NN * sizeof(int), stream);
    k_hist<<<4096, 256, 0, stream>>>(rows, counts, E);
    k_scan<<<1, 1024, 0, stream>>>(counts, offsets, cursor);
    k_proj_kv<<<2048, 256, 0, stream>>>(x, Wk, bk, Wv, bv, Kp, Vp);
    k_attn<<<4096, 256, 0, stream>>>(x, Kp, Vp, samp, Wq, bq, Wo, bo, g1, be1, hb);
    k_ffn_mfma<<<1563, 256, 0, stream>>>(hb, S, bf1, bf2, g2, be2, h2b);
    k_fill<<<4096, 256, 0, stream>>>(rows, cols, ev, cursor, payload, E);
    k_gather<<<4096, 256, 0, stream>>>(offsets, payload, h2b, hnb_b);
    k_gnn_mfma<<<1563, 256, 0, stream>>>(h2b, hnb_b, S + 32768, bg, gg, bgn, out);
    k_samples<<<2048, 256, 0, stream>>>(samp, out + (size_t)NN * D, NN * KS);
}

// Round 5
// 906.412 us; speedup vs baseline: 3.0221x; 1.3901x over previous
//
#include <hip/hip_runtime.h>
#include <hip/hip_bf16.h>

#define NN  100000
#define D   64
#define KS  20
#define DFF 256
#define EPS 1e-5f

typedef __attribute__((ext_vector_type(8))) short bf16x8;
typedef __attribute__((ext_vector_type(4))) float f32x4;

__device__ __forceinline__ short f2b(float f) {
    return __builtin_bit_cast(short, __float2bfloat16(f));
}
__device__ __forceinline__ unsigned short f2bu(float f) {
    return __builtin_bit_cast(unsigned short, __float2bfloat16(f));
}
__device__ __forceinline__ float b2f(unsigned short u) {
    return __builtin_bit_cast(float, ((unsigned)u) << 16);
}

__device__ __forceinline__ float wsum64(float v) {
    v += __shfl_xor(v, 1, 64);
    v += __shfl_xor(v, 2, 64);
    v += __shfl_xor(v, 4, 64);
    v += __shfl_xor(v, 8, 64);
    v += __shfl_xor(v, 16, 64);
    v += __shfl_xor(v, 32, 64);
    return v;
}
__device__ __forceinline__ float gsum16(float v) {
    v += __shfl_xor(v, 1, 64);
    v += __shfl_xor(v, 2, 64);
    v += __shfl_xor(v, 4, 64);
    v += __shfl_xor(v, 8, 64);
    return v;
}

// ---------------- weight fragment prep (bf16, B-operand layout) ----------------
__global__ __launch_bounds__(256) void k_prep(
    const float* __restrict__ W1, const float* __restrict__ W2,
    const float* __restrict__ Wg, short* __restrict__ S)
{
    int idx = blockIdx.x * 256 + threadIdx.x;
    const int total = 16384 + 16384 + 8192;
    for (; idx < total; idx += gridDim.x * 256) {
        float v;
        if (idx < 16384) {
            int f = idx >> 9, rem = idx & 511;
            int l = rem >> 3, i = rem & 7;
            int nt = f >> 1, kt = f & 1;
            int k = kt * 32 + (l >> 4) * 8 + i;
            int n = nt * 16 + (l & 15);
            v = W1[k * DFF + n];
        } else if (idx < 32768) {
            int j = idx - 16384;
            int f = j >> 9, rem = j & 511;
            int l = rem >> 3, i = rem & 7;
            int nt = f >> 3, kt = f & 7;
            int k = kt * 32 + (l >> 4) * 8 + i;
            int n = nt * 16 + (l & 15);
            v = W2[k * D + n];
        } else {
            int j = idx - 32768;
            int f = j >> 9, rem = j & 511;
            int l = rem >> 3, i = rem & 7;
            int nt = f >> 2, kt = f & 3;
            int k = kt * 32 + (l >> 4) * 8 + i;
            int n = nt * 16 + (l & 15);
            v = Wg[k * D + n];
        }
        S[idx] = f2b(v);
    }
}

// ---------------- CSR build: histogram ----------------
__global__ __launch_bounds__(256) void k_hist(
    const int* __restrict__ rows, int* __restrict__ counts, int E)
{
    int i = blockIdx.x * 256 + threadIdx.x;
    for (; i < E; i += gridDim.x * 256) atomicAdd(&counts[rows[i]], 1);
}

// ---------------- CSR build: single-block exclusive scan ----------------
__global__ __launch_bounds__(1024) void k_scan(
    const int* __restrict__ counts, int* __restrict__ offsets, int* __restrict__ cursor)
{
    __shared__ int wsum[16];
    __shared__ int woff[16];
    __shared__ int s_carry, s_total;
    const int tid = threadIdx.x;
    const int lane = tid & 63;
    const int wv = tid >> 6;
    if (tid == 0) s_carry = 0;
    __syncthreads();
    for (int base = 0; base < NN; base += 4096) {
        int i0 = base + tid * 4;
        int c0 = (i0 + 0 < NN) ? counts[i0 + 0] : 0;
        int c1 = (i0 + 1 < NN) ? counts[i0 + 1] : 0;
        int c2 = (i0 + 2 < NN) ? counts[i0 + 2] : 0;
        int c3 = (i0 + 3 < NN) ? counts[i0 + 3] : 0;
        int s = c0 + c1 + c2 + c3;
        int v = s;
        #pragma unroll
        for (int off = 1; off < 64; off <<= 1) {
            int t = __shfl_up(v, off, 64);
            if (lane >= off) v += t;
        }
        if (lane == 63) wsum[wv] = v;
        int texcl = v - s;
        __syncthreads();
        if (wv == 0) {
            int wval = (lane < 16) ? wsum[lane] : 0;
            #pragma unroll
            for (int off = 1; off < 16; off <<= 1) {
                int t = __shfl_up(wval, off, 64);
                if (lane >= off) wval += t;
            }
            if (lane < 16) woff[lane] = wval - wsum[lane];
            if (lane == 15) s_total = wval;
        }
        __syncthreads();
        int basev = s_carry + woff[wv] + texcl;
        int e0 = basev;
        int e1 = e0 + c0;
        int e2 = e1 + c1;
        int e3 = e2 + c2;
        if (i0 + 0 < NN) { offsets[i0 + 0] = e0; cursor[i0 + 0] = e0; }
        if (i0 + 1 < NN) { offsets[i0 + 1] = e1; cursor[i0 + 1] = e1; }
        if (i0 + 2 < NN) { offsets[i0 + 2] = e2; cursor[i0 + 2] = e2; }
        if (i0 + 3 < NN) { offsets[i0 + 3] = e3; cursor[i0 + 3] = e3; }
        __syncthreads();
        if (tid == 0) s_carry += s_total;
        __syncthreads();
    }
    if (threadIdx.x == 0) offsets[NN] = s_carry;
}

// ---------------- CSR build: fill payload (col, weight) grouped by row ----------------
__global__ __launch_bounds__(256) void k_fill(
    const int* __restrict__ rows, const int* __restrict__ cols,
    const float* __restrict__ ev, int* __restrict__ cursor,
    int2* __restrict__ payload, int E)
{
    int i = blockIdx.x * 256 + threadIdx.x;
    for (; i < E; i += gridDim.x * 256) {
        int r = rows[i];
        int pos = atomicAdd(&cursor[r], 1);
        payload[pos] = make_int2(cols[i], __float_as_int(ev[i]));
    }
}

// ---------------- segment gather-reduce: hnb[r] = sum ev * h2b[c]  (bf16 in/out) ----------------
__global__ __launch_bounds__(256) void k_gather(
    const int* __restrict__ offsets, const int2* __restrict__ payload,
    const unsigned short* __restrict__ h2b, unsigned short* __restrict__ hnb)
{
    const int lane = threadIdx.x & 63;
    const int g = lane >> 4, c0 = lane & 15;
    int w = (blockIdx.x * 256 + threadIdx.x) >> 6;
    const int nw = (gridDim.x * 256) >> 6;
    for (int row = w; row < NN; row += nw) {
        const int b = offsets[row], e = offsets[row + 1];
        float ax = 0.f, ay = 0.f, az = 0.f, aw = 0.f;
        for (int i = b + g; i < e; i += 4) {
            int2 p = payload[i];
            float wt = __int_as_float(p.y);
            const ushort4 v = *(const ushort4*)(h2b + (size_t)p.x * 64 + c0 * 4);
            ax = fmaf(b2f(v.x), wt, ax);
            ay = fmaf(b2f(v.y), wt, ay);
            az = fmaf(b2f(v.z), wt, az);
            aw = fmaf(b2f(v.w), wt, aw);
        }
        ax += __shfl_xor(ax, 16, 64); ax += __shfl_xor(ax, 32, 64);
        ay += __shfl_xor(ay, 16, 64); ay += __shfl_xor(ay, 32, 64);
        az += __shfl_xor(az, 16, 64); az += __shfl_xor(az, 32, 64);
        aw += __shfl_xor(aw, 16, 64); aw += __shfl_xor(aw, 32, 64);
        if (g == 0) {
            ushort4 o;
            o.x = f2bu(ax); o.y = f2bu(ay); o.z = f2bu(az); o.w = f2bu(aw);
            *(ushort4*)(hnb + (size_t)row * 64 + c0 * 4) = o;
        }
    }
}

// ---------------- K/V projection -> bf16 ----------------
__global__ __launch_bounds__(256) void k_proj_kv(
    const float* __restrict__ x,
    const float* __restrict__ Wk, const float* __restrict__ bk,
    const float* __restrict__ Wv, const float* __restrict__ bv,
    unsigned short* __restrict__ Kp, unsigned short* __restrict__ Vp)
{
    __shared__ float sWk[D * D], sWv[D * D];
    __shared__ float sbk[D], sbv[D];
    for (int i = threadIdx.x; i < D * D; i += 256) { sWk[i] = Wk[i]; sWv[i] = Wv[i]; }
    if (threadIdx.x < D) { sbk[threadIdx.x] = bk[threadIdx.x]; sbv[threadIdx.x] = bv[threadIdx.x]; }
    __syncthreads();
    const int lane = threadIdx.x & 63;
    int w = (blockIdx.x * 256 + threadIdx.x) >> 6;
    const int nw = (gridDim.x * 256) >> 6;
    for (int row = w; row < NN; row += nw) {
        float xv = x[row * D + lane];
        float aK = sbk[lane], aV = sbv[lane];
        #pragma unroll
        for (int d = 0; d < D; ++d) {
            float xd = __shfl(xv, d, 64);
            aK = fmaf(xd, sWk[d * D + lane], aK);
            aV = fmaf(xd, sWv[d * D + lane], aV);
        }
        Kp[(size_t)row * D + lane] = f2bu(aK);
        Vp[(size_t)row * D + lane] = f2bu(aV);
    }
}

// ---------------- attention + Wo + residual + LN1 (grouped gathers, bf16 K/V) ----------------
__global__ __launch_bounds__(256) void k_attn(
    const float* __restrict__ x,
    const unsigned short* __restrict__ Kp, const unsigned short* __restrict__ Vp,
    const int* __restrict__ samp,
    const float* __restrict__ Wq, const float* __restrict__ bq,
    const float* __restrict__ Wo, const float* __restrict__ bo,
    const float* __restrict__ g1, const float* __restrict__ be1,
    float* __restrict__ hb)
{
    __shared__ float sWq[D * D], sWo[D * D];
    __shared__ float sbq[D], sbo[D], sg1[D], sbe1[D];
    for (int i = threadIdx.x; i < D * D; i += 256) { sWq[i] = Wq[i]; sWo[i] = Wo[i]; }
    if (threadIdx.x < D) {
        sbq[threadIdx.x] = bq[threadIdx.x]; sbo[threadIdx.x] = bo[threadIdx.x];
        sg1[threadIdx.x] = g1[threadIdx.x]; sbe1[threadIdx.x] = be1[threadIdx.x];
    }
    __syncthreads();
    const int lane = threadIdx.x & 63;
    const int g = lane >> 4, c0 = lane & 15;
    int w = (blockIdx.x * 256 + threadIdx.x) >> 6;
    const int nw = (gridDim.x * 256) >> 6;
    for (int row = w; row < NN; row += nw) {
        float xj = x[row * D + lane];
        int idx_reg = (lane < KS) ? samp[row * KS + lane] : 0;

        // q = x@Wq + bq  (lane j holds q_j)
        float q = sbq[lane];
        #pragma unroll
        for (int d = 0; d < D; ++d)
            q = fmaf(__shfl(xj, d, 64), sWq[d * D + lane], q);
        // repack: lane holds q[4*c0 .. 4*c0+3]
        float q0 = __shfl(q, 4 * c0 + 0, 64);
        float q1 = __shfl(q, 4 * c0 + 1, 64);
        float q2 = __shfl(q, 4 * c0 + 2, 64);
        float q3 = __shfl(q, 4 * c0 + 3, 64);

        // group g handles samples g*5 .. g*5+4; K and V gathered together
        float s[5];
        ushort4 v4[5];
        #pragma unroll
        for (int t = 0; t < 5; ++t) {
            int idx = __shfl(idx_reg, g * 5 + t, 64);
            const ushort4 kk = *(const ushort4*)(Kp + (size_t)idx * D + c0 * 4);
            v4[t] = *(const ushort4*)(Vp + (size_t)idx * D + c0 * 4);
            float sc = q0 * b2f(kk.x);
            sc = fmaf(q1, b2f(kk.y), sc);
            sc = fmaf(q2, b2f(kk.z), sc);
            sc = fmaf(q3, b2f(kk.w), sc);
            sc += __shfl_xor(sc, 1, 64);
            sc += __shfl_xor(sc, 2, 64);
            sc += __shfl_xor(sc, 4, 64);
            sc += __shfl_xor(sc, 8, 64);
            s[t] = sc * 0.25f;   // 1/sqrt(DH=16)
        }
        // softmax over 20 (5 local x 4 groups)
        float m = fmaxf(fmaxf(fmaxf(s[0], s[1]), fmaxf(s[2], s[3])), s[4]);
        m = fmaxf(m, __shfl_xor(m, 16, 64));
        m = fmaxf(m, __shfl_xor(m, 32, 64));
        float o0 = 0.f, o1 = 0.f, o2 = 0.f, o3 = 0.f, ssum = 0.f;
        #pragma unroll
        for (int t = 0; t < 5; ++t) {
            float p = __expf(s[t] - m);
            ssum += p;
            o0 = fmaf(p, b2f(v4[t].x), o0);
            o1 = fmaf(p, b2f(v4[t].y), o1);
            o2 = fmaf(p, b2f(v4[t].z), o2);
            o3 = fmaf(p, b2f(v4[t].w), o3);
        }
        ssum += __shfl_xor(ssum, 16, 64);
        ssum += __shfl_xor(ssum, 32, 64);
        float inv = 1.0f / ssum;
        o0 += __shfl_xor(o0, 16, 64); o0 += __shfl_xor(o0, 32, 64); o0 *= inv;
        o1 += __shfl_xor(o1, 16, 64); o1 += __shfl_xor(o1, 32, 64); o1 *= inv;
        o2 += __shfl_xor(o2, 16, 64); o2 += __shfl_xor(o2, 32, 64); o2 *= inv;
        o3 += __shfl_xor(o3, 16, 64); o3 += __shfl_xor(o3, 32, 64); o3 *= inv;

        // @Wo + bo  (o channel d = dd*4+c lives in lane dd component c)
        float acc = sbo[lane];
        #pragma unroll
        for (int dd = 0; dd < 16; ++dd) {
            float e0 = __shfl(o0, dd, 64);
            float e1 = __shfl(o1, dd, 64);
            float e2 = __shfl(o2, dd, 64);
            float e3 = __shfl(o3, dd, 64);
            acc = fmaf(e0, sWo[(dd * 4 + 0) * D + lane], acc);
            acc = fmaf(e1, sWo[(dd * 4 + 1) * D + lane], acc);
            acc = fmaf(e2, sWo[(dd * 4 + 2) * D + lane], acc);
            acc = fmaf(e3, sWo[(dd * 4 + 3) * D + lane], acc);
        }
        float r = xj + acc;
        float mu = wsum64(r) * (1.f / 64.f);
        float dv = r - mu;
        float var = wsum64(dv * dv) * (1.f / 64.f);
        hb[(size_t)row * D + lane] = dv * rsqrtf(var + EPS) * sg1[lane] + sbe1[lane];
    }
}

// ---------------- FFN via MFMA -> bf16 h2 ----------------
__global__ __launch_bounds__(256) void k_ffn_mfma(
    const float* __restrict__ hb,
    const short* __restrict__ wf,
    const float* __restrict__ bf1, const float* __restrict__ bf2,
    const float* __restrict__ g2, const float* __restrict__ be2,
    unsigned short* __restrict__ h2b)
{
    __shared__ __align__(16) short Tl[4][16][264];
    const int lane = threadIdx.x & 63;
    const int wv   = threadIdx.x >> 6;
    const int c0   = lane & 15;
    const int g    = lane >> 4;
    const bf16x8* w1p = (const bf16x8*)wf;
    const bf16x8* w2p = (const bf16x8*)(wf + 16384);

    float b1v[16];
    #pragma unroll
    for (int nt = 0; nt < 16; ++nt) b1v[nt] = bf1[nt * 16 + c0];
    float b2v[4], g2v[4], bev[4];
    #pragma unroll
    for (int nt = 0; nt < 4; ++nt) {
        b2v[nt] = bf2[nt * 16 + c0];
        g2v[nt] = g2[nt * 16 + c0];
        bev[nt] = be2[nt * 16 + c0];
    }

    int wid = (blockIdx.x * 256 + threadIdx.x) >> 6;
    const int nwaves = (gridDim.x * 256) >> 6;
    for (int tile = wid; tile < NN / 16; tile += nwaves) {
        const int row0 = tile * 16;
        const float* ar = hb + (size_t)(row0 + c0) * D + g * 8;
        bf16x8 a0, a1;
        {
            float4 f0 = *(const float4*)(ar);
            float4 f1 = *(const float4*)(ar + 4);
            float4 f2 = *(const float4*)(ar + 32);
            float4 f3 = *(const float4*)(ar + 36);
            a0[0] = f2b(f0.x); a0[1] = f2b(f0.y); a0[2] = f2b(f0.z); a0[3] = f2b(f0.w);
            a0[4] = f2b(f1.x); a0[5] = f2b(f1.y); a0[6] = f2b(f1.z); a0[7] = f2b(f1.w);
            a1[0] = f2b(f2.x); a1[1] = f2b(f2.y); a1[2] = f2b(f2.z); a1[3] = f2b(f2.w);
            a1[4] = f2b(f3.x); a1[5] = f2b(f3.y); a1[6] = f2b(f3.z); a1[7] = f2b(f3.w);
        }
        f32x4 acc1[16];
        #pragma unroll
        for (int nt = 0; nt < 16; ++nt) {
            float b = b1v[nt];
            f32x4 c = {b, b, b, b};
            c = __builtin_amdgcn_mfma_f32_16x16x32_bf16(a0, w1p[(nt * 2 + 0) * 64 + lane], c, 0, 0, 0);
            c = __builtin_amdgcn_mfma_f32_16x16x32_bf16(a1, w1p[(nt * 2 + 1) * 64 + lane], c, 0, 0, 0);
            acc1[nt] = c;
        }
        #pragma unroll
        for (int nt = 0; nt < 16; ++nt) {
            #pragma unroll
            for (int r = 0; r < 4; ++r)
                Tl[wv][g * 4 + r][nt * 16 + c0] = f2b(fmaxf(acc1[nt][r], 0.f));
        }
        bf16x8 a2[8];
        #pragma unroll
        for (int kt = 0; kt < 8; ++kt)
            a2[kt] = *(const bf16x8*)&Tl[wv][c0][kt * 32 + g * 8];
        f32x4 acc2[4];
        #pragma unroll
        for (int nt = 0; nt < 4; ++nt) {
            float b = b2v[nt];
            f32x4 c = {b, b, b, b};
            #pragma unroll
            for (int kt = 0; kt < 8; ++kt)
                c = __builtin_amdgcn_mfma_f32_16x16x32_bf16(a2[kt], w2p[(nt * 8 + kt) * 64 + lane], c, 0, 0, 0);
            acc2[nt] = c;
        }
        const int r0 = row0 + g * 4;
        #pragma unroll
        for (int r = 0; r < 4; ++r) {
            float rv[4];
            float s = 0.f;
            #pragma unroll
            for (int nt = 0; nt < 4; ++nt) {
                rv[nt] = acc2[nt][r] + hb[(size_t)(r0 + r) * D + nt * 16 + c0];
                s += rv[nt];
            }
            s = gsum16(s);
            float mu = s * (1.f / 64.f);
            float q = 0.f;
            #pragma unroll
            for (int nt = 0; nt < 4; ++nt) { float d = rv[nt] - mu; q += d * d; }
            q = gsum16(q);
            float inv = rsqrtf(q * (1.f / 64.f) + EPS);
            #pragma unroll
            for (int nt = 0; nt < 4; ++nt)
                h2b[(size_t)(r0 + r) * D + nt * 16 + c0] = f2bu((rv[nt] - mu) * inv * g2v[nt] + bev[nt]);
        }
    }
}

// ---------------- GNN linear (MFMA, bf16 inputs) + relu + residual + LN -> fp32 out ----------------
__global__ __launch_bounds__(256) void k_gnn_mfma(
    const unsigned short* __restrict__ h2b, const unsigned short* __restrict__ hnb,
    const short* __restrict__ wgf,
    const float* __restrict__ bg, const float* __restrict__ gg,
    const float* __restrict__ bgn,
    float* __restrict__ out)
{
    const int lane = threadIdx.x & 63;
    const int c0 = lane & 15;
    const int g  = lane >> 4;
    const bf16x8* wp = (const bf16x8*)wgf;

    float bgv[4], ggv[4], bnv[4];
    #pragma unroll
    for (int nt = 0; nt < 4; ++nt) {
        bgv[nt] = bg[nt * 16 + c0];
        ggv[nt] = gg[nt * 16 + c0];
        bnv[nt] = bgn[nt * 16 + c0];
    }

    int wid = (blockIdx.x * 256 + threadIdx.x) >> 6;
    const int nwaves = (gridDim.x * 256) >> 6;
    for (int tile = wid; tile < NN / 16; tile += nwaves) {
        const int row0 = tile * 16;
        bf16x8 a[4];
        #pragma unroll
        for (int kt = 0; kt < 2; ++kt) {
            a[kt]     = *(const bf16x8*)&h2b[(size_t)(row0 + c0) * 64 + kt * 32 + g * 8];
            a[2 + kt] = *(const bf16x8*)&hnb[(size_t)(row0 + c0) * 64 + kt * 32 + g * 8];
        }
        f32x4 acc[4];
        #pragma unroll
        for (int nt = 0; nt < 4; ++nt) {
            float b = bgv[nt];
            f32x4 c = {b, b, b, b};
            #pragma unroll
            for (int kt = 0; kt < 4; ++kt)
                c = __builtin_amdgcn_mfma_f32_16x16x32_bf16(a[kt], wp[(nt * 4 + kt) * 64 + lane], c, 0, 0, 0);
            acc[nt] = c;
        }
        const int r0 = row0 + g * 4;
        #pragma unroll
        for (int r = 0; r < 4; ++r) {
            float rv[4];
            float s = 0.f;
            #pragma unroll
            for (int nt = 0; nt < 4; ++nt) {
                float hn = fmaxf(acc[nt][r], 0.f);
                rv[nt] = hn + b2f(h2b[(size_t)(r0 + r) * 64 + nt * 16 + c0]);
                s += rv[nt];
            }
            s = gsum16(s);
            float mu = s * (1.f / 64.f);
            float q = 0.f;
            #pragma unroll
            for (int nt = 0; nt < 4; ++nt) { float d = rv[nt] - mu; q += d * d; }
            q = gsum16(q);
            float inv = rsqrtf(q * (1.f / 64.f) + EPS);
            #pragma unroll
            for (int nt = 0; nt < 4; ++nt)
                out[(size_t)(r0 + r) * D + nt * 16 + c0] = (rv[nt] - mu) * inv * ggv[nt] + bnv[nt];
        }
    }
}

// ---------------- attention_samples passthrough (as fp32) ----------------
__global__ __launch_bounds__(256) void k_samples(
    const int* __restrict__ samp, float* __restrict__ out, int n)
{
    int i = blockIdx.x * blockDim.x + threadIdx.x;
    const int stride = gridDim.x * blockDim.x;
    for (; i < n; i += stride) out[i] = (float)samp[i];
}

extern "C" void kernel_launch(void* const* d_in, const int* in_sizes, int n_in,
                              void* d_out, int out_size, void* d_ws, size_t ws_size,
                              hipStream_t stream)
{
    const float* x   = (const float*)d_in[0];
    const int*   rows = (const int*)d_in[1];
    const int*   cols = (const int*)d_in[2];
    const float* ev  = (const float*)d_in[3];
    const int*   samp = (const int*)d_in[4];
    const float* Wq  = (const float*)d_in[5];
    const float* bq  = (const float*)d_in[6];
    const float* Wk  = (const float*)d_in[7];
    const float* bk  = (const float*)d_in[8];
    const float* Wv  = (const float*)d_in[9];
    const float* bv  = (const float*)d_in[10];
    const float* Wo  = (const float*)d_in[11];
    const float* bo  = (const float*)d_in[12];
    const float* g1  = (const float*)d_in[13];
    const float* be1 = (const float*)d_in[14];
    const float* g2  = (const float*)d_in[15];
    const float* be2 = (const float*)d_in[16];
    const float* W1  = (const float*)d_in[17];
    const float* bf1 = (const float*)d_in[18];
    const float* W2  = (const float*)d_in[19];
    const float* bf2 = (const float*)d_in[20];
    const float* Wg  = (const float*)d_in[21];
    const float* bg  = (const float*)d_in[22];
    const float* gg  = (const float*)d_in[23];
    const float* bgn = (const float*)d_in[24];
    const int E = in_sizes[1];

    // ws layout: 3 buffers of NN*D floats
    float* buf0 = (float*)d_ws;                   // [Kp_b | Vp_b] bf16 -> payload (int2[E])
    float* buf1 = buf0 + (size_t)NN * D;          // [hnb_b bf16 | h2b bf16]
    float* buf2 = buf1 + (size_t)NN * D;          // hb fp32
    unsigned short* Kp_b = (unsigned short*)buf0;                       // NN*64
    unsigned short* Vp_b = Kp_b + (size_t)NN * D;                       // NN*64
    int2* payload = (int2*)buf0;                                        // E (overwrites Kp/Vp after attn)
    unsigned short* hnb_b = (unsigned short*)buf1;                      // NN*64
    unsigned short* h2b   = (unsigned short*)(buf1 + (size_t)NN * D / 2); // NN*64
    float* hb = buf2;

    float* out = (float*)d_out;
    // scratch in samples region of d_out (rewritten by k_samples each call)
    short* S     = (short*)(out + (size_t)NN * D);   // 40960 shorts
    int* counts  = (int*)(S + 40960);                // NN
    int* offsets = counts + NN;                      // NN+1
    int* cursor  = offsets + NN + 1;                 // NN

    k_prep<<<40, 256, 0, stream>>>(W1, W2, Wg, S);
    hipMemsetAsync(counts, 0, (size_t)NN * sizeof(int), stream);
    k_hist<<<4096, 256, 0, stream>>>(rows, counts, E);
    k_scan<<<1, 1024, 0, stream>>>(counts, offsets, cursor);
    k_proj_kv<<<2048, 256, 0, stream>>>(x, Wk, bk, Wv, bv, Kp_b, Vp_b);
    k_attn<<<4096, 256, 0, stream>>>(x, Kp_b, Vp_b, samp, Wq, bq, Wo, bo, g1, be1, hb);
    k_ffn_mfma<<<1563, 256, 0, stream>>>(hb, S, bf1, bf2, g2, be2, h2b);
    k_fill<<<4096, 256, 0, stream>>>(rows, cols, ev, cursor, payload, E);
    k_gather<<<4096, 256, 0, stream>>>(offsets, payload, h2b, hnb_b);
    k_gnn_mfma<<<1563, 256, 0, stream>>>(h2b, hnb_b, S + 32768, bg, gg, bgn, out);
    k_samples<<<2048, 256, 0, stream>>>(samp, out + (size_t)NN * D, NN * KS);
}

// Round 6
// 805.167 us; speedup vs baseline: 3.4021x; 1.1257x over previous
//
#include <hip/hip_runtime.h>
#include <hip/hip_bf16.h>

#define NN  100000
#define D   64
#define KS  20
#define DFF 256
#define EPS 1e-5f

#define NPASS  8
#define NCHUNK 4096
#define WROWS  (NN / NPASS)

typedef __attribute__((ext_vector_type(8))) short bf16x8;
typedef __attribute__((ext_vector_type(4))) float f32x4;

__device__ __forceinline__ short f2b(float f) {
    return __builtin_bit_cast(short, __float2bfloat16(f));
}
__device__ __forceinline__ unsigned short f2bu(float f) {
    return __builtin_bit_cast(unsigned short, __float2bfloat16(f));
}
__device__ __forceinline__ float b2f(unsigned short u) {
    return __builtin_bit_cast(float, ((unsigned)u) << 16);
}

__device__ __forceinline__ float wsum64(float v) {
    v += __shfl_xor(v, 1, 64);
    v += __shfl_xor(v, 2, 64);
    v += __shfl_xor(v, 4, 64);
    v += __shfl_xor(v, 8, 64);
    v += __shfl_xor(v, 16, 64);
    v += __shfl_xor(v, 32, 64);
    return v;
}
__device__ __forceinline__ float gsum16(float v) {
    v += __shfl_xor(v, 1, 64);
    v += __shfl_xor(v, 2, 64);
    v += __shfl_xor(v, 4, 64);
    v += __shfl_xor(v, 8, 64);
    return v;
}

// ---------------- weight fragment prep (bf16, B-operand layout) ----------------
__global__ __launch_bounds__(256) void k_prep(
    const float* __restrict__ W1, const float* __restrict__ W2,
    const float* __restrict__ Wg, short* __restrict__ S)
{
    int idx = blockIdx.x * 256 + threadIdx.x;
    const int total = 16384 + 16384 + 8192;
    for (; idx < total; idx += gridDim.x * 256) {
        float v;
        if (idx < 16384) {
            int f = idx >> 9, rem = idx & 511;
            int l = rem >> 3, i = rem & 7;
            int nt = f >> 1, kt = f & 1;
            int k = kt * 32 + (l >> 4) * 8 + i;
            int n = nt * 16 + (l & 15);
            v = W1[k * DFF + n];
        } else if (idx < 32768) {
            int j = idx - 16384;
            int f = j >> 9, rem = j & 511;
            int l = rem >> 3, i = rem & 7;
            int nt = f >> 3, kt = f & 7;
            int k = kt * 32 + (l >> 4) * 8 + i;
            int n = nt * 16 + (l & 15);
            v = W2[k * D + n];
        } else {
            int j = idx - 32768;
            int f = j >> 9, rem = j & 511;
            int l = rem >> 3, i = rem & 7;
            int nt = f >> 2, kt = f & 3;
            int k = kt * 32 + (l >> 4) * 8 + i;
            int n = nt * 16 + (l & 15);
            v = Wg[k * D + n];
        }
        S[idx] = f2b(v);
    }
}

// ---------------- CSR build: histogram ----------------
__global__ __launch_bounds__(256) void k_hist(
    const int* __restrict__ rows, int* __restrict__ counts, int E)
{
    int i = blockIdx.x * 256 + threadIdx.x;
    for (; i < E; i += gridDim.x * 256) atomicAdd(&counts[rows[i]], 1);
}

// ---------------- CSR build: single-block exclusive scan ----------------
__global__ __launch_bounds__(1024) void k_scan(
    const int* __restrict__ counts, int* __restrict__ offsets, int* __restrict__ cursor)
{
    __shared__ int wsum[16];
    __shared__ int woff[16];
    __shared__ int s_carry, s_total;
    const int tid = threadIdx.x;
    const int lane = tid & 63;
    const int wv = tid >> 6;
    if (tid == 0) s_carry = 0;
    __syncthreads();
    for (int base = 0; base < NN; base += 4096) {
        int i0 = base + tid * 4;
        int c0 = (i0 + 0 < NN) ? counts[i0 + 0] : 0;
        int c1 = (i0 + 1 < NN) ? counts[i0 + 1] : 0;
        int c2 = (i0 + 2 < NN) ? counts[i0 + 2] : 0;
        int c3 = (i0 + 3 < NN) ? counts[i0 + 3] : 0;
        int s = c0 + c1 + c2 + c3;
        int v = s;
        #pragma unroll
        for (int off = 1; off < 64; off <<= 1) {
            int t = __shfl_up(v, off, 64);
            if (lane >= off) v += t;
        }
        if (lane == 63) wsum[wv] = v;
        int texcl = v - s;
        __syncthreads();
        if (wv == 0) {
            int wval = (lane < 16) ? wsum[lane] : 0;
            #pragma unroll
            for (int off = 1; off < 16; off <<= 1) {
                int t = __shfl_up(wval, off, 64);
                if (lane >= off) wval += t;
            }
            if (lane < 16) woff[lane] = wval - wsum[lane];
            if (lane == 15) s_total = wval;
        }
        __syncthreads();
        int basev = s_carry + woff[wv] + texcl;
        int e0 = basev;
        int e1 = e0 + c0;
        int e2 = e1 + c1;
        int e3 = e2 + c2;
        if (i0 + 0 < NN) { offsets[i0 + 0] = e0; cursor[i0 + 0] = e0; }
        if (i0 + 1 < NN) { offsets[i0 + 1] = e1; cursor[i0 + 1] = e1; }
        if (i0 + 2 < NN) { offsets[i0 + 2] = e2; cursor[i0 + 2] = e2; }
        if (i0 + 3 < NN) { offsets[i0 + 3] = e3; cursor[i0 + 3] = e3; }
        __syncthreads();
        if (tid == 0) s_carry += s_total;
        __syncthreads();
    }
    if (threadIdx.x == 0) offsets[NN] = s_carry;
}

// ---------------- CSR build: L2-windowed binned fill ----------------
// 8 temporal passes over destination-row windows; each pass's payload writes
// land in one contiguous ~3.2 MB slice whose 64B lines are fully written
// while L2-resident -> streaming evictions instead of random-line writes.
__global__ __launch_bounds__(256) void k_fill(
    const int* __restrict__ rows, const int* __restrict__ cols,
    const float* __restrict__ ev, int* __restrict__ cursor,
    int2* __restrict__ payload, int E)
{
    const int pass  = blockIdx.x >> 12;           // / NCHUNK
    const int chunk = blockIdx.x & (NCHUNK - 1);
    const int wlo = pass * WROWS;
    const int whi = wlo + WROWS;
    const int per = (E + NCHUNK - 1) / NCHUNK;
    const int i0 = chunk * per;
    const int i1 = min(E, i0 + per);
    for (int i = i0 + threadIdx.x; i < i1; i += 256) {
        int r = rows[i];
        if (r >= wlo && r < whi) {
            int pos = atomicAdd(&cursor[r], 1);
            payload[pos] = make_int2(cols[i], __float_as_int(ev[i]));
        }
    }
}

// ---------------- segment gather-reduce: hnb[r] = sum ev * h2b[c]  (bf16 in/out) ----------------
__global__ __launch_bounds__(256) void k_gather(
    const int* __restrict__ offsets, const int2* __restrict__ payload,
    const unsigned short* __restrict__ h2b, unsigned short* __restrict__ hnb)
{
    const int lane = threadIdx.x & 63;
    const int g = lane >> 4, c0 = lane & 15;
    int w = (blockIdx.x * 256 + threadIdx.x) >> 6;
    const int nw = (gridDim.x * 256) >> 6;
    for (int row = w; row < NN; row += nw) {
        const int b = offsets[row], e = offsets[row + 1];
        float ax = 0.f, ay = 0.f, az = 0.f, aw = 0.f;
        for (int i = b + g; i < e; i += 4) {
            int2 p = payload[i];
            float wt = __int_as_float(p.y);
            const ushort4 v = *(const ushort4*)(h2b + (size_t)p.x * 64 + c0 * 4);
            ax = fmaf(b2f(v.x), wt, ax);
            ay = fmaf(b2f(v.y), wt, ay);
            az = fmaf(b2f(v.z), wt, az);
            aw = fmaf(b2f(v.w), wt, aw);
        }
        ax += __shfl_xor(ax, 16, 64); ax += __shfl_xor(ax, 32, 64);
        ay += __shfl_xor(ay, 16, 64); ay += __shfl_xor(ay, 32, 64);
        az += __shfl_xor(az, 16, 64); az += __shfl_xor(az, 32, 64);
        aw += __shfl_xor(aw, 16, 64); aw += __shfl_xor(aw, 32, 64);
        if (g == 0) {
            ushort4 o;
            o.x = f2bu(ax); o.y = f2bu(ay); o.z = f2bu(az); o.w = f2bu(aw);
            *(ushort4*)(hnb + (size_t)row * 64 + c0 * 4) = o;
        }
    }
}

// ---------------- K/V projection -> bf16 ----------------
__global__ __launch_bounds__(256) void k_proj_kv(
    const float* __restrict__ x,
    const float* __restrict__ Wk, const float* __restrict__ bk,
    const float* __restrict__ Wv, const float* __restrict__ bv,
    unsigned short* __restrict__ Kp, unsigned short* __restrict__ Vp)
{
    __shared__ float sWk[D * D], sWv[D * D];
    __shared__ float sbk[D], sbv[D];
    for (int i = threadIdx.x; i < D * D; i += 256) { sWk[i] = Wk[i]; sWv[i] = Wv[i]; }
    if (threadIdx.x < D) { sbk[threadIdx.x] = bk[threadIdx.x]; sbv[threadIdx.x] = bv[threadIdx.x]; }
    __syncthreads();
    const int lane = threadIdx.x & 63;
    int w = (blockIdx.x * 256 + threadIdx.x) >> 6;
    const int nw = (gridDim.x * 256) >> 6;
    for (int row = w; row < NN; row += nw) {
        float xv = x[row * D + lane];
        float aK = sbk[lane], aV = sbv[lane];
        #pragma unroll
        for (int d = 0; d < D; ++d) {
            float xd = __shfl(xv, d, 64);
            aK = fmaf(xd, sWk[d * D + lane], aK);
            aV = fmaf(xd, sWv[d * D + lane], aV);
        }
        Kp[(size_t)row * D + lane] = f2bu(aK);
        Vp[(size_t)row * D + lane] = f2bu(aV);
    }
}

// ---------------- attention + Wo + residual + LN1 (grouped gathers, bf16 K/V) ----------------
__global__ __launch_bounds__(256) void k_attn(
    const float* __restrict__ x,
    const unsigned short* __restrict__ Kp, const unsigned short* __restrict__ Vp,
    const int* __restrict__ samp,
    const float* __restrict__ Wq, const float* __restrict__ bq,
    const float* __restrict__ Wo, const float* __restrict__ bo,
    const float* __restrict__ g1, const float* __restrict__ be1,
    float* __restrict__ hb)
{
    __shared__ float sWq[D * D], sWo[D * D];
    __shared__ float sbq[D], sbo[D], sg1[D], sbe1[D];
    for (int i = threadIdx.x; i < D * D; i += 256) { sWq[i] = Wq[i]; sWo[i] = Wo[i]; }
    if (threadIdx.x < D) {
        sbq[threadIdx.x] = bq[threadIdx.x]; sbo[threadIdx.x] = bo[threadIdx.x];
        sg1[threadIdx.x] = g1[threadIdx.x]; sbe1[threadIdx.x] = be1[threadIdx.x];
    }
    __syncthreads();
    const int lane = threadIdx.x & 63;
    const int g = lane >> 4, c0 = lane & 15;
    int w = (blockIdx.x * 256 + threadIdx.x) >> 6;
    const int nw = (gridDim.x * 256) >> 6;
    for (int row = w; row < NN; row += nw) {
        float xj = x[row * D + lane];
        int idx_reg = (lane < KS) ? samp[row * KS + lane] : 0;

        // q = x@Wq + bq  (lane j holds q_j)
        float q = sbq[lane];
        #pragma unroll
        for (int d = 0; d < D; ++d)
            q = fmaf(__shfl(xj, d, 64), sWq[d * D + lane], q);
        // repack: lane holds q[4*c0 .. 4*c0+3]
        float q0 = __shfl(q, 4 * c0 + 0, 64);
        float q1 = __shfl(q, 4 * c0 + 1, 64);
        float q2 = __shfl(q, 4 * c0 + 2, 64);
        float q3 = __shfl(q, 4 * c0 + 3, 64);

        // group g handles samples g*5 .. g*5+4; K and V gathered together
        float s[5];
        ushort4 v4[5];
        #pragma unroll
        for (int t = 0; t < 5; ++t) {
            int idx = __shfl(idx_reg, g * 5 + t, 64);
            const ushort4 kk = *(const ushort4*)(Kp + (size_t)idx * D + c0 * 4);
            v4[t] = *(const ushort4*)(Vp + (size_t)idx * D + c0 * 4);
            float sc = q0 * b2f(kk.x);
            sc = fmaf(q1, b2f(kk.y), sc);
            sc = fmaf(q2, b2f(kk.z), sc);
            sc = fmaf(q3, b2f(kk.w), sc);
            sc += __shfl_xor(sc, 1, 64);
            sc += __shfl_xor(sc, 2, 64);
            sc += __shfl_xor(sc, 4, 64);
            sc += __shfl_xor(sc, 8, 64);
            s[t] = sc * 0.25f;   // 1/sqrt(DH=16)
        }
        // softmax over 20 (5 local x 4 groups)
        float m = fmaxf(fmaxf(fmaxf(s[0], s[1]), fmaxf(s[2], s[3])), s[4]);
        m = fmaxf(m, __shfl_xor(m, 16, 64));
        m = fmaxf(m, __shfl_xor(m, 32, 64));
        float o0 = 0.f, o1 = 0.f, o2 = 0.f, o3 = 0.f, ssum = 0.f;
        #pragma unroll
        for (int t = 0; t < 5; ++t) {
            float p = __expf(s[t] - m);
            ssum += p;
            o0 = fmaf(p, b2f(v4[t].x), o0);
            o1 = fmaf(p, b2f(v4[t].y), o1);
            o2 = fmaf(p, b2f(v4[t].z), o2);
            o3 = fmaf(p, b2f(v4[t].w), o3);
        }
        ssum += __shfl_xor(ssum, 16, 64);
        ssum += __shfl_xor(ssum, 32, 64);
        float inv = 1.0f / ssum;
        o0 += __shfl_xor(o0, 16, 64); o0 += __shfl_xor(o0, 32, 64); o0 *= inv;
        o1 += __shfl_xor(o1, 16, 64); o1 += __shfl_xor(o1, 32, 64); o1 *= inv;
        o2 += __shfl_xor(o2, 16, 64); o2 += __shfl_xor(o2, 32, 64); o2 *= inv;
        o3 += __shfl_xor(o3, 16, 64); o3 += __shfl_xor(o3, 32, 64); o3 *= inv;

        // @Wo + bo  (o channel d = dd*4+c lives in lane dd component c)
        float acc = sbo[lane];
        #pragma unroll
        for (int dd = 0; dd < 16; ++dd) {
            float e0 = __shfl(o0, dd, 64);
            float e1 = __shfl(o1, dd, 64);
            float e2 = __shfl(o2, dd, 64);
            float e3 = __shfl(o3, dd, 64);
            acc = fmaf(e0, sWo[(dd * 4 + 0) * D + lane], acc);
            acc = fmaf(e1, sWo[(dd * 4 + 1) * D + lane], acc);
            acc = fmaf(e2, sWo[(dd * 4 + 2) * D + lane], acc);
            acc = fmaf(e3, sWo[(dd * 4 + 3) * D + lane], acc);
        }
        float r = xj + acc;
        float mu = wsum64(r) * (1.f / 64.f);
        float dv = r - mu;
        float var = wsum64(dv * dv) * (1.f / 64.f);
        hb[(size_t)row * D + lane] = dv * rsqrtf(var + EPS) * sg1[lane] + sbe1[lane];
    }
}

// ---------------- FFN via MFMA -> bf16 h2 ----------------
__global__ __launch_bounds__(256) void k_ffn_mfma(
    const float* __restrict__ hb,
    const short* __restrict__ wf,
    const float* __restrict__ bf1, const float* __restrict__ bf2,
    const float* __restrict__ g2, const float* __restrict__ be2,
    unsigned short* __restrict__ h2b)
{
    __shared__ __align__(16) short Tl[4][16][264];
    const int lane = threadIdx.x & 63;
    const int wv   = threadIdx.x >> 6;
    const int c0   = lane & 15;
    const int g    = lane >> 4;
    const bf16x8* w1p = (const bf16x8*)wf;
    const bf16x8* w2p = (const bf16x8*)(wf + 16384);

    float b1v[16];
    #pragma unroll
    for (int nt = 0; nt < 16; ++nt) b1v[nt] = bf1[nt * 16 + c0];
    float b2v[4], g2v[4], bev[4];
    #pragma unroll
    for (int nt = 0; nt < 4; ++nt) {
        b2v[nt] = bf2[nt * 16 + c0];
        g2v[nt] = g2[nt * 16 + c0];
        bev[nt] = be2[nt * 16 + c0];
    }

    int wid = (blockIdx.x * 256 + threadIdx.x) >> 6;
    const int nwaves = (gridDim.x * 256) >> 6;
    for (int tile = wid; tile < NN / 16; tile += nwaves) {
        const int row0 = tile * 16;
        const float* ar = hb + (size_t)(row0 + c0) * D + g * 8;
        bf16x8 a0, a1;
        {
            float4 f0 = *(const float4*)(ar);
            float4 f1 = *(const float4*)(ar + 4);
            float4 f2 = *(const float4*)(ar + 32);
            float4 f3 = *(const float4*)(ar + 36);
            a0[0] = f2b(f0.x); a0[1] = f2b(f0.y); a0[2] = f2b(f0.z); a0[3] = f2b(f0.w);
            a0[4] = f2b(f1.x); a0[5] = f2b(f1.y); a0[6] = f2b(f1.z); a0[7] = f2b(f1.w);
            a1[0] = f2b(f2.x); a1[1] = f2b(f2.y); a1[2] = f2b(f2.z); a1[3] = f2b(f2.w);
            a1[4] = f2b(f3.x); a1[5] = f2b(f3.y); a1[6] = f2b(f3.z); a1[7] = f2b(f3.w);
        }
        f32x4 acc1[16];
        #pragma unroll
        for (int nt = 0; nt < 16; ++nt) {
            float b = b1v[nt];
            f32x4 c = {b, b, b, b};
            c = __builtin_amdgcn_mfma_f32_16x16x32_bf16(a0, w1p[(nt * 2 + 0) * 64 + lane], c, 0, 0, 0);
            c = __builtin_amdgcn_mfma_f32_16x16x32_bf16(a1, w1p[(nt * 2 + 1) * 64 + lane], c, 0, 0, 0);
            acc1[nt] = c;
        }
        #pragma unroll
        for (int nt = 0; nt < 16; ++nt) {
            #pragma unroll
            for (int r = 0; r < 4; ++r)
                Tl[wv][g * 4 + r][nt * 16 + c0] = f2b(fmaxf(acc1[nt][r], 0.f));
        }
        bf16x8 a2[8];
        #pragma unroll
        for (int kt = 0; kt < 8; ++kt)
            a2[kt] = *(const bf16x8*)&Tl[wv][c0][kt * 32 + g * 8];
        f32x4 acc2[4];
        #pragma unroll
        for (int nt = 0; nt < 4; ++nt) {
            float b = b2v[nt];
            f32x4 c = {b, b, b, b};
            #pragma unroll
            for (int kt = 0; kt < 8; ++kt)
                c = __builtin_amdgcn_mfma_f32_16x16x32_bf16(a2[kt], w2p[(nt * 8 + kt) * 64 + lane], c, 0, 0, 0);
            acc2[nt] = c;
        }
        const int r0 = row0 + g * 4;
        #pragma unroll
        for (int r = 0; r < 4; ++r) {
            float rv[4];
            float s = 0.f;
            #pragma unroll
            for (int nt = 0; nt < 4; ++nt) {
                rv[nt] = acc2[nt][r] + hb[(size_t)(r0 + r) * D + nt * 16 + c0];
                s += rv[nt];
            }
            s = gsum16(s);
            float mu = s * (1.f / 64.f);
            float q = 0.f;
            #pragma unroll
            for (int nt = 0; nt < 4; ++nt) { float d = rv[nt] - mu; q += d * d; }
            q = gsum16(q);
            float inv = rsqrtf(q * (1.f / 64.f) + EPS);
            #pragma unroll
            for (int nt = 0; nt < 4; ++nt)
                h2b[(size_t)(r0 + r) * D + nt * 16 + c0] = f2bu((rv[nt] - mu) * inv * g2v[nt] + bev[nt]);
        }
    }
}

// ---------------- GNN linear (MFMA, bf16 inputs) + relu + residual + LN -> fp32 out ----------------
__global__ __launch_bounds__(256) void k_gnn_mfma(
    const unsigned short* __restrict__ h2b, const unsigned short* __restrict__ hnb,
    const short* __restrict__ wgf,
    const float* __restrict__ bg, const float* __restrict__ gg,
    const float* __restrict__ bgn,
    float* __restrict__ out)
{
    const int lane = threadIdx.x & 63;
    const int c0 = lane & 15;
    const int g  = lane >> 4;
    const bf16x8* wp = (const bf16x8*)wgf;

    float bgv[4], ggv[4], bnv[4];
    #pragma unroll
    for (int nt = 0; nt < 4; ++nt) {
        bgv[nt] = bg[nt * 16 + c0];
        ggv[nt] = gg[nt * 16 + c0];
        bnv[nt] = bgn[nt * 16 + c0];
    }

    int wid = (blockIdx.x * 256 + threadIdx.x) >> 6;
    const int nwaves = (gridDim.x * 256) >> 6;
    for (int tile = wid; tile < NN / 16; tile += nwaves) {
        const int row0 = tile * 16;
        bf16x8 a[4];
        #pragma unroll
        for (int kt = 0; kt < 2; ++kt) {
            a[kt]     = *(const bf16x8*)&h2b[(size_t)(row0 + c0) * 64 + kt * 32 + g * 8];
            a[2 + kt] = *(const bf16x8*)&hnb[(size_t)(row0 + c0) * 64 + kt * 32 + g * 8];
        }
        f32x4 acc[4];
        #pragma unroll
        for (int nt = 0; nt < 4; ++nt) {
            float b = bgv[nt];
            f32x4 c = {b, b, b, b};
            #pragma unroll
            for (int kt = 0; kt < 4; ++kt)
                c = __builtin_amdgcn_mfma_f32_16x16x32_bf16(a[kt], wp[(nt * 4 + kt) * 64 + lane], c, 0, 0, 0);
            acc[nt] = c;
        }
        const int r0 = row0 + g * 4;
        #pragma unroll
        for (int r = 0; r < 4; ++r) {
            float rv[4];
            float s = 0.f;
            #pragma unroll
            for (int nt = 0; nt < 4; ++nt) {
                float hn = fmaxf(acc[nt][r], 0.f);
                rv[nt] = hn + b2f(h2b[(size_t)(r0 + r) * 64 + nt * 16 + c0]);
                s += rv[nt];
            }
            s = gsum16(s);
            float mu = s * (1.f / 64.f);
            float q = 0.f;
            #pragma unroll
            for (int nt = 0; nt < 4; ++nt) { float d = rv[nt] - mu; q += d * d; }
            q = gsum16(q);
            float inv = rsqrtf(q * (1.f / 64.f) + EPS);
            #pragma unroll
            for (int nt = 0; nt < 4; ++nt)
                out[(size_t)(r0 + r) * D + nt * 16 + c0] = (rv[nt] - mu) * inv * ggv[nt] + bnv[nt];
        }
    }
}

// ---------------- attention_samples passthrough (as fp32) ----------------
__global__ __launch_bounds__(256) void k_samples(
    const int* __restrict__ samp, float* __restrict__ out, int n)
{
    int i = blockIdx.x * blockDim.x + threadIdx.x;
    const int stride = gridDim.x * blockDim.x;
    for (; i < n; i += stride) out[i] = (float)samp[i];
}

extern "C" void kernel_launch(void* const* d_in, const int* in_sizes, int n_in,
                              void* d_out, int out_size, void* d_ws, size_t ws_size,
                              hipStream_t stream)
{
    const float* x   = (const float*)d_in[0];
    const int*   rows = (const int*)d_in[1];
    const int*   cols = (const int*)d_in[2];
    const float* ev  = (const float*)d_in[3];
    const int*   samp = (const int*)d_in[4];
    const float* Wq  = (const float*)d_in[5];
    const float* bq  = (const float*)d_in[6];
    const float* Wk  = (const float*)d_in[7];
    const float* bk  = (const float*)d_in[8];
    const float* Wv  = (const float*)d_in[9];
    const float* bv  = (const float*)d_in[10];
    const float* Wo  = (const float*)d_in[11];
    const float* bo  = (const float*)d_in[12];
    const float* g1  = (const float*)d_in[13];
    const float* be1 = (const float*)d_in[14];
    const float* g2  = (const float*)d_in[15];
    const float* be2 = (const float*)d_in[16];
    const float* W1  = (const float*)d_in[17];
    const float* bf1 = (const float*)d_in[18];
    const float* W2  = (const float*)d_in[19];
    const float* bf2 = (const float*)d_in[20];
    const float* Wg  = (const float*)d_in[21];
    const float* bg  = (const float*)d_in[22];
    const float* gg  = (const float*)d_in[23];
    const float* bgn = (const float*)d_in[24];
    const int E = in_sizes[1];

    // ws layout: 3 buffers of NN*D floats
    float* buf0 = (float*)d_ws;                   // [Kp_b | Vp_b] bf16 -> payload (int2[E])
    float* buf1 = buf0 + (size_t)NN * D;          // [hnb_b bf16 | h2b bf16]
    float* buf2 = buf1 + (size_t)NN * D;          // hb fp32
    unsigned short* Kp_b = (unsigned short*)buf0;                       // NN*64
    unsigned short* Vp_b = Kp_b + (size_t)NN * D;                       // NN*64
    int2* payload = (int2*)buf0;                                        // E (overwrites Kp/Vp after attn)
    unsigned short* hnb_b = (unsigned short*)buf1;                      // NN*64
    unsigned short* h2b   = (unsigned short*)(buf1 + (size_t)NN * D / 2); // NN*64
    float* hb = buf2;

    float* out = (float*)d_out;
    // scratch in samples region of d_out (rewritten by k_samples each call)
    short* S     = (short*)(out + (size_t)NN * D);   // 40960 shorts
    int* counts  = (int*)(S + 40960);                // NN
    int* offsets = counts + NN;                      // NN+1
    int* cursor  = offsets + NN + 1;                 // NN

    k_prep<<<40, 256, 0, stream>>>(W1, W2, Wg, S);
    hipMemsetAsync(counts, 0, (size_t)NN * sizeof(int), stream);
    k_hist<<<4096, 256, 0, stream>>>(rows, counts, E);
    k_scan<<<1, 1024, 0, stream>>>(counts, offsets, cursor);
    k_proj_kv<<<2048, 256, 0, stream>>>(x, Wk, bk, Wv, bv, Kp_b, Vp_b);
    k_attn<<<4096, 256, 0, stream>>>(x, Kp_b, Vp_b, samp, Wq, bq, Wo, bo, g1, be1, hb);
    k_ffn_mfma<<<1563, 256, 0, stream>>>(hb, S, bf1, bf2, g2, be2, h2b);
    k_fill<<<NPASS * NCHUNK, 256, 0, stream>>>(rows, cols, ev, cursor, payload, E);
    k_gather<<<4096, 256, 0, stream>>>(offsets, payload, h2b, hnb_b);
    k_gnn_mfma<<<1563, 256, 0, stream>>>(h2b, hnb_b, S + 32768, bg, gg, bgn, out);
    k_samples<<<2048, 256, 0, stream>>>(samp, out + (size_t)NN * D, NN * KS);
}

// Round 7
// 569.618 us; speedup vs baseline: 4.8089x; 1.4135x over previous
//
#include <hip/hip_runtime.h>
#include <hip/hip_bf16.h>

#define NN  100000
#define D   64
#define KS  20
#define DFF 256
#define EPS 1e-5f

#define NPASS  8
#define NCHUNK 4096
#define WROWS  (NN / NPASS)

// frag-buffer offsets (shorts)
#define OFF_W1 0
#define OFF_W2 16384
#define OFF_WG 32768
#define OFF_WQ 40960
#define OFF_WK 45056
#define OFF_WV 49152
#define OFF_WO 53248
#define S_TOTAL 57344

typedef __attribute__((ext_vector_type(8))) short bf16x8;
typedef __attribute__((ext_vector_type(4))) float f32x4;

__device__ __forceinline__ short f2b(float f) {
    return __builtin_bit_cast(short, __float2bfloat16(f));
}
__device__ __forceinline__ unsigned short f2bu(float f) {
    return __builtin_bit_cast(unsigned short, __float2bfloat16(f));
}
__device__ __forceinline__ float b2f(unsigned short u) {
    return __builtin_bit_cast(float, ((unsigned)u) << 16);
}
__device__ __forceinline__ float gsum16(float v) {
    v += __shfl_xor(v, 1, 64);
    v += __shfl_xor(v, 2, 64);
    v += __shfl_xor(v, 4, 64);
    v += __shfl_xor(v, 8, 64);
    return v;
}

// ---------------- weight fragment prep (bf16, B-operand layout) ----------------
// B-frag: lane l, elem i -> B[k][n], n = nt*16 + (l&15), k = kt*32 + (l>>4)*8 + i
__global__ __launch_bounds__(256) void k_prep(
    const float* __restrict__ W1, const float* __restrict__ W2,
    const float* __restrict__ Wg,
    const float* __restrict__ Wq, const float* __restrict__ Wk,
    const float* __restrict__ Wv, const float* __restrict__ Wo,
    short* __restrict__ S)
{
    int idx = blockIdx.x * 256 + threadIdx.x;
    for (; idx < S_TOTAL; idx += gridDim.x * 256) {
        float v;
        if (idx < OFF_W2) {                 // W1 [64 x 256]
            int f = idx >> 9, rem = idx & 511;
            int l = rem >> 3, i = rem & 7;
            int nt = f >> 1, kt = f & 1;
            v = W1[(kt * 32 + (l >> 4) * 8 + i) * DFF + nt * 16 + (l & 15)];
        } else if (idx < OFF_WG) {          // W2 [256 x 64]
            int j = idx - OFF_W2;
            int f = j >> 9, rem = j & 511;
            int l = rem >> 3, i = rem & 7;
            int nt = f >> 3, kt = f & 7;
            v = W2[(kt * 32 + (l >> 4) * 8 + i) * D + nt * 16 + (l & 15)];
        } else if (idx < OFF_WQ) {          // Wg [128 x 64]
            int j = idx - OFF_WG;
            int f = j >> 9, rem = j & 511;
            int l = rem >> 3, i = rem & 7;
            int nt = f >> 2, kt = f & 3;
            v = Wg[(kt * 32 + (l >> 4) * 8 + i) * D + nt * 16 + (l & 15)];
        } else {                            // Wq/Wk/Wv/Wo [64 x 64]
            int j = idx - OFF_WQ;
            const float* W = (j < 4096) ? Wq : (j < 8192) ? Wk : (j < 12288) ? Wv : Wo;
            j &= 4095;
            int f = j >> 9, rem = j & 511;
            int l = rem >> 3, i = rem & 7;
            int nt = f >> 1, kt = f & 1;
            v = W[(kt * 32 + (l >> 4) * 8 + i) * D + nt * 16 + (l & 15)];
        }
        S[idx] = f2b(v);
    }
}

// ---------------- CSR build: histogram ----------------
__global__ __launch_bounds__(256) void k_hist(
    const int* __restrict__ rows, int* __restrict__ counts, int E)
{
    int i = blockIdx.x * 256 + threadIdx.x;
    for (; i < E; i += gridDim.x * 256) atomicAdd(&counts[rows[i]], 1);
}

// ---------------- CSR build: single-block exclusive scan ----------------
__global__ __launch_bounds__(1024) void k_scan(
    const int* __restrict__ counts, int* __restrict__ offsets, int* __restrict__ cursor)
{
    __shared__ int wsum[16];
    __shared__ int woff[16];
    __shared__ int s_carry, s_total;
    const int tid = threadIdx.x;
    const int lane = tid & 63;
    const int wv = tid >> 6;
    if (tid == 0) s_carry = 0;
    __syncthreads();
    for (int base = 0; base < NN; base += 4096) {
        int i0 = base + tid * 4;
        int c0 = (i0 + 0 < NN) ? counts[i0 + 0] : 0;
        int c1 = (i0 + 1 < NN) ? counts[i0 + 1] : 0;
        int c2 = (i0 + 2 < NN) ? counts[i0 + 2] : 0;
        int c3 = (i0 + 3 < NN) ? counts[i0 + 3] : 0;
        int s = c0 + c1 + c2 + c3;
        int v = s;
        #pragma unroll
        for (int off = 1; off < 64; off <<= 1) {
            int t = __shfl_up(v, off, 64);
            if (lane >= off) v += t;
        }
        if (lane == 63) wsum[wv] = v;
        int texcl = v - s;
        __syncthreads();
        if (wv == 0) {
            int wval = (lane < 16) ? wsum[lane] : 0;
            #pragma unroll
            for (int off = 1; off < 16; off <<= 1) {
                int t = __shfl_up(wval, off, 64);
                if (lane >= off) wval += t;
            }
            if (lane < 16) woff[lane] = wval - wsum[lane];
            if (lane == 15) s_total = wval;
        }
        __syncthreads();
        int basev = s_carry + woff[wv] + texcl;
        int e0 = basev;
        int e1 = e0 + c0;
        int e2 = e1 + c1;
        int e3 = e2 + c2;
        if (i0 + 0 < NN) { offsets[i0 + 0] = e0; cursor[i0 + 0] = e0; }
        if (i0 + 1 < NN) { offsets[i0 + 1] = e1; cursor[i0 + 1] = e1; }
        if (i0 + 2 < NN) { offsets[i0 + 2] = e2; cursor[i0 + 2] = e2; }
        if (i0 + 3 < NN) { offsets[i0 + 3] = e3; cursor[i0 + 3] = e3; }
        __syncthreads();
        if (tid == 0) s_carry += s_total;
        __syncthreads();
    }
    if (threadIdx.x == 0) offsets[NN] = s_carry;
}

// ---------------- CSR build: L2-windowed binned fill ----------------
__global__ __launch_bounds__(256) void k_fill(
    const int* __restrict__ rows, const int* __restrict__ cols,
    const float* __restrict__ ev, int* __restrict__ cursor,
    int2* __restrict__ payload, int E)
{
    const int pass  = blockIdx.x >> 12;
    const int chunk = blockIdx.x & (NCHUNK - 1);
    const int wlo = pass * WROWS;
    const int whi = wlo + WROWS;
    const int per = (E + NCHUNK - 1) / NCHUNK;
    const int i0 = chunk * per;
    const int i1 = min(E, i0 + per);
    for (int i = i0 + threadIdx.x; i < i1; i += 256) {
        int r = rows[i];
        if (r >= wlo && r < whi) {
            int pos = atomicAdd(&cursor[r], 1);
            payload[pos] = make_int2(cols[i], __float_as_int(ev[i]));
        }
    }
}

// ---------------- segment gather-reduce (2-deep pipelined) ----------------
__global__ __launch_bounds__(256) void k_gather(
    const int* __restrict__ offsets, const int2* __restrict__ payload,
    const unsigned short* __restrict__ h2b, unsigned short* __restrict__ hnb)
{
    const int lane = threadIdx.x & 63;
    const int g = lane >> 4, c0 = lane & 15;
    int w = (blockIdx.x * 256 + threadIdx.x) >> 6;
    const int nw = (gridDim.x * 256) >> 6;
    for (int row = w; row < NN; row += nw) {
        const int b = offsets[row], e = offsets[row + 1];
        float ax = 0.f, ay = 0.f, az = 0.f, aw = 0.f;
        int i = b + g;
        for (; i + 4 < e; i += 8) {
            int2 p0 = payload[i];
            int2 p1 = payload[i + 4];
            float w0 = __int_as_float(p0.y);
            float w1 = __int_as_float(p1.y);
            const ushort4 u0 = *(const ushort4*)(h2b + (size_t)p0.x * 64 + c0 * 4);
            const ushort4 u1 = *(const ushort4*)(h2b + (size_t)p1.x * 64 + c0 * 4);
            ax = fmaf(b2f(u0.x), w0, ax); ay = fmaf(b2f(u0.y), w0, ay);
            az = fmaf(b2f(u0.z), w0, az); aw = fmaf(b2f(u0.w), w0, aw);
            ax = fmaf(b2f(u1.x), w1, ax); ay = fmaf(b2f(u1.y), w1, ay);
            az = fmaf(b2f(u1.z), w1, az); aw = fmaf(b2f(u1.w), w1, aw);
        }
        if (i < e) {
            int2 p = payload[i];
            float wt = __int_as_float(p.y);
            const ushort4 u = *(const ushort4*)(h2b + (size_t)p.x * 64 + c0 * 4);
            ax = fmaf(b2f(u.x), wt, ax); ay = fmaf(b2f(u.y), wt, ay);
            az = fmaf(b2f(u.z), wt, az); aw = fmaf(b2f(u.w), wt, aw);
        }
        ax += __shfl_xor(ax, 16, 64); ax += __shfl_xor(ax, 32, 64);
        ay += __shfl_xor(ay, 16, 64); ay += __shfl_xor(ay, 32, 64);
        az += __shfl_xor(az, 16, 64); az += __shfl_xor(az, 32, 64);
        aw += __shfl_xor(aw, 16, 64); aw += __shfl_xor(aw, 32, 64);
        if (g == 0) {
            ushort4 o;
            o.x = f2bu(ax); o.y = f2bu(ay); o.z = f2bu(az); o.w = f2bu(aw);
            *(ushort4*)(hnb + (size_t)row * 64 + c0 * 4) = o;
        }
    }
}

// ---------------- Q/K/V projection via MFMA -> bf16 ----------------
__global__ __launch_bounds__(256) void k_projqkv_mfma(
    const float* __restrict__ x, const short* __restrict__ S,
    const float* __restrict__ bq, const float* __restrict__ bk,
    const float* __restrict__ bv,
    unsigned short* __restrict__ Qp, unsigned short* __restrict__ Kp,
    unsigned short* __restrict__ Vp)
{
    const int lane = threadIdx.x & 63;
    const int c0 = lane & 15;
    const int g  = lane >> 4;
    const bf16x8* wq = (const bf16x8*)(S + OFF_WQ);
    const bf16x8* wk = (const bf16x8*)(S + OFF_WK);
    const bf16x8* wv = (const bf16x8*)(S + OFF_WV);

    float bqv[4], bkv[4], bvv[4];
    #pragma unroll
    for (int nt = 0; nt < 4; ++nt) {
        bqv[nt] = bq[nt * 16 + c0];
        bkv[nt] = bk[nt * 16 + c0];
        bvv[nt] = bv[nt * 16 + c0];
    }

    int wid = (blockIdx.x * 256 + threadIdx.x) >> 6;
    const int nwaves = (gridDim.x * 256) >> 6;
    for (int tile = wid; tile < NN / 16; tile += nwaves) {
        const int row0 = tile * 16;
        const float* ar = x + (size_t)(row0 + c0) * D + g * 8;
        bf16x8 a0, a1;
        {
            float4 f0 = *(const float4*)(ar);
            float4 f1 = *(const float4*)(ar + 4);
            float4 f2 = *(const float4*)(ar + 32);
            float4 f3 = *(const float4*)(ar + 36);
            a0[0] = f2b(f0.x); a0[1] = f2b(f0.y); a0[2] = f2b(f0.z); a0[3] = f2b(f0.w);
            a0[4] = f2b(f1.x); a0[5] = f2b(f1.y); a0[6] = f2b(f1.z); a0[7] = f2b(f1.w);
            a1[0] = f2b(f2.x); a1[1] = f2b(f2.y); a1[2] = f2b(f2.z); a1[3] = f2b(f2.w);
            a1[4] = f2b(f3.x); a1[5] = f2b(f3.y); a1[6] = f2b(f3.z); a1[7] = f2b(f3.w);
        }
        f32x4 aq[4], ak[4], av[4];
        #pragma unroll
        for (int nt = 0; nt < 4; ++nt) {
            f32x4 cq = {bqv[nt], bqv[nt], bqv[nt], bqv[nt]};
            cq = __builtin_amdgcn_mfma_f32_16x16x32_bf16(a0, wq[(nt * 2 + 0) * 64 + lane], cq, 0, 0, 0);
            cq = __builtin_amdgcn_mfma_f32_16x16x32_bf16(a1, wq[(nt * 2 + 1) * 64 + lane], cq, 0, 0, 0);
            aq[nt] = cq;
            f32x4 ck = {bkv[nt], bkv[nt], bkv[nt], bkv[nt]};
            ck = __builtin_amdgcn_mfma_f32_16x16x32_bf16(a0, wk[(nt * 2 + 0) * 64 + lane], ck, 0, 0, 0);
            ck = __builtin_amdgcn_mfma_f32_16x16x32_bf16(a1, wk[(nt * 2 + 1) * 64 + lane], ck, 0, 0, 0);
            ak[nt] = ck;
            f32x4 cv = {bvv[nt], bvv[nt], bvv[nt], bvv[nt]};
            cv = __builtin_amdgcn_mfma_f32_16x16x32_bf16(a0, wv[(nt * 2 + 0) * 64 + lane], cv, 0, 0, 0);
            cv = __builtin_amdgcn_mfma_f32_16x16x32_bf16(a1, wv[(nt * 2 + 1) * 64 + lane], cv, 0, 0, 0);
            av[nt] = cv;
        }
        const int r0 = row0 + g * 4;
        #pragma unroll
        for (int r = 0; r < 4; ++r) {
            #pragma unroll
            for (int nt = 0; nt < 4; ++nt) {
                Qp[(size_t)(r0 + r) * D + nt * 16 + c0] = f2bu(aq[nt][r]);
                Kp[(size_t)(r0 + r) * D + nt * 16 + c0] = f2bu(ak[nt][r]);
                Vp[(size_t)(r0 + r) * D + nt * 16 + c0] = f2bu(av[nt][r]);
            }
        }
    }
}

// ---------------- attention core: gathers + per-head softmax + PV -> ob (bf16) ----------------
__global__ __launch_bounds__(256) void k_attn_lite(
    const unsigned short* __restrict__ Qp,
    const unsigned short* __restrict__ Kp, const unsigned short* __restrict__ Vp,
    const int* __restrict__ samp, unsigned short* __restrict__ ob)
{
    const int lane = threadIdx.x & 63;
    const int g = lane >> 4, c0 = lane & 15;
    int w = (blockIdx.x * 256 + threadIdx.x) >> 6;
    const int nw = (gridDim.x * 256) >> 6;
    for (int row = w; row < NN; row += nw) {
        int idx_reg = (lane < KS) ? samp[row * KS + lane] : 0;
        const ushort4 qv = *(const ushort4*)(Qp + (size_t)row * D + c0 * 4);
        float q0 = b2f(qv.x), q1 = b2f(qv.y), q2 = b2f(qv.z), q3 = b2f(qv.w);

        // group g handles samples g*5 .. g*5+4
        float s[5];
        ushort4 v4[5];
        #pragma unroll
        for (int t = 0; t < 5; ++t) {
            int idx = __shfl(idx_reg, g * 5 + t, 64);
            const ushort4 kk = *(const ushort4*)(Kp + (size_t)idx * D + c0 * 4);
            v4[t] = *(const ushort4*)(Vp + (size_t)idx * D + c0 * 4);
            float sc = q0 * b2f(kk.x);
            sc = fmaf(q1, b2f(kk.y), sc);
            sc = fmaf(q2, b2f(kk.z), sc);
            sc = fmaf(q3, b2f(kk.w), sc);
            // per-head dot: head = c0>>2 spans lanes (c0&~3)..(c0|3)
            sc += __shfl_xor(sc, 1, 64);
            sc += __shfl_xor(sc, 2, 64);
            s[t] = sc * 0.25f;   // 1/sqrt(DH=16)
        }
        // per-head softmax over 20 samples (5 local x 4 groups; xor16/32 keep c0 => within-head)
        float m = fmaxf(fmaxf(fmaxf(s[0], s[1]), fmaxf(s[2], s[3])), s[4]);
        m = fmaxf(m, __shfl_xor(m, 16, 64));
        m = fmaxf(m, __shfl_xor(m, 32, 64));
        float o0 = 0.f, o1 = 0.f, o2 = 0.f, o3 = 0.f, ssum = 0.f;
        #pragma unroll
        for (int t = 0; t < 5; ++t) {
            float p = __expf(s[t] - m);
            ssum += p;
            o0 = fmaf(p, b2f(v4[t].x), o0);
            o1 = fmaf(p, b2f(v4[t].y), o1);
            o2 = fmaf(p, b2f(v4[t].z), o2);
            o3 = fmaf(p, b2f(v4[t].w), o3);
        }
        ssum += __shfl_xor(ssum, 16, 64);
        ssum += __shfl_xor(ssum, 32, 64);
        float inv = 1.0f / ssum;
        o0 += __shfl_xor(o0, 16, 64); o0 += __shfl_xor(o0, 32, 64);
        o1 += __shfl_xor(o1, 16, 64); o1 += __shfl_xor(o1, 32, 64);
        o2 += __shfl_xor(o2, 16, 64); o2 += __shfl_xor(o2, 32, 64);
        o3 += __shfl_xor(o3, 16, 64); o3 += __shfl_xor(o3, 32, 64);
        if (g == 0) {
            ushort4 o;
            o.x = f2bu(o0 * inv); o.y = f2bu(o1 * inv);
            o.z = f2bu(o2 * inv); o.w = f2bu(o3 * inv);
            *(ushort4*)(ob + (size_t)row * D + c0 * 4) = o;
        }
    }
}

// ---------------- Wo projection + residual + LN1 via MFMA -> hb fp32 ----------------
__global__ __launch_bounds__(256) void k_attno_mfma(
    const unsigned short* __restrict__ ob, const float* __restrict__ x,
    const short* __restrict__ S,
    const float* __restrict__ bo, const float* __restrict__ g1,
    const float* __restrict__ be1,
    float* __restrict__ hb)
{
    const int lane = threadIdx.x & 63;
    const int c0 = lane & 15;
    const int g  = lane >> 4;
    const bf16x8* wp = (const bf16x8*)(S + OFF_WO);

    float bov[4], g1v[4], b1v[4];
    #pragma unroll
    for (int nt = 0; nt < 4; ++nt) {
        bov[nt] = bo[nt * 16 + c0];
        g1v[nt] = g1[nt * 16 + c0];
        b1v[nt] = be1[nt * 16 + c0];
    }

    int wid = (blockIdx.x * 256 + threadIdx.x) >> 6;
    const int nwaves = (gridDim.x * 256) >> 6;
    for (int tile = wid; tile < NN / 16; tile += nwaves) {
        const int row0 = tile * 16;
        bf16x8 a[2];
        #pragma unroll
        for (int kt = 0; kt < 2; ++kt)
            a[kt] = *(const bf16x8*)&ob[(size_t)(row0 + c0) * D + kt * 32 + g * 8];
        f32x4 acc[4];
        #pragma unroll
        for (int nt = 0; nt < 4; ++nt) {
            f32x4 c = {bov[nt], bov[nt], bov[nt], bov[nt]};
            #pragma unroll
            for (int kt = 0; kt < 2; ++kt)
                c = __builtin_amdgcn_mfma_f32_16x16x32_bf16(a[kt], wp[(nt * 2 + kt) * 64 + lane], c, 0, 0, 0);
            acc[nt] = c;
        }
        const int r0 = row0 + g * 4;
        #pragma unroll
        for (int r = 0; r < 4; ++r) {
            float rv[4];
            float s = 0.f;
            #pragma unroll
            for (int nt = 0; nt < 4; ++nt) {
                rv[nt] = acc[nt][r] + x[(size_t)(r0 + r) * D + nt * 16 + c0];
                s += rv[nt];
            }
            s = gsum16(s);
            float mu = s * (1.f / 64.f);
            float q = 0.f;
            #pragma unroll
            for (int nt = 0; nt < 4; ++nt) { float d = rv[nt] - mu; q += d * d; }
            q = gsum16(q);
            float inv = rsqrtf(q * (1.f / 64.f) + EPS);
            #pragma unroll
            for (int nt = 0; nt < 4; ++nt)
                hb[(size_t)(r0 + r) * D + nt * 16 + c0] = (rv[nt] - mu) * inv * g1v[nt] + b1v[nt];
        }
    }
}

// ---------------- FFN via MFMA -> bf16 h2 ----------------
__global__ __launch_bounds__(256) void k_ffn_mfma(
    const float* __restrict__ hb,
    const short* __restrict__ wf,
    const float* __restrict__ bf1, const float* __restrict__ bf2,
    const float* __restrict__ g2, const float* __restrict__ be2,
    unsigned short* __restrict__ h2b)
{
    __shared__ __align__(16) short Tl[4][16][264];
    const int lane = threadIdx.x & 63;
    const int wv   = threadIdx.x >> 6;
    const int c0   = lane & 15;
    const int g    = lane >> 4;
    const bf16x8* w1p = (const bf16x8*)(wf + OFF_W1);
    const bf16x8* w2p = (const bf16x8*)(wf + OFF_W2);

    float b1v[16];
    #pragma unroll
    for (int nt = 0; nt < 16; ++nt) b1v[nt] = bf1[nt * 16 + c0];
    float b2v[4], g2v[4], bev[4];
    #pragma unroll
    for (int nt = 0; nt < 4; ++nt) {
        b2v[nt] = bf2[nt * 16 + c0];
        g2v[nt] = g2[nt * 16 + c0];
        bev[nt] = be2[nt * 16 + c0];
    }

    int wid = (blockIdx.x * 256 + threadIdx.x) >> 6;
    const int nwaves = (gridDim.x * 256) >> 6;
    for (int tile = wid; tile < NN / 16; tile += nwaves) {
        const int row0 = tile * 16;
        const float* ar = hb + (size_t)(row0 + c0) * D + g * 8;
        bf16x8 a0, a1;
        {
            float4 f0 = *(const float4*)(ar);
            float4 f1 = *(const float4*)(ar + 4);
            float4 f2 = *(const float4*)(ar + 32);
            float4 f3 = *(const float4*)(ar + 36);
            a0[0] = f2b(f0.x); a0[1] = f2b(f0.y); a0[2] = f2b(f0.z); a0[3] = f2b(f0.w);
            a0[4] = f2b(f1.x); a0[5] = f2b(f1.y); a0[6] = f2b(f1.z); a0[7] = f2b(f1.w);
            a1[0] = f2b(f2.x); a1[1] = f2b(f2.y); a1[2] = f2b(f2.z); a1[3] = f2b(f2.w);
            a1[4] = f2b(f3.x); a1[5] = f2b(f3.y); a1[6] = f2b(f3.z); a1[7] = f2b(f3.w);
        }
        f32x4 acc1[16];
        #pragma unroll
        for (int nt = 0; nt < 16; ++nt) {
            float b = b1v[nt];
            f32x4 c = {b, b, b, b};
            c = __builtin_amdgcn_mfma_f32_16x16x32_bf16(a0, w1p[(nt * 2 + 0) * 64 + lane], c, 0, 0, 0);
            c = __builtin_amdgcn_mfma_f32_16x16x32_bf16(a1, w1p[(nt * 2 + 1) * 64 + lane], c, 0, 0, 0);
            acc1[nt] = c;
        }
        #pragma unroll
        for (int nt = 0; nt < 16; ++nt) {
            #pragma unroll
            for (int r = 0; r < 4; ++r)
                Tl[wv][g * 4 + r][nt * 16 + c0] = f2b(fmaxf(acc1[nt][r], 0.f));
        }
        bf16x8 a2[8];
        #pragma unroll
        for (int kt = 0; kt < 8; ++kt)
            a2[kt] = *(const bf16x8*)&Tl[wv][c0][kt * 32 + g * 8];
        f32x4 acc2[4];
        #pragma unroll
        for (int nt = 0; nt < 4; ++nt) {
            float b = b2v[nt];
            f32x4 c = {b, b, b, b};
            #pragma unroll
            for (int kt = 0; kt < 8; ++kt)
                c = __builtin_amdgcn_mfma_f32_16x16x32_bf16(a2[kt], w2p[(nt * 8 + kt) * 64 + lane], c, 0, 0, 0);
            acc2[nt] = c;
        }
        const int r0 = row0 + g * 4;
        #pragma unroll
        for (int r = 0; r < 4; ++r) {
            float rv[4];
            float s = 0.f;
            #pragma unroll
            for (int nt = 0; nt < 4; ++nt) {
                rv[nt] = acc2[nt][r] + hb[(size_t)(r0 + r) * D + nt * 16 + c0];
                s += rv[nt];
            }
            s = gsum16(s);
            float mu = s * (1.f / 64.f);
            float q = 0.f;
            #pragma unroll
            for (int nt = 0; nt < 4; ++nt) { float d = rv[nt] - mu; q += d * d; }
            q = gsum16(q);
            float inv = rsqrtf(q * (1.f / 64.f) + EPS);
            #pragma unroll
            for (int nt = 0; nt < 4; ++nt)
                h2b[(size_t)(r0 + r) * D + nt * 16 + c0] = f2bu((rv[nt] - mu) * inv * g2v[nt] + bev[nt]);
        }
    }
}

// ---------------- GNN linear (MFMA, bf16 inputs) + relu + residual + LN -> fp32 out ----------------
__global__ __launch_bounds__(256) void k_gnn_mfma(
    const unsigned short* __restrict__ h2b, const unsigned short* __restrict__ hnb,
    const short* __restrict__ S,
    const float* __restrict__ bg, const float* __restrict__ gg,
    const float* __restrict__ bgn,
    float* __restrict__ out)
{
    const int lane = threadIdx.x & 63;
    const int c0 = lane & 15;
    const int g  = lane >> 4;
    const bf16x8* wp = (const bf16x8*)(S + OFF_WG);

    float bgv[4], ggv[4], bnv[4];
    #pragma unroll
    for (int nt = 0; nt < 4; ++nt) {
        bgv[nt] = bg[nt * 16 + c0];
        ggv[nt] = gg[nt * 16 + c0];
        bnv[nt] = bgn[nt * 16 + c0];
    }

    int wid = (blockIdx.x * 256 + threadIdx.x) >> 6;
    const int nwaves = (gridDim.x * 256) >> 6;
    for (int tile = wid; tile < NN / 16; tile += nwaves) {
        const int row0 = tile * 16;
        bf16x8 a[4];
        #pragma unroll
        for (int kt = 0; kt < 2; ++kt) {
            a[kt]     = *(const bf16x8*)&h2b[(size_t)(row0 + c0) * 64 + kt * 32 + g * 8];
            a[2 + kt] = *(const bf16x8*)&hnb[(size_t)(row0 + c0) * 64 + kt * 32 + g * 8];
        }
        f32x4 acc[4];
        #pragma unroll
        for (int nt = 0; nt < 4; ++nt) {
            float b = bgv[nt];
            f32x4 c = {b, b, b, b};
            #pragma unroll
            for (int kt = 0; kt < 4; ++kt)
                c = __builtin_amdgcn_mfma_f32_16x16x32_bf16(a[kt], wp[(nt * 4 + kt) * 64 + lane], c, 0, 0, 0);
            acc[nt] = c;
        }
        const int r0 = row0 + g * 4;
        #pragma unroll
        for (int r = 0; r < 4; ++r) {
            float rv[4];
            float s = 0.f;
            #pragma unroll
            for (int nt = 0; nt < 4; ++nt) {
                float hn = fmaxf(acc[nt][r], 0.f);
                rv[nt] = hn + b2f(h2b[(size_t)(r0 + r) * 64 + nt * 16 + c0]);
                s += rv[nt];
            }
            s = gsum16(s);
            float mu = s * (1.f / 64.f);
            float q = 0.f;
            #pragma unroll
            for (int nt = 0; nt < 4; ++nt) { float d = rv[nt] - mu; q += d * d; }
            q = gsum16(q);
            float inv = rsqrtf(q * (1.f / 64.f) + EPS);
            #pragma unroll
            for (int nt = 0; nt < 4; ++nt)
                out[(size_t)(r0 + r) * D + nt * 16 + c0] = (rv[nt] - mu) * inv * ggv[nt] + bnv[nt];
        }
    }
}

// ---------------- attention_samples passthrough (as fp32) ----------------
__global__ __launch_bounds__(256) void k_samples(
    const int* __restrict__ samp, float* __restrict__ out, int n)
{
    int i = blockIdx.x * blockDim.x + threadIdx.x;
    const int stride = gridDim.x * blockDim.x;
    for (; i < n; i += stride) out[i] = (float)samp[i];
}

extern "C" void kernel_launch(void* const* d_in, const int* in_sizes, int n_in,
                              void* d_out, int out_size, void* d_ws, size_t ws_size,
                              hipStream_t stream)
{
    const float* x   = (const float*)d_in[0];
    const int*   rows = (const int*)d_in[1];
    const int*   cols = (const int*)d_in[2];
    const float* ev  = (const float*)d_in[3];
    const int*   samp = (const int*)d_in[4];
    const float* Wq  = (const float*)d_in[5];
    const float* bq  = (const float*)d_in[6];
    const float* Wk  = (const float*)d_in[7];
    const float* bk  = (const float*)d_in[8];
    const float* Wv  = (const float*)d_in[9];
    const float* bv  = (const float*)d_in[10];
    const float* Wo  = (const float*)d_in[11];
    const float* bo  = (const float*)d_in[12];
    const float* g1  = (const float*)d_in[13];
    const float* be1 = (const float*)d_in[14];
    const float* g2  = (const float*)d_in[15];
    const float* be2 = (const float*)d_in[16];
    const float* W1  = (const float*)d_in[17];
    const float* bf1 = (const float*)d_in[18];
    const float* W2  = (const float*)d_in[19];
    const float* bf2 = (const float*)d_in[20];
    const float* Wg  = (const float*)d_in[21];
    const float* bg  = (const float*)d_in[22];
    const float* gg  = (const float*)d_in[23];
    const float* bgn = (const float*)d_in[24];
    const int E = in_sizes[1];

    // ws layout: 3 buffers of NN*D floats (76.8 MB)
    float* buf0 = (float*)d_ws;                   // [Kp_b | Vp_b] bf16 -> payload (int2[E])
    float* buf1 = buf0 + (size_t)NN * D;          // [Qp_b -> hnb_b | ob -> h2b] bf16
    float* buf2 = buf1 + (size_t)NN * D;          // hb fp32
    unsigned short* Kp_b = (unsigned short*)buf0;
    unsigned short* Vp_b = Kp_b + (size_t)NN * D;
    int2* payload = (int2*)buf0;                       // overwrites Kp/Vp after attn
    unsigned short* Qp_b  = (unsigned short*)buf1;     // dead after attn -> hnb slot
    unsigned short* hnb_b = (unsigned short*)buf1;
    unsigned short* ob    = (unsigned short*)(buf1 + (size_t)NN * D / 2); // dead after attno -> h2b slot
    unsigned short* h2b   = ob;
    float* hb = buf2;

    float* out = (float*)d_out;
    // scratch in samples region of d_out (rewritten by k_samples each call)
    short* S     = (short*)(out + (size_t)NN * D);   // S_TOTAL shorts
    int* counts  = (int*)(S + S_TOTAL);              // NN
    int* offsets = counts + NN;                      // NN+1
    int* cursor  = offsets + NN + 1;                 // NN

    k_prep<<<56, 256, 0, stream>>>(W1, W2, Wg, Wq, Wk, Wv, Wo, S);
    hipMemsetAsync(counts, 0, (size_t)NN * sizeof(int), stream);
    k_hist<<<4096, 256, 0, stream>>>(rows, counts, E);
    k_scan<<<1, 1024, 0, stream>>>(counts, offsets, cursor);
    k_projqkv_mfma<<<1563, 256, 0, stream>>>(x, S, bq, bk, bv, Qp_b, Kp_b, Vp_b);
    k_attn_lite<<<4096, 256, 0, stream>>>(Qp_b, Kp_b, Vp_b, samp, ob);
    k_attno_mfma<<<1563, 256, 0, stream>>>(ob, x, S, bo, g1, be1, hb);
    k_ffn_mfma<<<1563, 256, 0, stream>>>(hb, S, bf1, bf2, g2, be2, h2b);
    k_fill<<<NPASS * NCHUNK, 256, 0, stream>>>(rows, cols, ev, cursor, payload, E);
    k_gather<<<4096, 256, 0, stream>>>(offsets, payload, h2b, hnb_b);
    k_gnn_mfma<<<1563, 256, 0, stream>>>(h2b, hnb_b, S, bg, gg, bgn, out);
    k_samples<<<2048, 256, 0, stream>>>(samp, out + (size_t)NN * D, NN * KS);
}

// Round 8
// 547.405 us; speedup vs baseline: 5.0041x; 1.0406x over previous
//
#include <hip/hip_runtime.h>
#include <hip/hip_bf16.h>

#define NN  100000
#define D   64
#define KS  20
#define DFF 256
#define EPS 1e-5f

#define NPASS  8
#define NCHUNK 4096
#define WROWS  (NN / NPASS)

// frag-buffer offsets (shorts)
#define OFF_W1 0
#define OFF_W2 16384
#define OFF_WG 32768
#define OFF_WQ 40960
#define OFF_WK 45056
#define OFF_WV 49152
#define OFF_WO 53248
#define S_TOTAL 57344

typedef __attribute__((ext_vector_type(8))) short bf16x8;
typedef __attribute__((ext_vector_type(4))) float f32x4;

__device__ __forceinline__ short f2b(float f) {
    return __builtin_bit_cast(short, __float2bfloat16(f));
}
__device__ __forceinline__ unsigned short f2bu(float f) {
    return __builtin_bit_cast(unsigned short, __float2bfloat16(f));
}
__device__ __forceinline__ float b2f(unsigned short u) {
    return __builtin_bit_cast(float, ((unsigned)u) << 16);
}
__device__ __forceinline__ float gsum16(float v) {
    v += __shfl_xor(v, 1, 64);
    v += __shfl_xor(v, 2, 64);
    v += __shfl_xor(v, 4, 64);
    v += __shfl_xor(v, 8, 64);
    return v;
}

// ---------------- weight fragment prep (bf16, B-operand layout) ----------------
// B-frag: lane l, elem i -> B[k][n], n = nt*16 + (l&15), k = kt*32 + (l>>4)*8 + i
__global__ __launch_bounds__(256) void k_prep(
    const float* __restrict__ W1, const float* __restrict__ W2,
    const float* __restrict__ Wg,
    const float* __restrict__ Wq, const float* __restrict__ Wk,
    const float* __restrict__ Wv, const float* __restrict__ Wo,
    short* __restrict__ S)
{
    int idx = blockIdx.x * 256 + threadIdx.x;
    for (; idx < S_TOTAL; idx += gridDim.x * 256) {
        float v;
        if (idx < OFF_W2) {                 // W1 [64 x 256]
            int f = idx >> 9, rem = idx & 511;
            int l = rem >> 3, i = rem & 7;
            int nt = f >> 1, kt = f & 1;
            v = W1[(kt * 32 + (l >> 4) * 8 + i) * DFF + nt * 16 + (l & 15)];
        } else if (idx < OFF_WG) {          // W2 [256 x 64]
            int j = idx - OFF_W2;
            int f = j >> 9, rem = j & 511;
            int l = rem >> 3, i = rem & 7;
            int nt = f >> 3, kt = f & 7;
            v = W2[(kt * 32 + (l >> 4) * 8 + i) * D + nt * 16 + (l & 15)];
        } else if (idx < OFF_WQ) {          // Wg [128 x 64]
            int j = idx - OFF_WG;
            int f = j >> 9, rem = j & 511;
            int l = rem >> 3, i = rem & 7;
            int nt = f >> 2, kt = f & 3;
            v = Wg[(kt * 32 + (l >> 4) * 8 + i) * D + nt * 16 + (l & 15)];
        } else {                            // Wq/Wk/Wv/Wo [64 x 64]
            int j = idx - OFF_WQ;
            const float* W = (j < 4096) ? Wq : (j < 8192) ? Wk : (j < 12288) ? Wv : Wo;
            j &= 4095;
            int f = j >> 9, rem = j & 511;
            int l = rem >> 3, i = rem & 7;
            int nt = f >> 1, kt = f & 1;
            v = W[(kt * 32 + (l >> 4) * 8 + i) * D + nt * 16 + (l & 15)];
        }
        S[idx] = f2b(v);
    }
}

// ---------------- CSR build: histogram ----------------
__global__ __launch_bounds__(256) void k_hist(
    const int* __restrict__ rows, int* __restrict__ counts, int E)
{
    int i = blockIdx.x * 256 + threadIdx.x;
    for (; i < E; i += gridDim.x * 256) atomicAdd(&counts[rows[i]], 1);
}

// ---------------- CSR build: single-block exclusive scan ----------------
__global__ __launch_bounds__(1024) void k_scan(
    const int* __restrict__ counts, int* __restrict__ offsets, int* __restrict__ cursor)
{
    __shared__ int wsum[16];
    __shared__ int woff[16];
    __shared__ int s_carry, s_total;
    const int tid = threadIdx.x;
    const int lane = tid & 63;
    const int wv = tid >> 6;
    if (tid == 0) s_carry = 0;
    __syncthreads();
    for (int base = 0; base < NN; base += 4096) {
        int i0 = base + tid * 4;
        int c0 = (i0 + 0 < NN) ? counts[i0 + 0] : 0;
        int c1 = (i0 + 1 < NN) ? counts[i0 + 1] : 0;
        int c2 = (i0 + 2 < NN) ? counts[i0 + 2] : 0;
        int c3 = (i0 + 3 < NN) ? counts[i0 + 3] : 0;
        int s = c0 + c1 + c2 + c3;
        int v = s;
        #pragma unroll
        for (int off = 1; off < 64; off <<= 1) {
            int t = __shfl_up(v, off, 64);
            if (lane >= off) v += t;
        }
        if (lane == 63) wsum[wv] = v;
        int texcl = v - s;
        __syncthreads();
        if (wv == 0) {
            int wval = (lane < 16) ? wsum[lane] : 0;
            #pragma unroll
            for (int off = 1; off < 16; off <<= 1) {
                int t = __shfl_up(wval, off, 64);
                if (lane >= off) wval += t;
            }
            if (lane < 16) woff[lane] = wval - wsum[lane];
            if (lane == 15) s_total = wval;
        }
        __syncthreads();
        int basev = s_carry + woff[wv] + texcl;
        int e0 = basev;
        int e1 = e0 + c0;
        int e2 = e1 + c1;
        int e3 = e2 + c2;
        if (i0 + 0 < NN) { offsets[i0 + 0] = e0; cursor[i0 + 0] = e0; }
        if (i0 + 1 < NN) { offsets[i0 + 1] = e1; cursor[i0 + 1] = e1; }
        if (i0 + 2 < NN) { offsets[i0 + 2] = e2; cursor[i0 + 2] = e2; }
        if (i0 + 3 < NN) { offsets[i0 + 3] = e3; cursor[i0 + 3] = e3; }
        __syncthreads();
        if (tid == 0) s_carry += s_total;
        __syncthreads();
    }
    if (threadIdx.x == 0) offsets[NN] = s_carry;
}

// ---------------- CSR build: XCD-owned windowed fill ----------------
// pass = blockIdx & 7 == XCD id under round-robin dispatch: all writes to
// window p's payload slice come from XCD p's L2 only -> each 64B line
// accumulates in ONE cache and evicts once, full. Non-temporal loads keep
// the per-pass edge stream from thrashing the 3.2MB payload slice.
__global__ __launch_bounds__(256) void k_fill(
    const int* __restrict__ rows, const int* __restrict__ cols,
    const float* __restrict__ ev, int* __restrict__ cursor,
    int2* __restrict__ payload, int E)
{
    const int pass  = blockIdx.x & (NPASS - 1);   // == XCD id (heuristic, perf-only)
    const int chunk = blockIdx.x >> 3;
    const int wlo = pass * WROWS;
    const int whi = wlo + WROWS;
    const int per = (E + NCHUNK - 1) / NCHUNK;
    const int i0 = chunk * per;
    const int i1 = min(E, i0 + per);
    for (int i = i0 + threadIdx.x; i < i1; i += 256) {
        int r = __builtin_nontemporal_load(rows + i);
        if (r >= wlo && r < whi) {
            int c = __builtin_nontemporal_load(cols + i);
            float wt = __builtin_nontemporal_load(ev + i);
            int pos = atomicAdd(&cursor[r], 1);
            payload[pos] = make_int2(c, __float_as_int(wt));
        }
    }
}

// ---------------- segment gather-reduce (2-deep pipelined) ----------------
__global__ __launch_bounds__(256) void k_gather(
    const int* __restrict__ offsets, const int2* __restrict__ payload,
    const unsigned short* __restrict__ h2b, unsigned short* __restrict__ hnb)
{
    const int lane = threadIdx.x & 63;
    const int g = lane >> 4, c0 = lane & 15;
    int w = (blockIdx.x * 256 + threadIdx.x) >> 6;
    const int nw = (gridDim.x * 256) >> 6;
    for (int row = w; row < NN; row += nw) {
        const int b = offsets[row], e = offsets[row + 1];
        float ax = 0.f, ay = 0.f, az = 0.f, aw = 0.f;
        int i = b + g;
        for (; i + 4 < e; i += 8) {
            int2 p0 = payload[i];
            int2 p1 = payload[i + 4];
            float w0 = __int_as_float(p0.y);
            float w1 = __int_as_float(p1.y);
            const ushort4 u0 = *(const ushort4*)(h2b + (size_t)p0.x * 64 + c0 * 4);
            const ushort4 u1 = *(const ushort4*)(h2b + (size_t)p1.x * 64 + c0 * 4);
            ax = fmaf(b2f(u0.x), w0, ax); ay = fmaf(b2f(u0.y), w0, ay);
            az = fmaf(b2f(u0.z), w0, az); aw = fmaf(b2f(u0.w), w0, aw);
            ax = fmaf(b2f(u1.x), w1, ax); ay = fmaf(b2f(u1.y), w1, ay);
            az = fmaf(b2f(u1.z), w1, az); aw = fmaf(b2f(u1.w), w1, aw);
        }
        if (i < e) {
            int2 p = payload[i];
            float wt = __int_as_float(p.y);
            const ushort4 u = *(const ushort4*)(h2b + (size_t)p.x * 64 + c0 * 4);
            ax = fmaf(b2f(u.x), wt, ax); ay = fmaf(b2f(u.y), wt, ay);
            az = fmaf(b2f(u.z), wt, az); aw = fmaf(b2f(u.w), wt, aw);
        }
        ax += __shfl_xor(ax, 16, 64); ax += __shfl_xor(ax, 32, 64);
        ay += __shfl_xor(ay, 16, 64); ay += __shfl_xor(ay, 32, 64);
        az += __shfl_xor(az, 16, 64); az += __shfl_xor(az, 32, 64);
        aw += __shfl_xor(aw, 16, 64); aw += __shfl_xor(aw, 32, 64);
        if (g == 0) {
            ushort4 o;
            o.x = f2bu(ax); o.y = f2bu(ay); o.z = f2bu(az); o.w = f2bu(aw);
            *(ushort4*)(hnb + (size_t)row * 64 + c0 * 4) = o;
        }
    }
}

// ---------------- Q/K/V projection via MFMA -> bf16 ----------------
__global__ __launch_bounds__(256) void k_projqkv_mfma(
    const float* __restrict__ x, const short* __restrict__ S,
    const float* __restrict__ bq, const float* __restrict__ bk,
    const float* __restrict__ bv,
    unsigned short* __restrict__ Qp, unsigned short* __restrict__ Kp,
    unsigned short* __restrict__ Vp)
{
    const int lane = threadIdx.x & 63;
    const int c0 = lane & 15;
    const int g  = lane >> 4;
    const bf16x8* wq = (const bf16x8*)(S + OFF_WQ);
    const bf16x8* wk = (const bf16x8*)(S + OFF_WK);
    const bf16x8* wv = (const bf16x8*)(S + OFF_WV);

    float bqv[4], bkv[4], bvv[4];
    #pragma unroll
    for (int nt = 0; nt < 4; ++nt) {
        bqv[nt] = bq[nt * 16 + c0];
        bkv[nt] = bk[nt * 16 + c0];
        bvv[nt] = bv[nt * 16 + c0];
    }

    int wid = (blockIdx.x * 256 + threadIdx.x) >> 6;
    const int nwaves = (gridDim.x * 256) >> 6;
    for (int tile = wid; tile < NN / 16; tile += nwaves) {
        const int row0 = tile * 16;
        const float* ar = x + (size_t)(row0 + c0) * D + g * 8;
        bf16x8 a0, a1;
        {
            float4 f0 = *(const float4*)(ar);
            float4 f1 = *(const float4*)(ar + 4);
            float4 f2 = *(const float4*)(ar + 32);
            float4 f3 = *(const float4*)(ar + 36);
            a0[0] = f2b(f0.x); a0[1] = f2b(f0.y); a0[2] = f2b(f0.z); a0[3] = f2b(f0.w);
            a0[4] = f2b(f1.x); a0[5] = f2b(f1.y); a0[6] = f2b(f1.z); a0[7] = f2b(f1.w);
            a1[0] = f2b(f2.x); a1[1] = f2b(f2.y); a1[2] = f2b(f2.z); a1[3] = f2b(f2.w);
            a1[4] = f2b(f3.x); a1[5] = f2b(f3.y); a1[6] = f2b(f3.z); a1[7] = f2b(f3.w);
        }
        f32x4 aq[4], ak[4], av[4];
        #pragma unroll
        for (int nt = 0; nt < 4; ++nt) {
            f32x4 cq = {bqv[nt], bqv[nt], bqv[nt], bqv[nt]};
            cq = __builtin_amdgcn_mfma_f32_16x16x32_bf16(a0, wq[(nt * 2 + 0) * 64 + lane], cq, 0, 0, 0);
            cq = __builtin_amdgcn_mfma_f32_16x16x32_bf16(a1, wq[(nt * 2 + 1) * 64 + lane], cq, 0, 0, 0);
            aq[nt] = cq;
            f32x4 ck = {bkv[nt], bkv[nt], bkv[nt], bkv[nt]};
            ck = __builtin_amdgcn_mfma_f32_16x16x32_bf16(a0, wk[(nt * 2 + 0) * 64 + lane], ck, 0, 0, 0);
            ck = __builtin_amdgcn_mfma_f32_16x16x32_bf16(a1, wk[(nt * 2 + 1) * 64 + lane], ck, 0, 0, 0);
            ak[nt] = ck;
            f32x4 cv = {bvv[nt], bvv[nt], bvv[nt], bvv[nt]};
            cv = __builtin_amdgcn_mfma_f32_16x16x32_bf16(a0, wv[(nt * 2 + 0) * 64 + lane], cv, 0, 0, 0);
            cv = __builtin_amdgcn_mfma_f32_16x16x32_bf16(a1, wv[(nt * 2 + 1) * 64 + lane], cv, 0, 0, 0);
            av[nt] = cv;
        }
        const int r0 = row0 + g * 4;
        #pragma unroll
        for (int r = 0; r < 4; ++r) {
            #pragma unroll
            for (int nt = 0; nt < 4; ++nt) {
                Qp[(size_t)(r0 + r) * D + nt * 16 + c0] = f2bu(aq[nt][r]);
                Kp[(size_t)(r0 + r) * D + nt * 16 + c0] = f2bu(ak[nt][r]);
                Vp[(size_t)(r0 + r) * D + nt * 16 + c0] = f2bu(av[nt][r]);
            }
        }
    }
}

// ---------------- attention core: gathers + per-head softmax + PV -> ob (bf16) ----------------
__global__ __launch_bounds__(256) void k_attn_lite(
    const unsigned short* __restrict__ Qp,
    const unsigned short* __restrict__ Kp, const unsigned short* __restrict__ Vp,
    const int* __restrict__ samp, unsigned short* __restrict__ ob)
{
    const int lane = threadIdx.x & 63;
    const int g = lane >> 4, c0 = lane & 15;
    int w = (blockIdx.x * 256 + threadIdx.x) >> 6;
    const int nw = (gridDim.x * 256) >> 6;
    for (int row = w; row < NN; row += nw) {
        int idx_reg = (lane < KS) ? samp[row * KS + lane] : 0;
        const ushort4 qv = *(const ushort4*)(Qp + (size_t)row * D + c0 * 4);
        float q0 = b2f(qv.x), q1 = b2f(qv.y), q2 = b2f(qv.z), q3 = b2f(qv.w);

        // group g handles samples g*5 .. g*5+4
        float s[5];
        ushort4 v4[5];
        #pragma unroll
        for (int t = 0; t < 5; ++t) {
            int idx = __shfl(idx_reg, g * 5 + t, 64);
            const ushort4 kk = *(const ushort4*)(Kp + (size_t)idx * D + c0 * 4);
            v4[t] = *(const ushort4*)(Vp + (size_t)idx * D + c0 * 4);
            float sc = q0 * b2f(kk.x);
            sc = fmaf(q1, b2f(kk.y), sc);
            sc = fmaf(q2, b2f(kk.z), sc);
            sc = fmaf(q3, b2f(kk.w), sc);
            // per-head dot: head = c0>>2 spans lanes (c0&~3)..(c0|3)
            sc += __shfl_xor(sc, 1, 64);
            sc += __shfl_xor(sc, 2, 64);
            s[t] = sc * 0.25f;   // 1/sqrt(DH=16)
        }
        // per-head softmax over 20 samples (5 local x 4 groups; xor16/32 keep c0 => within-head)
        float m = fmaxf(fmaxf(fmaxf(s[0], s[1]), fmaxf(s[2], s[3])), s[4]);
        m = fmaxf(m, __shfl_xor(m, 16, 64));
        m = fmaxf(m, __shfl_xor(m, 32, 64));
        float o0 = 0.f, o1 = 0.f, o2 = 0.f, o3 = 0.f, ssum = 0.f;
        #pragma unroll
        for (int t = 0; t < 5; ++t) {
            float p = __expf(s[t] - m);
            ssum += p;
            o0 = fmaf(p, b2f(v4[t].x), o0);
            o1 = fmaf(p, b2f(v4[t].y), o1);
            o2 = fmaf(p, b2f(v4[t].z), o2);
            o3 = fmaf(p, b2f(v4[t].w), o3);
        }
        ssum += __shfl_xor(ssum, 16, 64);
        ssum += __shfl_xor(ssum, 32, 64);
        float inv = 1.0f / ssum;
        o0 += __shfl_xor(o0, 16, 64); o0 += __shfl_xor(o0, 32, 64);
        o1 += __shfl_xor(o1, 16, 64); o1 += __shfl_xor(o1, 32, 64);
        o2 += __shfl_xor(o2, 16, 64); o2 += __shfl_xor(o2, 32, 64);
        o3 += __shfl_xor(o3, 16, 64); o3 += __shfl_xor(o3, 32, 64);
        if (g == 0) {
            ushort4 o;
            o.x = f2bu(o0 * inv); o.y = f2bu(o1 * inv);
            o.z = f2bu(o2 * inv); o.w = f2bu(o3 * inv);
            *(ushort4*)(ob + (size_t)row * D + c0 * 4) = o;
        }
    }
}

// ---------------- Wo projection + residual + LN1 via MFMA -> hb fp32 ----------------
__global__ __launch_bounds__(256) void k_attno_mfma(
    const unsigned short* __restrict__ ob, const float* __restrict__ x,
    const short* __restrict__ S,
    const float* __restrict__ bo, const float* __restrict__ g1,
    const float* __restrict__ be1,
    float* __restrict__ hb)
{
    const int lane = threadIdx.x & 63;
    const int c0 = lane & 15;
    const int g  = lane >> 4;
    const bf16x8* wp = (const bf16x8*)(S + OFF_WO);

    float bov[4], g1v[4], b1v[4];
    #pragma unroll
    for (int nt = 0; nt < 4; ++nt) {
        bov[nt] = bo[nt * 16 + c0];
        g1v[nt] = g1[nt * 16 + c0];
        b1v[nt] = be1[nt * 16 + c0];
    }

    int wid = (blockIdx.x * 256 + threadIdx.x) >> 6;
    const int nwaves = (gridDim.x * 256) >> 6;
    for (int tile = wid; tile < NN / 16; tile += nwaves) {
        const int row0 = tile * 16;
        bf16x8 a[2];
        #pragma unroll
        for (int kt = 0; kt < 2; ++kt)
            a[kt] = *(const bf16x8*)&ob[(size_t)(row0 + c0) * D + kt * 32 + g * 8];
        f32x4 acc[4];
        #pragma unroll
        for (int nt = 0; nt < 4; ++nt) {
            f32x4 c = {bov[nt], bov[nt], bov[nt], bov[nt]};
            #pragma unroll
            for (int kt = 0; kt < 2; ++kt)
                c = __builtin_amdgcn_mfma_f32_16x16x32_bf16(a[kt], wp[(nt * 2 + kt) * 64 + lane], c, 0, 0, 0);
            acc[nt] = c;
        }
        const int r0 = row0 + g * 4;
        #pragma unroll
        for (int r = 0; r < 4; ++r) {
            float rv[4];
            float s = 0.f;
            #pragma unroll
            for (int nt = 0; nt < 4; ++nt) {
                rv[nt] = acc[nt][r] + x[(size_t)(r0 + r) * D + nt * 16 + c0];
                s += rv[nt];
            }
            s = gsum16(s);
            float mu = s * (1.f / 64.f);
            float q = 0.f;
            #pragma unroll
            for (int nt = 0; nt < 4; ++nt) { float d = rv[nt] - mu; q += d * d; }
            q = gsum16(q);
            float inv = rsqrtf(q * (1.f / 64.f) + EPS);
            #pragma unroll
            for (int nt = 0; nt < 4; ++nt)
                hb[(size_t)(r0 + r) * D + nt * 16 + c0] = (rv[nt] - mu) * inv * g1v[nt] + b1v[nt];
        }
    }
}

// ---------------- FFN via MFMA -> bf16 h2 ----------------
__global__ __launch_bounds__(256) void k_ffn_mfma(
    const float* __restrict__ hb,
    const short* __restrict__ wf,
    const float* __restrict__ bf1, const float* __restrict__ bf2,
    const float* __restrict__ g2, const float* __restrict__ be2,
    unsigned short* __restrict__ h2b)
{
    __shared__ __align__(16) short Tl[4][16][264];
    const int lane = threadIdx.x & 63;
    const int wv   = threadIdx.x >> 6;
    const int c0   = lane & 15;
    const int g    = lane >> 4;
    const bf16x8* w1p = (const bf16x8*)(wf + OFF_W1);
    const bf16x8* w2p = (const bf16x8*)(wf + OFF_W2);

    float b1v[16];
    #pragma unroll
    for (int nt = 0; nt < 16; ++nt) b1v[nt] = bf1[nt * 16 + c0];
    float b2v[4], g2v[4], bev[4];
    #pragma unroll
    for (int nt = 0; nt < 4; ++nt) {
        b2v[nt] = bf2[nt * 16 + c0];
        g2v[nt] = g2[nt * 16 + c0];
        bev[nt] = be2[nt * 16 + c0];
    }

    int wid = (blockIdx.x * 256 + threadIdx.x) >> 6;
    const int nwaves = (gridDim.x * 256) >> 6;
    for (int tile = wid; tile < NN / 16; tile += nwaves) {
        const int row0 = tile * 16;
        const float* ar = hb + (size_t)(row0 + c0) * D + g * 8;
        bf16x8 a0, a1;
        {
            float4 f0 = *(const float4*)(ar);
            float4 f1 = *(const float4*)(ar + 4);
            float4 f2 = *(const float4*)(ar + 32);
            float4 f3 = *(const float4*)(ar + 36);
            a0[0] = f2b(f0.x); a0[1] = f2b(f0.y); a0[2] = f2b(f0.z); a0[3] = f2b(f0.w);
            a0[4] = f2b(f1.x); a0[5] = f2b(f1.y); a0[6] = f2b(f1.z); a0[7] = f2b(f1.w);
            a1[0] = f2b(f2.x); a1[1] = f2b(f2.y); a1[2] = f2b(f2.z); a1[3] = f2b(f2.w);
            a1[4] = f2b(f3.x); a1[5] = f2b(f3.y); a1[6] = f2b(f3.z); a1[7] = f2b(f3.w);
        }
        f32x4 acc1[16];
        #pragma unroll
        for (int nt = 0; nt < 16; ++nt) {
            float b = b1v[nt];
            f32x4 c = {b, b, b, b};
            c = __builtin_amdgcn_mfma_f32_16x16x32_bf16(a0, w1p[(nt * 2 + 0) * 64 + lane], c, 0, 0, 0);
            c = __builtin_amdgcn_mfma_f32_16x16x32_bf16(a1, w1p[(nt * 2 + 1) * 64 + lane], c, 0, 0, 0);
            acc1[nt] = c;
        }
        #pragma unroll
        for (int nt = 0; nt < 16; ++nt) {
            #pragma unroll
            for (int r = 0; r < 4; ++r)
                Tl[wv][g * 4 + r][nt * 16 + c0] = f2b(fmaxf(acc1[nt][r], 0.f));
        }
        bf16x8 a2[8];
        #pragma unroll
        for (int kt = 0; kt < 8; ++kt)
            a2[kt] = *(const bf16x8*)&Tl[wv][c0][kt * 32 + g * 8];
        f32x4 acc2[4];
        #pragma unroll
        for (int nt = 0; nt < 4; ++nt) {
            float b = b2v[nt];
            f32x4 c = {b, b, b, b};
            #pragma unroll
            for (int kt = 0; kt < 8; ++kt)
                c = __builtin_amdgcn_mfma_f32_16x16x32_bf16(a2[kt], w2p[(nt * 8 + kt) * 64 + lane], c, 0, 0, 0);
            acc2[nt] = c;
        }
        const int r0 = row0 + g * 4;
        #pragma unroll
        for (int r = 0; r < 4; ++r) {
            float rv[4];
            float s = 0.f;
            #pragma unroll
            for (int nt = 0; nt < 4; ++nt) {
                rv[nt] = acc2[nt][r] + hb[(size_t)(r0 + r) * D + nt * 16 + c0];
                s += rv[nt];
            }
            s = gsum16(s);
            float mu = s * (1.f / 64.f);
            float q = 0.f;
            #pragma unroll
            for (int nt = 0; nt < 4; ++nt) { float d = rv[nt] - mu; q += d * d; }
            q = gsum16(q);
            float inv = rsqrtf(q * (1.f / 64.f) + EPS);
            #pragma unroll
            for (int nt = 0; nt < 4; ++nt)
                h2b[(size_t)(r0 + r) * D + nt * 16 + c0] = f2bu((rv[nt] - mu) * inv * g2v[nt] + bev[nt]);
        }
    }
}

// ---------------- GNN linear (MFMA, bf16 inputs) + relu + residual + LN -> fp32 out ----------------
__global__ __launch_bounds__(256) void k_gnn_mfma(
    const unsigned short* __restrict__ h2b, const unsigned short* __restrict__ hnb,
    const short* __restrict__ S,
    const float* __restrict__ bg, const float* __restrict__ gg,
    const float* __restrict__ bgn,
    float* __restrict__ out)
{
    const int lane = threadIdx.x & 63;
    const int c0 = lane & 15;
    const int g  = lane >> 4;
    const bf16x8* wp = (const bf16x8*)(S + OFF_WG);

    float bgv[4], ggv[4], bnv[4];
    #pragma unroll
    for (int nt = 0; nt < 4; ++nt) {
        bgv[nt] = bg[nt * 16 + c0];
        ggv[nt] = gg[nt * 16 + c0];
        bnv[nt] = bgn[nt * 16 + c0];
    }

    int wid = (blockIdx.x * 256 + threadIdx.x) >> 6;
    const int nwaves = (gridDim.x * 256) >> 6;
    for (int tile = wid; tile < NN / 16; tile += nwaves) {
        const int row0 = tile * 16;
        bf16x8 a[4];
        #pragma unroll
        for (int kt = 0; kt < 2; ++kt) {
            a[kt]     = *(const bf16x8*)&h2b[(size_t)(row0 + c0) * 64 + kt * 32 + g * 8];
            a[2 + kt] = *(const bf16x8*)&hnb[(size_t)(row0 + c0) * 64 + kt * 32 + g * 8];
        }
        f32x4 acc[4];
        #pragma unroll
        for (int nt = 0; nt < 4; ++nt) {
            float b = bgv[nt];
            f32x4 c = {b, b, b, b};
            #pragma unroll
            for (int kt = 0; kt < 4; ++kt)
                c = __builtin_amdgcn_mfma_f32_16x16x32_bf16(a[kt], wp[(nt * 4 + kt) * 64 + lane], c, 0, 0, 0);
            acc[nt] = c;
        }
        const int r0 = row0 + g * 4;
        #pragma unroll
        for (int r = 0; r < 4; ++r) {
            float rv[4];
            float s = 0.f;
            #pragma unroll
            for (int nt = 0; nt < 4; ++nt) {
                float hn = fmaxf(acc[nt][r], 0.f);
                rv[nt] = hn + b2f(h2b[(size_t)(r0 + r) * 64 + nt * 16 + c0]);
                s += rv[nt];
            }
            s = gsum16(s);
            float mu = s * (1.f / 64.f);
            float q = 0.f;
            #pragma unroll
            for (int nt = 0; nt < 4; ++nt) { float d = rv[nt] - mu; q += d * d; }
            q = gsum16(q);
            float inv = rsqrtf(q * (1.f / 64.f) + EPS);
            #pragma unroll
            for (int nt = 0; nt < 4; ++nt)
                out[(size_t)(r0 + r) * D + nt * 16 + c0] = (rv[nt] - mu) * inv * ggv[nt] + bnv[nt];
        }
    }
}

// ---------------- attention_samples passthrough (as fp32) ----------------
__global__ __launch_bounds__(256) void k_samples(
    const int* __restrict__ samp, float* __restrict__ out, int n)
{
    int i = blockIdx.x * blockDim.x + threadIdx.x;
    const int stride = gridDim.x * blockDim.x;
    for (; i < n; i += stride) out[i] = (float)samp[i];
}

extern "C" void kernel_launch(void* const* d_in, const int* in_sizes, int n_in,
                              void* d_out, int out_size, void* d_ws, size_t ws_size,
                              hipStream_t stream)
{
    const float* x   = (const float*)d_in[0];
    const int*   rows = (const int*)d_in[1];
    const int*   cols = (const int*)d_in[2];
    const float* ev  = (const float*)d_in[3];
    const int*   samp = (const int*)d_in[4];
    const float* Wq  = (const float*)d_in[5];
    const float* bq  = (const float*)d_in[6];
    const float* Wk  = (const float*)d_in[7];
    const float* bk  = (const float*)d_in[8];
    const float* Wv  = (const float*)d_in[9];
    const float* bv  = (const float*)d_in[10];
    const float* Wo  = (const float*)d_in[11];
    const float* bo  = (const float*)d_in[12];
    const float* g1  = (const float*)d_in[13];
    const float* be1 = (const float*)d_in[14];
    const float* g2  = (const float*)d_in[15];
    const float* be2 = (const float*)d_in[16];
    const float* W1  = (const float*)d_in[17];
    const float* bf1 = (const float*)d_in[18];
    const float* W2  = (const float*)d_in[19];
    const float* bf2 = (const float*)d_in[20];
    const float* Wg  = (const float*)d_in[21];
    const float* bg  = (const float*)d_in[22];
    const float* gg  = (const float*)d_in[23];
    const float* bgn = (const float*)d_in[24];
    const int E = in_sizes[1];

    // ws layout: 3 buffers of NN*D floats (76.8 MB)
    float* buf0 = (float*)d_ws;                   // [Kp_b | Vp_b] bf16 -> payload (int2[E])
    float* buf1 = buf0 + (size_t)NN * D;          // [Qp_b -> hnb_b | ob -> h2b] bf16
    float* buf2 = buf1 + (size_t)NN * D;          // hb fp32
    unsigned short* Kp_b = (unsigned short*)buf0;
    unsigned short* Vp_b = Kp_b + (size_t)NN * D;
    int2* payload = (int2*)buf0;                       // overwrites Kp/Vp after attn
    unsigned short* Qp_b  = (unsigned short*)buf1;     // dead after attn -> hnb slot
    unsigned short* hnb_b = (unsigned short*)buf1;
    unsigned short* ob    = (unsigned short*)(buf1 + (size_t)NN * D / 2); // dead after attno -> h2b slot
    unsigned short* h2b   = ob;
    float* hb = buf2;

    float* out = (float*)d_out;
    // scratch in samples region of d_out (rewritten by k_samples each call)
    short* S     = (short*)(out + (size_t)NN * D);   // S_TOTAL shorts
    int* counts  = (int*)(S + S_TOTAL);              // NN
    int* offsets = counts + NN;                      // NN+1
    int* cursor  = offsets + NN + 1;                 // NN

    k_prep<<<56, 256, 0, stream>>>(W1, W2, Wg, Wq, Wk, Wv, Wo, S);
    hipMemsetAsync(counts, 0, (size_t)NN * sizeof(int), stream);
    k_hist<<<4096, 256, 0, stream>>>(rows, counts, E);
    k_scan<<<1, 1024, 0, stream>>>(counts, offsets, cursor);
    k_projqkv_mfma<<<1563, 256, 0, stream>>>(x, S, bq, bk, bv, Qp_b, Kp_b, Vp_b);
    k_attn_lite<<<4096, 256, 0, stream>>>(Qp_b, Kp_b, Vp_b, samp, ob);
    k_attno_mfma<<<1563, 256, 0, stream>>>(ob, x, S, bo, g1, be1, hb);
    k_ffn_mfma<<<1563, 256, 0, stream>>>(hb, S, bf1, bf2, g2, be2, h2b);
    k_fill<<<NPASS * NCHUNK, 256, 0, stream>>>(rows, cols, ev, cursor, payload, E);
    k_gather<<<4096, 256, 0, stream>>>(offsets, payload, h2b, hnb_b);
    k_gnn_mfma<<<1563, 256, 0, stream>>>(h2b, hnb_b, S, bg, gg, bgn, out);
    k_samples<<<2048, 256, 0, stream>>>(samp, out + (size_t)NN * D, NN * KS);
}

// Round 9
// 485.185 us; speedup vs baseline: 5.6458x; 1.1282x over previous
//
#include <hip/hip_runtime.h>
#include <hip/hip_bf16.h>

#define NN  100000
#define D   64
#define KS  20
#define DFF 256
#define EPS 1e-5f

// radix-partition params
#define BROWS  512
#define NB     ((NN + BROWS - 1) / BROWS)   // 196 buckets
#define PCHUNK 8192                          // edges per k_part block

// frag-buffer offsets (shorts)
#define OFF_W1 0
#define OFF_W2 16384
#define OFF_WG 32768
#define OFF_WQ 40960
#define OFF_WK 45056
#define OFF_WV 49152
#define OFF_WO 53248
#define S_TOTAL 57344

typedef __attribute__((ext_vector_type(8))) short bf16x8;
typedef __attribute__((ext_vector_type(4))) float f32x4;

__device__ __forceinline__ short f2b(float f) {
    return __builtin_bit_cast(short, __float2bfloat16(f));
}
__device__ __forceinline__ unsigned short f2bu(float f) {
    return __builtin_bit_cast(unsigned short, __float2bfloat16(f));
}
__device__ __forceinline__ float b2f(unsigned short u) {
    return __builtin_bit_cast(float, ((unsigned)u) << 16);
}
__device__ __forceinline__ float gsum16(float v) {
    v += __shfl_xor(v, 1, 64);
    v += __shfl_xor(v, 2, 64);
    v += __shfl_xor(v, 4, 64);
    v += __shfl_xor(v, 8, 64);
    return v;
}

// ---------------- weight fragment prep (bf16, B-operand layout) ----------------
// B-frag: lane l, elem i -> B[k][n], n = nt*16 + (l&15), k = kt*32 + (l>>4)*8 + i
__global__ __launch_bounds__(256) void k_prep(
    const float* __restrict__ W1, const float* __restrict__ W2,
    const float* __restrict__ Wg,
    const float* __restrict__ Wq, const float* __restrict__ Wk,
    const float* __restrict__ Wv, const float* __restrict__ Wo,
    short* __restrict__ S)
{
    int idx = blockIdx.x * 256 + threadIdx.x;
    for (; idx < S_TOTAL; idx += gridDim.x * 256) {
        float v;
        if (idx < OFF_W2) {                 // W1 [64 x 256]
            int f = idx >> 9, rem = idx & 511;
            int l = rem >> 3, i = rem & 7;
            int nt = f >> 1, kt = f & 1;
            v = W1[(kt * 32 + (l >> 4) * 8 + i) * DFF + nt * 16 + (l & 15)];
        } else if (idx < OFF_WG) {          // W2 [256 x 64]
            int j = idx - OFF_W2;
            int f = j >> 9, rem = j & 511;
            int l = rem >> 3, i = rem & 7;
            int nt = f >> 3, kt = f & 7;
            v = W2[(kt * 32 + (l >> 4) * 8 + i) * D + nt * 16 + (l & 15)];
        } else if (idx < OFF_WQ) {          // Wg [128 x 64]
            int j = idx - OFF_WG;
            int f = j >> 9, rem = j & 511;
            int l = rem >> 3, i = rem & 7;
            int nt = f >> 2, kt = f & 3;
            v = Wg[(kt * 32 + (l >> 4) * 8 + i) * D + nt * 16 + (l & 15)];
        } else {                            // Wq/Wk/Wv/Wo [64 x 64]
            int j = idx - OFF_WQ;
            const float* W = (j < 4096) ? Wq : (j < 8192) ? Wk : (j < 12288) ? Wv : Wo;
            j &= 4095;
            int f = j >> 9, rem = j & 511;
            int l = rem >> 3, i = rem & 7;
            int nt = f >> 1, kt = f & 1;
            v = W[(kt * 32 + (l >> 4) * 8 + i) * D + nt * 16 + (l & 15)];
        }
        S[idx] = f2b(v);
    }
}

// ---------------- CSR build: histogram ----------------
__global__ __launch_bounds__(256) void k_hist(
    const int* __restrict__ rows, int* __restrict__ counts, int E)
{
    int i = blockIdx.x * 256 + threadIdx.x;
    for (; i < E; i += gridDim.x * 256) atomicAdd(&counts[rows[i]], 1);
}

// ---------------- CSR build: single-block exclusive scan ----------------
__global__ __launch_bounds__(1024) void k_scan(
    const int* __restrict__ counts, int* __restrict__ offsets)
{
    __shared__ int wsum[16];
    __shared__ int woff[16];
    __shared__ int s_carry, s_total;
    const int tid = threadIdx.x;
    const int lane = tid & 63;
    const int wv = tid >> 6;
    if (tid == 0) s_carry = 0;
    __syncthreads();
    for (int base = 0; base < NN; base += 4096) {
        int i0 = base + tid * 4;
        int c0 = (i0 + 0 < NN) ? counts[i0 + 0] : 0;
        int c1 = (i0 + 1 < NN) ? counts[i0 + 1] : 0;
        int c2 = (i0 + 2 < NN) ? counts[i0 + 2] : 0;
        int c3 = (i0 + 3 < NN) ? counts[i0 + 3] : 0;
        int s = c0 + c1 + c2 + c3;
        int v = s;
        #pragma unroll
        for (int off = 1; off < 64; off <<= 1) {
            int t = __shfl_up(v, off, 64);
            if (lane >= off) v += t;
        }
        if (lane == 63) wsum[wv] = v;
        int texcl = v - s;
        __syncthreads();
        if (wv == 0) {
            int wval = (lane < 16) ? wsum[lane] : 0;
            #pragma unroll
            for (int off = 1; off < 16; off <<= 1) {
                int t = __shfl_up(wval, off, 64);
                if (lane >= off) wval += t;
            }
            if (lane < 16) woff[lane] = wval - wsum[lane];
            if (lane == 15) s_total = wval;
        }
        __syncthreads();
        int basev = s_carry + woff[wv] + texcl;
        if (i0 + 0 < NN) offsets[i0 + 0] = basev;
        if (i0 + 1 < NN) offsets[i0 + 1] = basev + c0;
        if (i0 + 2 < NN) offsets[i0 + 2] = basev + c0 + c1;
        if (i0 + 3 < NN) offsets[i0 + 3] = basev + c0 + c1 + c2;
        __syncthreads();
        if (tid == 0) s_carry += s_total;
        __syncthreads();
    }
    if (threadIdx.x == 0) offsets[NN] = s_carry;
}

// ---------------- bucket cursor init: bcur[b] = offsets[b*BROWS] ----------------
__global__ __launch_bounds__(256) void k_binit(
    const int* __restrict__ offsets, int* __restrict__ bcur)
{
    int t = threadIdx.x;
    if (t < NB) bcur[t] = offsets[min(t * BROWS, NN)];
}

// ---------------- phase 1: radix-partition edges by bucket (row>>9) ----------------
// Per-block LDS histogram -> one global reservation per (block,bucket) ->
// records written in runs of ~chunk/NB consecutive slots = full 64B lines.
__global__ __launch_bounds__(256) void k_part(
    const int* __restrict__ rows, const int* __restrict__ cols,
    const float* __restrict__ ev, int* __restrict__ bcur,
    int2* __restrict__ part, int E)
{
    __shared__ int srow[PCHUNK];    // 32 KB
    __shared__ int hist[NB];
    __shared__ int base[NB];
    __shared__ int lcnt[NB];
    const int tid = threadIdx.x;
    const int i0 = blockIdx.x * PCHUNK;
    const int n = min(PCHUNK, E - i0);
    for (int t = tid; t < NB; t += 256) { hist[t] = 0; lcnt[t] = 0; }
    __syncthreads();
    for (int t = tid; t < n; t += 256) {
        int r = __builtin_nontemporal_load(rows + i0 + t);
        srow[t] = r;
        atomicAdd(&hist[r >> 9], 1);
    }
    __syncthreads();
    for (int t = tid; t < NB; t += 256)
        base[t] = (hist[t] > 0) ? atomicAdd(&bcur[t], hist[t]) : 0;
    __syncthreads();
    for (int t = tid; t < n; t += 256) {
        int r = srow[t];
        int b = r >> 9;
        int c = __builtin_nontemporal_load(cols + i0 + t);
        float w = __builtin_nontemporal_load(ev + i0 + t);
        int lpos = atomicAdd(&lcnt[b], 1);
        part[base[b] + lpos] = make_int2(((r & (BROWS - 1)) << 17) | c, __float_as_int(w));
    }
}

// ---------------- phase 2: within-bucket final CSR placement (L2-resident) ----------------
// One block per bucket: 512 row cursors live in LDS; the write region
// (~130KB) is touched by this block only -> lines fill before eviction.
__global__ __launch_bounds__(256) void k_fill2(
    const int* __restrict__ offsets, const int2* __restrict__ part,
    int2* __restrict__ payload)
{
    __shared__ int lcur[BROWS];
    const int b = blockIdx.x;
    const int row0 = b * BROWS;
    const int rend = min(row0 + BROWS, NN);
    const int tid = threadIdx.x;
    for (int t = tid; t < rend - row0; t += 256) lcur[t] = offsets[row0 + t];
    __syncthreads();
    const int e0 = offsets[row0], e1 = offsets[rend];
    for (int i = e0 + tid; i < e1; i += 256) {
        int2 rec = part[i];
        int rowoff = (unsigned)rec.x >> 17;
        int col = rec.x & 0x1FFFF;
        int pos = atomicAdd(&lcur[rowoff], 1);
        payload[pos] = make_int2(col, rec.y);
    }
}

// ---------------- segment gather-reduce (2-deep pipelined) ----------------
__global__ __launch_bounds__(256) void k_gather(
    const int* __restrict__ offsets, const int2* __restrict__ payload,
    const unsigned short* __restrict__ h2b, unsigned short* __restrict__ hnb)
{
    const int lane = threadIdx.x & 63;
    const int g = lane >> 4, c0 = lane & 15;
    int w = (blockIdx.x * 256 + threadIdx.x) >> 6;
    const int nw = (gridDim.x * 256) >> 6;
    for (int row = w; row < NN; row += nw) {
        const int b = offsets[row], e = offsets[row + 1];
        float ax = 0.f, ay = 0.f, az = 0.f, aw = 0.f;
        int i = b + g;
        for (; i + 4 < e; i += 8) {
            int2 p0 = payload[i];
            int2 p1 = payload[i + 4];
            float w0 = __int_as_float(p0.y);
            float w1 = __int_as_float(p1.y);
            const ushort4 u0 = *(const ushort4*)(h2b + (size_t)p0.x * 64 + c0 * 4);
            const ushort4 u1 = *(const ushort4*)(h2b + (size_t)p1.x * 64 + c0 * 4);
            ax = fmaf(b2f(u0.x), w0, ax); ay = fmaf(b2f(u0.y), w0, ay);
            az = fmaf(b2f(u0.z), w0, az); aw = fmaf(b2f(u0.w), w0, aw);
            ax = fmaf(b2f(u1.x), w1, ax); ay = fmaf(b2f(u1.y), w1, ay);
            az = fmaf(b2f(u1.z), w1, az); aw = fmaf(b2f(u1.w), w1, aw);
        }
        if (i < e) {
            int2 p = payload[i];
            float wt = __int_as_float(p.y);
            const ushort4 u = *(const ushort4*)(h2b + (size_t)p.x * 64 + c0 * 4);
            ax = fmaf(b2f(u.x), wt, ax); ay = fmaf(b2f(u.y), wt, ay);
            az = fmaf(b2f(u.z), wt, az); aw = fmaf(b2f(u.w), wt, aw);
        }
        ax += __shfl_xor(ax, 16, 64); ax += __shfl_xor(ax, 32, 64);
        ay += __shfl_xor(ay, 16, 64); ay += __shfl_xor(ay, 32, 64);
        az += __shfl_xor(az, 16, 64); az += __shfl_xor(az, 32, 64);
        aw += __shfl_xor(aw, 16, 64); aw += __shfl_xor(aw, 32, 64);
        if (g == 0) {
            ushort4 o;
            o.x = f2bu(ax); o.y = f2bu(ay); o.z = f2bu(az); o.w = f2bu(aw);
            *(ushort4*)(hnb + (size_t)row * 64 + c0 * 4) = o;
        }
    }
}

// ---------------- Q/K/V projection via MFMA -> bf16 ----------------
__global__ __launch_bounds__(256) void k_projqkv_mfma(
    const float* __restrict__ x, const short* __restrict__ S,
    const float* __restrict__ bq, const float* __restrict__ bk,
    const float* __restrict__ bv,
    unsigned short* __restrict__ Qp, unsigned short* __restrict__ Kp,
    unsigned short* __restrict__ Vp)
{
    const int lane = threadIdx.x & 63;
    const int c0 = lane & 15;
    const int g  = lane >> 4;
    const bf16x8* wq = (const bf16x8*)(S + OFF_WQ);
    const bf16x8* wk = (const bf16x8*)(S + OFF_WK);
    const bf16x8* wv = (const bf16x8*)(S + OFF_WV);

    float bqv[4], bkv[4], bvv[4];
    #pragma unroll
    for (int nt = 0; nt < 4; ++nt) {
        bqv[nt] = bq[nt * 16 + c0];
        bkv[nt] = bk[nt * 16 + c0];
        bvv[nt] = bv[nt * 16 + c0];
    }

    int wid = (blockIdx.x * 256 + threadIdx.x) >> 6;
    const int nwaves = (gridDim.x * 256) >> 6;
    for (int tile = wid; tile < NN / 16; tile += nwaves) {
        const int row0 = tile * 16;
        const float* ar = x + (size_t)(row0 + c0) * D + g * 8;
        bf16x8 a0, a1;
        {
            float4 f0 = *(const float4*)(ar);
            float4 f1 = *(const float4*)(ar + 4);
            float4 f2 = *(const float4*)(ar + 32);
            float4 f3 = *(const float4*)(ar + 36);
            a0[0] = f2b(f0.x); a0[1] = f2b(f0.y); a0[2] = f2b(f0.z); a0[3] = f2b(f0.w);
            a0[4] = f2b(f1.x); a0[5] = f2b(f1.y); a0[6] = f2b(f1.z); a0[7] = f2b(f1.w);
            a1[0] = f2b(f2.x); a1[1] = f2b(f2.y); a1[2] = f2b(f2.z); a1[3] = f2b(f2.w);
            a1[4] = f2b(f3.x); a1[5] = f2b(f3.y); a1[6] = f2b(f3.z); a1[7] = f2b(f3.w);
        }
        f32x4 aq[4], ak[4], av[4];
        #pragma unroll
        for (int nt = 0; nt < 4; ++nt) {
            f32x4 cq = {bqv[nt], bqv[nt], bqv[nt], bqv[nt]};
            cq = __builtin_amdgcn_mfma_f32_16x16x32_bf16(a0, wq[(nt * 2 + 0) * 64 + lane], cq, 0, 0, 0);
            cq = __builtin_amdgcn_mfma_f32_16x16x32_bf16(a1, wq[(nt * 2 + 1) * 64 + lane], cq, 0, 0, 0);
            aq[nt] = cq;
            f32x4 ck = {bkv[nt], bkv[nt], bkv[nt], bkv[nt]};
            ck = __builtin_amdgcn_mfma_f32_16x16x32_bf16(a0, wk[(nt * 2 + 0) * 64 + lane], ck, 0, 0, 0);
            ck = __builtin_amdgcn_mfma_f32_16x16x32_bf16(a1, wk[(nt * 2 + 1) * 64 + lane], ck, 0, 0, 0);
            ak[nt] = ck;
            f32x4 cv = {bvv[nt], bvv[nt], bvv[nt], bvv[nt]};
            cv = __builtin_amdgcn_mfma_f32_16x16x32_bf16(a0, wv[(nt * 2 + 0) * 64 + lane], cv, 0, 0, 0);
            cv = __builtin_amdgcn_mfma_f32_16x16x32_bf16(a1, wv[(nt * 2 + 1) * 64 + lane], cv, 0, 0, 0);
            av[nt] = cv;
        }
        const int r0 = row0 + g * 4;
        #pragma unroll
        for (int r = 0; r < 4; ++r) {
            #pragma unroll
            for (int nt = 0; nt < 4; ++nt) {
                Qp[(size_t)(r0 + r) * D + nt * 16 + c0] = f2bu(aq[nt][r]);
                Kp[(size_t)(r0 + r) * D + nt * 16 + c0] = f2bu(ak[nt][r]);
                Vp[(size_t)(r0 + r) * D + nt * 16 + c0] = f2bu(av[nt][r]);
            }
        }
    }
}

// ---------------- attention core: gathers + per-head softmax + PV -> ob (bf16) ----------------
__global__ __launch_bounds__(256) void k_attn_lite(
    const unsigned short* __restrict__ Qp,
    const unsigned short* __restrict__ Kp, const unsigned short* __restrict__ Vp,
    const int* __restrict__ samp, unsigned short* __restrict__ ob)
{
    const int lane = threadIdx.x & 63;
    const int g = lane >> 4, c0 = lane & 15;
    int w = (blockIdx.x * 256 + threadIdx.x) >> 6;
    const int nw = (gridDim.x * 256) >> 6;
    for (int row = w; row < NN; row += nw) {
        int idx_reg = (lane < KS) ? samp[row * KS + lane] : 0;
        const ushort4 qv = *(const ushort4*)(Qp + (size_t)row * D + c0 * 4);
        float q0 = b2f(qv.x), q1 = b2f(qv.y), q2 = b2f(qv.z), q3 = b2f(qv.w);

        // group g handles samples g*5 .. g*5+4
        float s[5];
        ushort4 v4[5];
        #pragma unroll
        for (int t = 0; t < 5; ++t) {
            int idx = __shfl(idx_reg, g * 5 + t, 64);
            const ushort4 kk = *(const ushort4*)(Kp + (size_t)idx * D + c0 * 4);
            v4[t] = *(const ushort4*)(Vp + (size_t)idx * D + c0 * 4);
            float sc = q0 * b2f(kk.x);
            sc = fmaf(q1, b2f(kk.y), sc);
            sc = fmaf(q2, b2f(kk.z), sc);
            sc = fmaf(q3, b2f(kk.w), sc);
            // per-head dot: head = c0>>2 spans lanes (c0&~3)..(c0|3)
            sc += __shfl_xor(sc, 1, 64);
            sc += __shfl_xor(sc, 2, 64);
            s[t] = sc * 0.25f;   // 1/sqrt(DH=16)
        }
        // per-head softmax over 20 samples (5 local x 4 groups; xor16/32 keep c0 => within-head)
        float m = fmaxf(fmaxf(fmaxf(s[0], s[1]), fmaxf(s[2], s[3])), s[4]);
        m = fmaxf(m, __shfl_xor(m, 16, 64));
        m = fmaxf(m, __shfl_xor(m, 32, 64));
        float o0 = 0.f, o1 = 0.f, o2 = 0.f, o3 = 0.f, ssum = 0.f;
        #pragma unroll
        for (int t = 0; t < 5; ++t) {
            float p = __expf(s[t] - m);
            ssum += p;
            o0 = fmaf(p, b2f(v4[t].x), o0);
            o1 = fmaf(p, b2f(v4[t].y), o1);
            o2 = fmaf(p, b2f(v4[t].z), o2);
            o3 = fmaf(p, b2f(v4[t].w), o3);
        }
        ssum += __shfl_xor(ssum, 16, 64);
        ssum += __shfl_xor(ssum, 32, 64);
        float inv = 1.0f / ssum;
        o0 += __shfl_xor(o0, 16, 64); o0 += __shfl_xor(o0, 32, 64);
        o1 += __shfl_xor(o1, 16, 64); o1 += __shfl_xor(o1, 32, 64);
        o2 += __shfl_xor(o2, 16, 64); o2 += __shfl_xor(o2, 32, 64);
        o3 += __shfl_xor(o3, 16, 64); o3 += __shfl_xor(o3, 32, 64);
        if (g == 0) {
            ushort4 o;
            o.x = f2bu(o0 * inv); o.y = f2bu(o1 * inv);
            o.z = f2bu(o2 * inv); o.w = f2bu(o3 * inv);
            *(ushort4*)(ob + (size_t)row * D + c0 * 4) = o;
        }
    }
}

// ---------------- Wo projection + residual + LN1 via MFMA -> hb fp32 ----------------
__global__ __launch_bounds__(256) void k_attno_mfma(
    const unsigned short* __restrict__ ob, const float* __restrict__ x,
    const short* __restrict__ S,
    const float* __restrict__ bo, const float* __restrict__ g1,
    const float* __restrict__ be1,
    float* __restrict__ hb)
{
    const int lane = threadIdx.x & 63;
    const int c0 = lane & 15;
    const int g  = lane >> 4;
    const bf16x8* wp = (const bf16x8*)(S + OFF_WO);

    float bov[4], g1v[4], b1v[4];
    #pragma unroll
    for (int nt = 0; nt < 4; ++nt) {
        bov[nt] = bo[nt * 16 + c0];
        g1v[nt] = g1[nt * 16 + c0];
        b1v[nt] = be1[nt * 16 + c0];
    }

    int wid = (blockIdx.x * 256 + threadIdx.x) >> 6;
    const int nwaves = (gridDim.x * 256) >> 6;
    for (int tile = wid; tile < NN / 16; tile += nwaves) {
        const int row0 = tile * 16;
        bf16x8 a[2];
        #pragma unroll
        for (int kt = 0; kt < 2; ++kt)
            a[kt] = *(const bf16x8*)&ob[(size_t)(row0 + c0) * D + kt * 32 + g * 8];
        f32x4 acc[4];
        #pragma unroll
        for (int nt = 0; nt < 4; ++nt) {
            f32x4 c = {bov[nt], bov[nt], bov[nt], bov[nt]};
            #pragma unroll
            for (int kt = 0; kt < 2; ++kt)
                c = __builtin_amdgcn_mfma_f32_16x16x32_bf16(a[kt], wp[(nt * 2 + kt) * 64 + lane], c, 0, 0, 0);
            acc[nt] = c;
        }
        const int r0 = row0 + g * 4;
        #pragma unroll
        for (int r = 0; r < 4; ++r) {
            float rv[4];
            float s = 0.f;
            #pragma unroll
            for (int nt = 0; nt < 4; ++nt) {
                rv[nt] = acc[nt][r] + x[(size_t)(r0 + r) * D + nt * 16 + c0];
                s += rv[nt];
            }
            s = gsum16(s);
            float mu = s * (1.f / 64.f);
            float q = 0.f;
            #pragma unroll
            for (int nt = 0; nt < 4; ++nt) { float d = rv[nt] - mu; q += d * d; }
            q = gsum16(q);
            float inv = rsqrtf(q * (1.f / 64.f) + EPS);
            #pragma unroll
            for (int nt = 0; nt < 4; ++nt)
                hb[(size_t)(r0 + r) * D + nt * 16 + c0] = (rv[nt] - mu) * inv * g1v[nt] + b1v[nt];
        }
    }
}

// ---------------- FFN via MFMA -> bf16 h2 ----------------
__global__ __launch_bounds__(256) void k_ffn_mfma(
    const float* __restrict__ hb,
    const short* __restrict__ wf,
    const float* __restrict__ bf1, const float* __restrict__ bf2,
    const float* __restrict__ g2, const float* __restrict__ be2,
    unsigned short* __restrict__ h2b)
{
    __shared__ __align__(16) short Tl[4][16][264];
    const int lane = threadIdx.x & 63;
    const int wv   = threadIdx.x >> 6;
    const int c0   = lane & 15;
    const int g    = lane >> 4;
    const bf16x8* w1p = (const bf16x8*)(wf + OFF_W1);
    const bf16x8* w2p = (const bf16x8*)(wf + OFF_W2);

    float b1v[16];
    #pragma unroll
    for (int nt = 0; nt < 16; ++nt) b1v[nt] = bf1[nt * 16 + c0];
    float b2v[4], g2v[4], bev[4];
    #pragma unroll
    for (int nt = 0; nt < 4; ++nt) {
        b2v[nt] = bf2[nt * 16 + c0];
        g2v[nt] = g2[nt * 16 + c0];
        bev[nt] = be2[nt * 16 + c0];
    }

    int wid = (blockIdx.x * 256 + threadIdx.x) >> 6;
    const int nwaves = (gridDim.x * 256) >> 6;
    for (int tile = wid; tile < NN / 16; tile += nwaves) {
        const int row0 = tile * 16;
        const float* ar = hb + (size_t)(row0 + c0) * D + g * 8;
        bf16x8 a0, a1;
        {
            float4 f0 = *(const float4*)(ar);
            float4 f1 = *(const float4*)(ar + 4);
            float4 f2 = *(const float4*)(ar + 32);
            float4 f3 = *(const float4*)(ar + 36);
            a0[0] = f2b(f0.x); a0[1] = f2b(f0.y); a0[2] = f2b(f0.z); a0[3] = f2b(f0.w);
            a0[4] = f2b(f1.x); a0[5] = f2b(f1.y); a0[6] = f2b(f1.z); a0[7] = f2b(f1.w);
            a1[0] = f2b(f2.x); a1[1] = f2b(f2.y); a1[2] = f2b(f2.z); a1[3] = f2b(f2.w);
            a1[4] = f2b(f3.x); a1[5] = f2b(f3.y); a1[6] = f2b(f3.z); a1[7] = f2b(f3.w);
        }
        f32x4 acc1[16];
        #pragma unroll
        for (int nt = 0; nt < 16; ++nt) {
            float b = b1v[nt];
            f32x4 c = {b, b, b, b};
            c = __builtin_amdgcn_mfma_f32_16x16x32_bf16(a0, w1p[(nt * 2 + 0) * 64 + lane], c, 0, 0, 0);
            c = __builtin_amdgcn_mfma_f32_16x16x32_bf16(a1, w1p[(nt * 2 + 1) * 64 + lane], c, 0, 0, 0);
            acc1[nt] = c;
        }
        #pragma unroll
        for (int nt = 0; nt < 16; ++nt) {
            #pragma unroll
            for (int r = 0; r < 4; ++r)
                Tl[wv][g * 4 + r][nt * 16 + c0] = f2b(fmaxf(acc1[nt][r], 0.f));
        }
        bf16x8 a2[8];
        #pragma unroll
        for (int kt = 0; kt < 8; ++kt)
            a2[kt] = *(const bf16x8*)&Tl[wv][c0][kt * 32 + g * 8];
        f32x4 acc2[4];
        #pragma unroll
        for (int nt = 0; nt < 4; ++nt) {
            float b = b2v[nt];
            f32x4 c = {b, b, b, b};
            #pragma unroll
            for (int kt = 0; kt < 8; ++kt)
                c = __builtin_amdgcn_mfma_f32_16x16x32_bf16(a2[kt], w2p[(nt * 8 + kt) * 64 + lane], c, 0, 0, 0);
            acc2[nt] = c;
        }
        const int r0 = row0 + g * 4;
        #pragma unroll
        for (int r = 0; r < 4; ++r) {
            float rv[4];
            float s = 0.f;
            #pragma unroll
            for (int nt = 0; nt < 4; ++nt) {
                rv[nt] = acc2[nt][r] + hb[(size_t)(r0 + r) * D + nt * 16 + c0];
                s += rv[nt];
            }
            s = gsum16(s);
            float mu = s * (1.f / 64.f);
            float q = 0.f;
            #pragma unroll
            for (int nt = 0; nt < 4; ++nt) { float d = rv[nt] - mu; q += d * d; }
            q = gsum16(q);
            float inv = rsqrtf(q * (1.f / 64.f) + EPS);
            #pragma unroll
            for (int nt = 0; nt < 4; ++nt)
                h2b[(size_t)(r0 + r) * D + nt * 16 + c0] = f2bu((rv[nt] - mu) * inv * g2v[nt] + bev[nt]);
        }
    }
}

// ---------------- GNN linear (MFMA, bf16 inputs) + relu + residual + LN -> fp32 out ----------------
__global__ __launch_bounds__(256) void k_gnn_mfma(
    const unsigned short* __restrict__ h2b, const unsigned short* __restrict__ hnb,
    const short* __restrict__ S,
    const float* __restrict__ bg, const float* __restrict__ gg,
    const float* __restrict__ bgn,
    float* __restrict__ out)
{
    const int lane = threadIdx.x & 63;
    const int c0 = lane & 15;
    const int g  = lane >> 4;
    const bf16x8* wp = (const bf16x8*)(S + OFF_WG);

    float bgv[4], ggv[4], bnv[4];
    #pragma unroll
    for (int nt = 0; nt < 4; ++nt) {
        bgv[nt] = bg[nt * 16 + c0];
        ggv[nt] = gg[nt * 16 + c0];
        bnv[nt] = bgn[nt * 16 + c0];
    }

    int wid = (blockIdx.x * 256 + threadIdx.x) >> 6;
    const int nwaves = (gridDim.x * 256) >> 6;
    for (int tile = wid; tile < NN / 16; tile += nwaves) {
        const int row0 = tile * 16;
        bf16x8 a[4];
        #pragma unroll
        for (int kt = 0; kt < 2; ++kt) {
            a[kt]     = *(const bf16x8*)&h2b[(size_t)(row0 + c0) * 64 + kt * 32 + g * 8];
            a[2 + kt] = *(const bf16x8*)&hnb[(size_t)(row0 + c0) * 64 + kt * 32 + g * 8];
        }
        f32x4 acc[4];
        #pragma unroll
        for (int nt = 0; nt < 4; ++nt) {
            float b = bgv[nt];
            f32x4 c = {b, b, b, b};
            #pragma unroll
            for (int kt = 0; kt < 4; ++kt)
                c = __builtin_amdgcn_mfma_f32_16x16x32_bf16(a[kt], wp[(nt * 4 + kt) * 64 + lane], c, 0, 0, 0);
            acc[nt] = c;
        }
        const int r0 = row0 + g * 4;
        #pragma unroll
        for (int r = 0; r < 4; ++r) {
            float rv[4];
            float s = 0.f;
            #pragma unroll
            for (int nt = 0; nt < 4; ++nt) {
                float hn = fmaxf(acc[nt][r], 0.f);
                rv[nt] = hn + b2f(h2b[(size_t)(r0 + r) * 64 + nt * 16 + c0]);
                s += rv[nt];
            }
            s = gsum16(s);
            float mu = s * (1.f / 64.f);
            float q = 0.f;
            #pragma unroll
            for (int nt = 0; nt < 4; ++nt) { float d = rv[nt] - mu; q += d * d; }
            q = gsum16(q);
            float inv = rsqrtf(q * (1.f / 64.f) + EPS);
            #pragma unroll
            for (int nt = 0; nt < 4; ++nt)
                out[(size_t)(r0 + r) * D + nt * 16 + c0] = (rv[nt] - mu) * inv * ggv[nt] + bnv[nt];
        }
    }
}

// ---------------- attention_samples passthrough (as fp32) ----------------
__global__ __launch_bounds__(256) void k_samples(
    const int* __restrict__ samp, float* __restrict__ out, int n)
{
    int i = blockIdx.x * blockDim.x + threadIdx.x;
    const int stride = gridDim.x * blockDim.x;
    for (; i < n; i += stride) out[i] = (float)samp[i];
}

extern "C" void kernel_launch(void* const* d_in, const int* in_sizes, int n_in,
                              void* d_out, int out_size, void* d_ws, size_t ws_size,
                              hipStream_t stream)
{
    const float* x   = (const float*)d_in[0];
    const int*   rows = (const int*)d_in[1];
    const int*   cols = (const int*)d_in[2];
    const float* ev  = (const float*)d_in[3];
    const int*   samp = (const int*)d_in[4];
    const float* Wq  = (const float*)d_in[5];
    const float* bq  = (const float*)d_in[6];
    const float* Wk  = (const float*)d_in[7];
    const float* bk  = (const float*)d_in[8];
    const float* Wv  = (const float*)d_in[9];
    const float* bv  = (const float*)d_in[10];
    const float* Wo  = (const float*)d_in[11];
    const float* bo  = (const float*)d_in[12];
    const float* g1  = (const float*)d_in[13];
    const float* be1 = (const float*)d_in[14];
    const float* g2  = (const float*)d_in[15];
    const float* be2 = (const float*)d_in[16];
    const float* W1  = (const float*)d_in[17];
    const float* bf1 = (const float*)d_in[18];
    const float* W2  = (const float*)d_in[19];
    const float* bf2 = (const float*)d_in[20];
    const float* Wg  = (const float*)d_in[21];
    const float* bg  = (const float*)d_in[22];
    const float* gg  = (const float*)d_in[23];
    const float* bgn = (const float*)d_in[24];
    const int E = in_sizes[1];

    // ws layout: 3 buffers of NN*D floats (76.8 MB)
    float* buf0 = (float*)d_ws;                   // [Kp_b | Vp_b] bf16 -> payload (int2[E])
    float* buf1 = buf0 + (size_t)NN * D;          // [Qp_b -> hnb_b | ob -> h2b] bf16
    float* buf2 = buf1 + (size_t)NN * D;          // hb fp32 -> part (int2[E])
    unsigned short* Kp_b = (unsigned short*)buf0;
    unsigned short* Vp_b = Kp_b + (size_t)NN * D;
    int2* payload = (int2*)buf0;                       // overwrites Kp/Vp after attn
    unsigned short* Qp_b  = (unsigned short*)buf1;     // dead after attn -> hnb slot
    unsigned short* hnb_b = (unsigned short*)buf1;
    unsigned short* ob    = (unsigned short*)(buf1 + (size_t)NN * D / 2); // dead after attno -> h2b slot
    unsigned short* h2b   = ob;
    float* hb = buf2;
    int2* part = (int2*)buf2;                          // overwrites hb after ffn

    float* out = (float*)d_out;
    // scratch in samples region of d_out (rewritten by k_samples each call)
    short* S     = (short*)(out + (size_t)NN * D);   // S_TOTAL shorts
    int* counts  = (int*)(S + S_TOTAL);              // NN
    int* offsets = counts + NN;                      // NN+1
    int* bcur    = offsets + NN + 1;                 // NB

    k_prep<<<56, 256, 0, stream>>>(W1, W2, Wg, Wq, Wk, Wv, Wo, S);
    hipMemsetAsync(counts, 0, (size_t)NN * sizeof(int), stream);
    k_hist<<<4096, 256, 0, stream>>>(rows, counts, E);
    k_scan<<<1, 1024, 0, stream>>>(counts, offsets);
    k_binit<<<1, 256, 0, stream>>>(offsets, bcur);
    k_projqkv_mfma<<<1563, 256, 0, stream>>>(x, S, bq, bk, bv, Qp_b, Kp_b, Vp_b);
    k_attn_lite<<<4096, 256, 0, stream>>>(Qp_b, Kp_b, Vp_b, samp, ob);
    k_attno_mfma<<<1563, 256, 0, stream>>>(ob, x, S, bo, g1, be1, hb);
    k_ffn_mfma<<<1563, 256, 0, stream>>>(hb, S, bf1, bf2, g2, be2, h2b);
    k_part<<<(E + PCHUNK - 1) / PCHUNK, 256, 0, stream>>>(rows, cols, ev, bcur, part, E);
    k_fill2<<<NB, 256, 0, stream>>>(offsets, part, payload);
    k_gather<<<4096, 256, 0, stream>>>(offsets, payload, h2b, hnb_b);
    k_gnn_mfma<<<1563, 256, 0, stream>>>(h2b, hnb_b, S, bg, gg, bgn, out);
    k_samples<<<2048, 256, 0, stream>>>(samp, out + (size_t)NN * D, NN * KS);
}

// Round 10
// 447.747 us; speedup vs baseline: 6.1179x; 1.0836x over previous
//
#include <hip/hip_runtime.h>
#include <hip/hip_bf16.h>

#define NN  100000
#define D   64
#define KS  20
#define DFF 256
#define EPS 1e-5f

// radix-partition params
#define BROWS  512
#define NB     ((NN + BROWS - 1) / BROWS)   // 196 buckets
#define PCHUNK 8192                          // edges per k_part block

// frag-buffer offsets (shorts)
#define OFF_W1 0
#define OFF_W2 16384
#define OFF_WG 32768
#define OFF_WQ 40960
#define OFF_WK 45056
#define OFF_WV 49152
#define OFF_WO 53248
#define S_TOTAL 57344

typedef __attribute__((ext_vector_type(8))) short bf16x8;
typedef __attribute__((ext_vector_type(4))) float f32x4;

__device__ __forceinline__ short f2b(float f) {
    return __builtin_bit_cast(short, __float2bfloat16(f));
}
__device__ __forceinline__ unsigned short f2bu(float f) {
    return __builtin_bit_cast(unsigned short, __float2bfloat16(f));
}
__device__ __forceinline__ float b2f(unsigned short u) {
    return __builtin_bit_cast(float, ((unsigned)u) << 16);
}
__device__ __forceinline__ float gsum16(float v) {
    v += __shfl_xor(v, 1, 64);
    v += __shfl_xor(v, 2, 64);
    v += __shfl_xor(v, 4, 64);
    v += __shfl_xor(v, 8, 64);
    return v;
}

// ---------------- weight fragment prep (bf16, B-operand layout) ----------------
// B-frag: lane l, elem i -> B[k][n], n = nt*16 + (l&15), k = kt*32 + (l>>4)*8 + i
__global__ __launch_bounds__(256) void k_prep(
    const float* __restrict__ W1, const float* __restrict__ W2,
    const float* __restrict__ Wg,
    const float* __restrict__ Wq, const float* __restrict__ Wk,
    const float* __restrict__ Wv, const float* __restrict__ Wo,
    short* __restrict__ S)
{
    int idx = blockIdx.x * 256 + threadIdx.x;
    for (; idx < S_TOTAL; idx += gridDim.x * 256) {
        float v;
        if (idx < OFF_W2) {                 // W1 [64 x 256]
            int f = idx >> 9, rem = idx & 511;
            int l = rem >> 3, i = rem & 7;
            int nt = f >> 1, kt = f & 1;
            v = W1[(kt * 32 + (l >> 4) * 8 + i) * DFF + nt * 16 + (l & 15)];
        } else if (idx < OFF_WG) {          // W2 [256 x 64]
            int j = idx - OFF_W2;
            int f = j >> 9, rem = j & 511;
            int l = rem >> 3, i = rem & 7;
            int nt = f >> 3, kt = f & 7;
            v = W2[(kt * 32 + (l >> 4) * 8 + i) * D + nt * 16 + (l & 15)];
        } else if (idx < OFF_WQ) {          // Wg [128 x 64]
            int j = idx - OFF_WG;
            int f = j >> 9, rem = j & 511;
            int l = rem >> 3, i = rem & 7;
            int nt = f >> 2, kt = f & 3;
            v = Wg[(kt * 32 + (l >> 4) * 8 + i) * D + nt * 16 + (l & 15)];
        } else {                            // Wq/Wk/Wv/Wo [64 x 64]
            int j = idx - OFF_WQ;
            const float* W = (j < 4096) ? Wq : (j < 8192) ? Wk : (j < 12288) ? Wv : Wo;
            j &= 4095;
            int f = j >> 9, rem = j & 511;
            int l = rem >> 3, i = rem & 7;
            int nt = f >> 1, kt = f & 1;
            v = W[(kt * 32 + (l >> 4) * 8 + i) * D + nt * 16 + (l & 15)];
        }
        S[idx] = f2b(v);
    }
}

// ---------------- bucket-level histogram (LDS-aggregated) ----------------
__global__ __launch_bounds__(256) void k_bhist(
    const int* __restrict__ rows, int* __restrict__ bcnt, int E)
{
    __shared__ int h[NB];
    for (int t = threadIdx.x; t < NB; t += 256) h[t] = 0;
    __syncthreads();
    int i = blockIdx.x * 256 + threadIdx.x;
    for (; i < E; i += gridDim.x * 256)
        atomicAdd(&h[__builtin_nontemporal_load(rows + i) >> 9], 1);
    __syncthreads();
    for (int t = threadIdx.x; t < NB; t += 256)
        if (h[t]) atomicAdd(&bcnt[t], h[t]);
}

// ---------------- bucket scan: bbase/bcur from bcnt; offsets[NN]=E ----------------
__global__ __launch_bounds__(256) void k_bscan(
    const int* __restrict__ bcnt, int* __restrict__ bbase,
    int* __restrict__ bcur, int* __restrict__ offsets)
{
    __shared__ int wsum[4];
    const int t = threadIdx.x;
    const int lane = t & 63, wv = t >> 6;
    int v = (t < NB) ? bcnt[t] : 0;
    int sv = v;
    #pragma unroll
    for (int off = 1; off < 64; off <<= 1) {
        int u = __shfl_up(sv, off, 64);
        if (lane >= off) sv += u;
    }
    if (lane == 63) wsum[wv] = sv;
    __syncthreads();
    int wofs = 0;
    for (int k = 0; k < wv; ++k) wofs += wsum[k];
    int excl = wofs + sv - v;
    if (t < NB) { bbase[t] = excl; bcur[t] = excl; }
    if (t == 0) {
        int total = wsum[0] + wsum[1] + wsum[2] + wsum[3];
        bbase[NB] = total;
        offsets[NN] = total;
    }
}

// ---------------- phase 1: radix-partition edges by bucket (row>>9) ----------------
__global__ __launch_bounds__(256) void k_part(
    const int* __restrict__ rows, const int* __restrict__ cols,
    const float* __restrict__ ev, int* __restrict__ bcur,
    int2* __restrict__ part, int E)
{
    __shared__ int srow[PCHUNK];    // 32 KB
    __shared__ int hist[NB];
    __shared__ int base[NB];
    __shared__ int lcnt[NB];
    const int tid = threadIdx.x;
    const int i0 = blockIdx.x * PCHUNK;
    const int n = min(PCHUNK, E - i0);
    for (int t = tid; t < NB; t += 256) { hist[t] = 0; lcnt[t] = 0; }
    __syncthreads();
    for (int t = tid; t < n; t += 256) {
        int r = __builtin_nontemporal_load(rows + i0 + t);
        srow[t] = r;
        atomicAdd(&hist[r >> 9], 1);
    }
    __syncthreads();
    for (int t = tid; t < NB; t += 256)
        base[t] = (hist[t] > 0) ? atomicAdd(&bcur[t], hist[t]) : 0;
    __syncthreads();
    for (int t = tid; t < n; t += 256) {
        int r = srow[t];
        int b = r >> 9;
        int c = __builtin_nontemporal_load(cols + i0 + t);
        float w = __builtin_nontemporal_load(ev + i0 + t);
        int lpos = atomicAdd(&lcnt[b], 1);
        part[base[b] + lpos] = make_int2(((r & (BROWS - 1)) << 17) | c, __float_as_int(w));
    }
}

// ---------------- phase 2: in-bucket row offsets (LDS scan) + final placement ----------------
// One block per bucket: count this bucket's 512 rows from its contiguous
// record range (L2-resident), scan in LDS, emit offsets[] for k_gather, place.
__global__ __launch_bounds__(256) void k_fill2(
    const int* __restrict__ bbase, const int2* __restrict__ part,
    int* __restrict__ offsets, int2* __restrict__ payload)
{
    __shared__ int lcnt[BROWS];
    __shared__ int lcur[BROWS];
    __shared__ int wsum[4];
    const int b = blockIdx.x;
    const int row0 = b * BROWS;
    const int nrows = min(BROWS, NN - row0);
    const int tid = threadIdx.x;
    for (int t = tid; t < BROWS; t += 256) lcnt[t] = 0;
    __syncthreads();
    const int e0 = bbase[b], e1 = bbase[b + 1];
    for (int i = e0 + tid; i < e1; i += 256)
        atomicAdd(&lcnt[(unsigned)part[i].x >> 17], 1);
    __syncthreads();
    // exclusive scan of 512 LDS counters: thread t owns pair (2t, 2t+1)
    int c0 = lcnt[2 * tid], c1 = lcnt[2 * tid + 1];
    int s = c0 + c1;
    const int lane = tid & 63, wv = tid >> 6;
    int sv = s;
    #pragma unroll
    for (int off = 1; off < 64; off <<= 1) {
        int u = __shfl_up(sv, off, 64);
        if (lane >= off) sv += u;
    }
    if (lane == 63) wsum[wv] = sv;
    __syncthreads();
    int wofs = 0;
    for (int k = 0; k < wv; ++k) wofs += wsum[k];
    int o0 = e0 + wofs + sv - s;
    int o1 = o0 + c0;
    lcur[2 * tid] = o0;
    lcur[2 * tid + 1] = o1;
    if (2 * tid < nrows)     offsets[row0 + 2 * tid]     = o0;
    if (2 * tid + 1 < nrows) offsets[row0 + 2 * tid + 1] = o1;
    __syncthreads();
    for (int i = e0 + tid; i < e1; i += 256) {
        int2 rec = part[i];
        int rowoff = (unsigned)rec.x >> 17;
        int pos = atomicAdd(&lcur[rowoff], 1);
        payload[pos] = make_int2(rec.x & 0x1FFFF, rec.y);
    }
}

// ---------------- segment gather-reduce (2-deep pipelined) ----------------
__global__ __launch_bounds__(256) void k_gather(
    const int* __restrict__ offsets, const int2* __restrict__ payload,
    const unsigned short* __restrict__ h2b, unsigned short* __restrict__ hnb)
{
    const int lane = threadIdx.x & 63;
    const int g = lane >> 4, c0 = lane & 15;
    int w = (blockIdx.x * 256 + threadIdx.x) >> 6;
    const int nw = (gridDim.x * 256) >> 6;
    for (int row = w; row < NN; row += nw) {
        const int b = offsets[row], e = offsets[row + 1];
        float ax = 0.f, ay = 0.f, az = 0.f, aw = 0.f;
        int i = b + g;
        for (; i + 4 < e; i += 8) {
            int2 p0 = payload[i];
            int2 p1 = payload[i + 4];
            float w0 = __int_as_float(p0.y);
            float w1 = __int_as_float(p1.y);
            const ushort4 u0 = *(const ushort4*)(h2b + (size_t)p0.x * 64 + c0 * 4);
            const ushort4 u1 = *(const ushort4*)(h2b + (size_t)p1.x * 64 + c0 * 4);
            ax = fmaf(b2f(u0.x), w0, ax); ay = fmaf(b2f(u0.y), w0, ay);
            az = fmaf(b2f(u0.z), w0, az); aw = fmaf(b2f(u0.w), w0, aw);
            ax = fmaf(b2f(u1.x), w1, ax); ay = fmaf(b2f(u1.y), w1, ay);
            az = fmaf(b2f(u1.z), w1, az); aw = fmaf(b2f(u1.w), w1, aw);
        }
        if (i < e) {
            int2 p = payload[i];
            float wt = __int_as_float(p.y);
            const ushort4 u = *(const ushort4*)(h2b + (size_t)p.x * 64 + c0 * 4);
            ax = fmaf(b2f(u.x), wt, ax); ay = fmaf(b2f(u.y), wt, ay);
            az = fmaf(b2f(u.z), wt, az); aw = fmaf(b2f(u.w), wt, aw);
        }
        ax += __shfl_xor(ax, 16, 64); ax += __shfl_xor(ax, 32, 64);
        ay += __shfl_xor(ay, 16, 64); ay += __shfl_xor(ay, 32, 64);
        az += __shfl_xor(az, 16, 64); az += __shfl_xor(az, 32, 64);
        aw += __shfl_xor(aw, 16, 64); aw += __shfl_xor(aw, 32, 64);
        if (g == 0) {
            ushort4 o;
            o.x = f2bu(ax); o.y = f2bu(ay); o.z = f2bu(az); o.w = f2bu(aw);
            *(ushort4*)(hnb + (size_t)row * 64 + c0 * 4) = o;
        }
    }
}

// ---------------- Q/K/V projection via MFMA -> bf16 ----------------
__global__ __launch_bounds__(256) void k_projqkv_mfma(
    const float* __restrict__ x, const short* __restrict__ S,
    const float* __restrict__ bq, const float* __restrict__ bk,
    const float* __restrict__ bv,
    unsigned short* __restrict__ Qp, unsigned short* __restrict__ Kp,
    unsigned short* __restrict__ Vp)
{
    const int lane = threadIdx.x & 63;
    const int c0 = lane & 15;
    const int g  = lane >> 4;
    const bf16x8* wq = (const bf16x8*)(S + OFF_WQ);
    const bf16x8* wk = (const bf16x8*)(S + OFF_WK);
    const bf16x8* wv = (const bf16x8*)(S + OFF_WV);

    float bqv[4], bkv[4], bvv[4];
    #pragma unroll
    for (int nt = 0; nt < 4; ++nt) {
        bqv[nt] = bq[nt * 16 + c0];
        bkv[nt] = bk[nt * 16 + c0];
        bvv[nt] = bv[nt * 16 + c0];
    }

    int wid = (blockIdx.x * 256 + threadIdx.x) >> 6;
    const int nwaves = (gridDim.x * 256) >> 6;
    for (int tile = wid; tile < NN / 16; tile += nwaves) {
        const int row0 = tile * 16;
        const float* ar = x + (size_t)(row0 + c0) * D + g * 8;
        bf16x8 a0, a1;
        {
            float4 f0 = *(const float4*)(ar);
            float4 f1 = *(const float4*)(ar + 4);
            float4 f2 = *(const float4*)(ar + 32);
            float4 f3 = *(const float4*)(ar + 36);
            a0[0] = f2b(f0.x); a0[1] = f2b(f0.y); a0[2] = f2b(f0.z); a0[3] = f2b(f0.w);
            a0[4] = f2b(f1.x); a0[5] = f2b(f1.y); a0[6] = f2b(f1.z); a0[7] = f2b(f1.w);
            a1[0] = f2b(f2.x); a1[1] = f2b(f2.y); a1[2] = f2b(f2.z); a1[3] = f2b(f2.w);
            a1[4] = f2b(f3.x); a1[5] = f2b(f3.y); a1[6] = f2b(f3.z); a1[7] = f2b(f3.w);
        }
        f32x4 aq[4], ak[4], av[4];
        #pragma unroll
        for (int nt = 0; nt < 4; ++nt) {
            f32x4 cq = {bqv[nt], bqv[nt], bqv[nt], bqv[nt]};
            cq = __builtin_amdgcn_mfma_f32_16x16x32_bf16(a0, wq[(nt * 2 + 0) * 64 + lane], cq, 0, 0, 0);
            cq = __builtin_amdgcn_mfma_f32_16x16x32_bf16(a1, wq[(nt * 2 + 1) * 64 + lane], cq, 0, 0, 0);
            aq[nt] = cq;
            f32x4 ck = {bkv[nt], bkv[nt], bkv[nt], bkv[nt]};
            ck = __builtin_amdgcn_mfma_f32_16x16x32_bf16(a0, wk[(nt * 2 + 0) * 64 + lane], ck, 0, 0, 0);
            ck = __builtin_amdgcn_mfma_f32_16x16x32_bf16(a1, wk[(nt * 2 + 1) * 64 + lane], ck, 0, 0, 0);
            ak[nt] = ck;
            f32x4 cv = {bvv[nt], bvv[nt], bvv[nt], bvv[nt]};
            cv = __builtin_amdgcn_mfma_f32_16x16x32_bf16(a0, wv[(nt * 2 + 0) * 64 + lane], cv, 0, 0, 0);
            cv = __builtin_amdgcn_mfma_f32_16x16x32_bf16(a1, wv[(nt * 2 + 1) * 64 + lane], cv, 0, 0, 0);
            av[nt] = cv;
        }
        const int r0 = row0 + g * 4;
        #pragma unroll
        for (int r = 0; r < 4; ++r) {
            #pragma unroll
            for (int nt = 0; nt < 4; ++nt) {
                Qp[(size_t)(r0 + r) * D + nt * 16 + c0] = f2bu(aq[nt][r]);
                Kp[(size_t)(r0 + r) * D + nt * 16 + c0] = f2bu(ak[nt][r]);
                Vp[(size_t)(r0 + r) * D + nt * 16 + c0] = f2bu(av[nt][r]);
            }
        }
    }
}

// ---------------- attention core: gathers + per-head softmax + PV -> ob (bf16) ----------------
__global__ __launch_bounds__(256) void k_attn_lite(
    const unsigned short* __restrict__ Qp,
    const unsigned short* __restrict__ Kp, const unsigned short* __restrict__ Vp,
    const int* __restrict__ samp, unsigned short* __restrict__ ob)
{
    const int lane = threadIdx.x & 63;
    const int g = lane >> 4, c0 = lane & 15;
    int w = (blockIdx.x * 256 + threadIdx.x) >> 6;
    const int nw = (gridDim.x * 256) >> 6;
    for (int row = w; row < NN; row += nw) {
        int idx_reg = (lane < KS) ? samp[row * KS + lane] : 0;
        const ushort4 qv = *(const ushort4*)(Qp + (size_t)row * D + c0 * 4);
        float q0 = b2f(qv.x), q1 = b2f(qv.y), q2 = b2f(qv.z), q3 = b2f(qv.w);

        // group g handles samples g*5 .. g*5+4
        float s[5];
        ushort4 v4[5];
        #pragma unroll
        for (int t = 0; t < 5; ++t) {
            int idx = __shfl(idx_reg, g * 5 + t, 64);
            const ushort4 kk = *(const ushort4*)(Kp + (size_t)idx * D + c0 * 4);
            v4[t] = *(const ushort4*)(Vp + (size_t)idx * D + c0 * 4);
            float sc = q0 * b2f(kk.x);
            sc = fmaf(q1, b2f(kk.y), sc);
            sc = fmaf(q2, b2f(kk.z), sc);
            sc = fmaf(q3, b2f(kk.w), sc);
            // per-head dot: head = c0>>2 spans lanes (c0&~3)..(c0|3)
            sc += __shfl_xor(sc, 1, 64);
            sc += __shfl_xor(sc, 2, 64);
            s[t] = sc * 0.25f;   // 1/sqrt(DH=16)
        }
        // per-head softmax over 20 samples (5 local x 4 groups; xor16/32 keep c0 => within-head)
        float m = fmaxf(fmaxf(fmaxf(s[0], s[1]), fmaxf(s[2], s[3])), s[4]);
        m = fmaxf(m, __shfl_xor(m, 16, 64));
        m = fmaxf(m, __shfl_xor(m, 32, 64));
        float o0 = 0.f, o1 = 0.f, o2 = 0.f, o3 = 0.f, ssum = 0.f;
        #pragma unroll
        for (int t = 0; t < 5; ++t) {
            float p = __expf(s[t] - m);
            ssum += p;
            o0 = fmaf(p, b2f(v4[t].x), o0);
            o1 = fmaf(p, b2f(v4[t].y), o1);
            o2 = fmaf(p, b2f(v4[t].z), o2);
            o3 = fmaf(p, b2f(v4[t].w), o3);
        }
        ssum += __shfl_xor(ssum, 16, 64);
        ssum += __shfl_xor(ssum, 32, 64);
        float inv = 1.0f / ssum;
        o0 += __shfl_xor(o0, 16, 64); o0 += __shfl_xor(o0, 32, 64);
        o1 += __shfl_xor(o1, 16, 64); o1 += __shfl_xor(o1, 32, 64);
        o2 += __shfl_xor(o2, 16, 64); o2 += __shfl_xor(o2, 32, 64);
        o3 += __shfl_xor(o3, 16, 64); o3 += __shfl_xor(o3, 32, 64);
        if (g == 0) {
            ushort4 o;
            o.x = f2bu(o0 * inv); o.y = f2bu(o1 * inv);
            o.z = f2bu(o2 * inv); o.w = f2bu(o3 * inv);
            *(ushort4*)(ob + (size_t)row * D + c0 * 4) = o;
        }
    }
}

// ---------------- Wo projection + residual + LN1 via MFMA -> hb fp32 ----------------
__global__ __launch_bounds__(256) void k_attno_mfma(
    const unsigned short* __restrict__ ob, const float* __restrict__ x,
    const short* __restrict__ S,
    const float* __restrict__ bo, const float* __restrict__ g1,
    const float* __restrict__ be1,
    float* __restrict__ hb)
{
    const int lane = threadIdx.x & 63;
    const int c0 = lane & 15;
    const int g  = lane >> 4;
    const bf16x8* wp = (const bf16x8*)(S + OFF_WO);

    float bov[4], g1v[4], b1v[4];
    #pragma unroll
    for (int nt = 0; nt < 4; ++nt) {
        bov[nt] = bo[nt * 16 + c0];
        g1v[nt] = g1[nt * 16 + c0];
        b1v[nt] = be1[nt * 16 + c0];
    }

    int wid = (blockIdx.x * 256 + threadIdx.x) >> 6;
    const int nwaves = (gridDim.x * 256) >> 6;
    for (int tile = wid; tile < NN / 16; tile += nwaves) {
        const int row0 = tile * 16;
        bf16x8 a[2];
        #pragma unroll
        for (int kt = 0; kt < 2; ++kt)
            a[kt] = *(const bf16x8*)&ob[(size_t)(row0 + c0) * D + kt * 32 + g * 8];
        f32x4 acc[4];
        #pragma unroll
        for (int nt = 0; nt < 4; ++nt) {
            f32x4 c = {bov[nt], bov[nt], bov[nt], bov[nt]};
            #pragma unroll
            for (int kt = 0; kt < 2; ++kt)
                c = __builtin_amdgcn_mfma_f32_16x16x32_bf16(a[kt], wp[(nt * 2 + kt) * 64 + lane], c, 0, 0, 0);
            acc[nt] = c;
        }
        const int r0 = row0 + g * 4;
        #pragma unroll
        for (int r = 0; r < 4; ++r) {
            float rv[4];
            float s = 0.f;
            #pragma unroll
            for (int nt = 0; nt < 4; ++nt) {
                rv[nt] = acc[nt][r] + x[(size_t)(r0 + r) * D + nt * 16 + c0];
                s += rv[nt];
            }
            s = gsum16(s);
            float mu = s * (1.f / 64.f);
            float q = 0.f;
            #pragma unroll
            for (int nt = 0; nt < 4; ++nt) { float d = rv[nt] - mu; q += d * d; }
            q = gsum16(q);
            float inv = rsqrtf(q * (1.f / 64.f) + EPS);
            #pragma unroll
            for (int nt = 0; nt < 4; ++nt)
                hb[(size_t)(r0 + r) * D + nt * 16 + c0] = (rv[nt] - mu) * inv * g1v[nt] + b1v[nt];
        }
    }
}

// ---------------- FFN via MFMA -> bf16 h2 ----------------
__global__ __launch_bounds__(256) void k_ffn_mfma(
    const float* __restrict__ hb,
    const short* __restrict__ wf,
    const float* __restrict__ bf1, const float* __restrict__ bf2,
    const float* __restrict__ g2, const float* __restrict__ be2,
    unsigned short* __restrict__ h2b)
{
    __shared__ __align__(16) short Tl[4][16][264];
    const int lane = threadIdx.x & 63;
    const int wv   = threadIdx.x >> 6;
    const int c0   = lane & 15;
    const int g    = lane >> 4;
    const bf16x8* w1p = (const bf16x8*)(wf + OFF_W1);
    const bf16x8* w2p = (const bf16x8*)(wf + OFF_W2);

    float b1v[16];
    #pragma unroll
    for (int nt = 0; nt < 16; ++nt) b1v[nt] = bf1[nt * 16 + c0];
    float b2v[4], g2v[4], bev[4];
    #pragma unroll
    for (int nt = 0; nt < 4; ++nt) {
        b2v[nt] = bf2[nt * 16 + c0];
        g2v[nt] = g2[nt * 16 + c0];
        bev[nt] = be2[nt * 16 + c0];
    }

    int wid = (blockIdx.x * 256 + threadIdx.x) >> 6;
    const int nwaves = (gridDim.x * 256) >> 6;
    for (int tile = wid; tile < NN / 16; tile += nwaves) {
        const int row0 = tile * 16;
        const float* ar = hb + (size_t)(row0 + c0) * D + g * 8;
        bf16x8 a0, a1;
        {
            float4 f0 = *(const float4*)(ar);
            float4 f1 = *(const float4*)(ar + 4);
            float4 f2 = *(const float4*)(ar + 32);
            float4 f3 = *(const float4*)(ar + 36);
            a0[0] = f2b(f0.x); a0[1] = f2b(f0.y); a0[2] = f2b(f0.z); a0[3] = f2b(f0.w);
            a0[4] = f2b(f1.x); a0[5] = f2b(f1.y); a0[6] = f2b(f1.z); a0[7] = f2b(f1.w);
            a1[0] = f2b(f2.x); a1[1] = f2b(f2.y); a1[2] = f2b(f2.z); a1[3] = f2b(f2.w);
            a1[4] = f2b(f3.x); a1[5] = f2b(f3.y); a1[6] = f2b(f3.z); a1[7] = f2b(f3.w);
        }
        f32x4 acc1[16];
        #pragma unroll
        for (int nt = 0; nt < 16; ++nt) {
            float b = b1v[nt];
            f32x4 c = {b, b, b, b};
            c = __builtin_amdgcn_mfma_f32_16x16x32_bf16(a0, w1p[(nt * 2 + 0) * 64 + lane], c, 0, 0, 0);
            c = __builtin_amdgcn_mfma_f32_16x16x32_bf16(a1, w1p[(nt * 2 + 1) * 64 + lane], c, 0, 0, 0);
            acc1[nt] = c;
        }
        #pragma unroll
        for (int nt = 0; nt < 16; ++nt) {
            #pragma unroll
            for (int r = 0; r < 4; ++r)
                Tl[wv][g * 4 + r][nt * 16 + c0] = f2b(fmaxf(acc1[nt][r], 0.f));
        }
        bf16x8 a2[8];
        #pragma unroll
        for (int kt = 0; kt < 8; ++kt)
            a2[kt] = *(const bf16x8*)&Tl[wv][c0][kt * 32 + g * 8];
        f32x4 acc2[4];
        #pragma unroll
        for (int nt = 0; nt < 4; ++nt) {
            float b = b2v[nt];
            f32x4 c = {b, b, b, b};
            #pragma unroll
            for (int kt = 0; kt < 8; ++kt)
                c = __builtin_amdgcn_mfma_f32_16x16x32_bf16(a2[kt], w2p[(nt * 8 + kt) * 64 + lane], c, 0, 0, 0);
            acc2[nt] = c;
        }
        const int r0 = row0 + g * 4;
        #pragma unroll
        for (int r = 0; r < 4; ++r) {
            float rv[4];
            float s = 0.f;
            #pragma unroll
            for (int nt = 0; nt < 4; ++nt) {
                rv[nt] = acc2[nt][r] + hb[(size_t)(r0 + r) * D + nt * 16 + c0];
                s += rv[nt];
            }
            s = gsum16(s);
            float mu = s * (1.f / 64.f);
            float q = 0.f;
            #pragma unroll
            for (int nt = 0; nt < 4; ++nt) { float d = rv[nt] - mu; q += d * d; }
            q = gsum16(q);
            float inv = rsqrtf(q * (1.f / 64.f) + EPS);
            #pragma unroll
            for (int nt = 0; nt < 4; ++nt)
                h2b[(size_t)(r0 + r) * D + nt * 16 + c0] = f2bu((rv[nt] - mu) * inv * g2v[nt] + bev[nt]);
        }
    }
}

// ---------------- GNN linear (MFMA, bf16 inputs) + relu + residual + LN -> fp32 out ----------------
__global__ __launch_bounds__(256) void k_gnn_mfma(
    const unsigned short* __restrict__ h2b, const unsigned short* __restrict__ hnb,
    const short* __restrict__ S,
    const float* __restrict__ bg, const float* __restrict__ gg,
    const float* __restrict__ bgn,
    float* __restrict__ out)
{
    const int lane = threadIdx.x & 63;
    const int c0 = lane & 15;
    const int g  = lane >> 4;
    const bf16x8* wp = (const bf16x8*)(S + OFF_WG);

    float bgv[4], ggv[4], bnv[4];
    #pragma unroll
    for (int nt = 0; nt < 4; ++nt) {
        bgv[nt] = bg[nt * 16 + c0];
        ggv[nt] = gg[nt * 16 + c0];
        bnv[nt] = bgn[nt * 16 + c0];
    }

    int wid = (blockIdx.x * 256 + threadIdx.x) >> 6;
    const int nwaves = (gridDim.x * 256) >> 6;
    for (int tile = wid; tile < NN / 16; tile += nwaves) {
        const int row0 = tile * 16;
        bf16x8 a[4];
        #pragma unroll
        for (int kt = 0; kt < 2; ++kt) {
            a[kt]     = *(const bf16x8*)&h2b[(size_t)(row0 + c0) * 64 + kt * 32 + g * 8];
            a[2 + kt] = *(const bf16x8*)&hnb[(size_t)(row0 + c0) * 64 + kt * 32 + g * 8];
        }
        f32x4 acc[4];
        #pragma unroll
        for (int nt = 0; nt < 4; ++nt) {
            float b = bgv[nt];
            f32x4 c = {b, b, b, b};
            #pragma unroll
            for (int kt = 0; kt < 4; ++kt)
                c = __builtin_amdgcn_mfma_f32_16x16x32_bf16(a[kt], wp[(nt * 4 + kt) * 64 + lane], c, 0, 0, 0);
            acc[nt] = c;
        }
        const int r0 = row0 + g * 4;
        #pragma unroll
        for (int r = 0; r < 4; ++r) {
            float rv[4];
            float s = 0.f;
            #pragma unroll
            for (int nt = 0; nt < 4; ++nt) {
                float hn = fmaxf(acc[nt][r], 0.f);
                rv[nt] = hn + b2f(h2b[(size_t)(r0 + r) * 64 + nt * 16 + c0]);
                s += rv[nt];
            }
            s = gsum16(s);
            float mu = s * (1.f / 64.f);
            float q = 0.f;
            #pragma unroll
            for (int nt = 0; nt < 4; ++nt) { float d = rv[nt] - mu; q += d * d; }
            q = gsum16(q);
            float inv = rsqrtf(q * (1.f / 64.f) + EPS);
            #pragma unroll
            for (int nt = 0; nt < 4; ++nt)
                out[(size_t)(r0 + r) * D + nt * 16 + c0] = (rv[nt] - mu) * inv * ggv[nt] + bnv[nt];
        }
    }
}

// ---------------- attention_samples passthrough (as fp32) ----------------
__global__ __launch_bounds__(256) void k_samples(
    const int* __restrict__ samp, float* __restrict__ out, int n)
{
    int i = blockIdx.x * blockDim.x + threadIdx.x;
    const int stride = gridDim.x * blockDim.x;
    for (; i < n; i += stride) out[i] = (float)samp[i];
}

extern "C" void kernel_launch(void* const* d_in, const int* in_sizes, int n_in,
                              void* d_out, int out_size, void* d_ws, size_t ws_size,
                              hipStream_t stream)
{
    const float* x   = (const float*)d_in[0];
    const int*   rows = (const int*)d_in[1];
    const int*   cols = (const int*)d_in[2];
    const float* ev  = (const float*)d_in[3];
    const int*   samp = (const int*)d_in[4];
    const float* Wq  = (const float*)d_in[5];
    const float* bq  = (const float*)d_in[6];
    const float* Wk  = (const float*)d_in[7];
    const float* bk  = (const float*)d_in[8];
    const float* Wv  = (const float*)d_in[9];
    const float* bv  = (const float*)d_in[10];
    const float* Wo  = (const float*)d_in[11];
    const float* bo  = (const float*)d_in[12];
    const float* g1  = (const float*)d_in[13];
    const float* be1 = (const float*)d_in[14];
    const float* g2  = (const float*)d_in[15];
    const float* be2 = (const float*)d_in[16];
    const float* W1  = (const float*)d_in[17];
    const float* bf1 = (const float*)d_in[18];
    const float* W2  = (const float*)d_in[19];
    const float* bf2 = (const float*)d_in[20];
    const float* Wg  = (const float*)d_in[21];
    const float* bg  = (const float*)d_in[22];
    const float* gg  = (const float*)d_in[23];
    const float* bgn = (const float*)d_in[24];
    const int E = in_sizes[1];

    // ws layout: 3 buffers of NN*D floats (76.8 MB)
    float* buf0 = (float*)d_ws;                   // [Kp_b | Vp_b] bf16 -> payload (int2[E])
    float* buf1 = buf0 + (size_t)NN * D;          // [Qp_b -> hnb_b | ob -> h2b] bf16
    float* buf2 = buf1 + (size_t)NN * D;          // hb fp32 -> part (int2[E])
    unsigned short* Kp_b = (unsigned short*)buf0;
    unsigned short* Vp_b = Kp_b + (size_t)NN * D;
    int2* payload = (int2*)buf0;                       // overwrites Kp/Vp after attn
    unsigned short* Qp_b  = (unsigned short*)buf1;     // dead after attn -> hnb slot
    unsigned short* hnb_b = (unsigned short*)buf1;
    unsigned short* ob    = (unsigned short*)(buf1 + (size_t)NN * D / 2); // dead after attno -> h2b slot
    unsigned short* h2b   = ob;
    float* hb = buf2;
    int2* part = (int2*)buf2;                          // overwrites hb after ffn

    float* out = (float*)d_out;
    // scratch in samples region of d_out (rewritten by k_samples each call)
    short* S     = (short*)(out + (size_t)NN * D);   // S_TOTAL shorts
    int* offsets = (int*)(S + S_TOTAL);              // NN+1
    int* bcnt    = offsets + NN + 1;                 // NB
    int* bbase   = bcnt + NB;                        // NB+1
    int* bcur    = bbase + NB + 1;                   // NB

    k_prep<<<56, 256, 0, stream>>>(W1, W2, Wg, Wq, Wk, Wv, Wo, S);
    hipMemsetAsync(bcnt, 0, (size_t)NB * sizeof(int), stream);
    k_bhist<<<4096, 256, 0, stream>>>(rows, bcnt, E);
    k_bscan<<<1, 256, 0, stream>>>(bcnt, bbase, bcur, offsets);
    k_projqkv_mfma<<<1563, 256, 0, stream>>>(x, S, bq, bk, bv, Qp_b, Kp_b, Vp_b);
    k_attn_lite<<<4096, 256, 0, stream>>>(Qp_b, Kp_b, Vp_b, samp, ob);
    k_attno_mfma<<<1563, 256, 0, stream>>>(ob, x, S, bo, g1, be1, hb);
    k_ffn_mfma<<<1563, 256, 0, stream>>>(hb, S, bf1, bf2, g2, be2, h2b);
    k_part<<<(E + PCHUNK - 1) / PCHUNK, 256, 0, stream>>>(rows, cols, ev, bcur, part, E);
    k_fill2<<<NB, 256, 0, stream>>>(bbase, part, offsets, payload);
    k_gather<<<4096, 256, 0, stream>>>(offsets, payload, h2b, hnb_b);
    k_gnn_mfma<<<1563, 256, 0, stream>>>(h2b, hnb_b, S, bg, gg, bgn, out);
    k_samples<<<2048, 256, 0, stream>>>(samp, out + (size_t)NN * D, NN * KS);
}

// Round 11
// 416.400 us; speedup vs baseline: 6.5784x; 1.0753x over previous
//
#include <hip/hip_runtime.h>
#include <hip/hip_bf16.h>

#define NN  100000
#define D   64
#define KS  20
#define DFF 256
#define EPS 1e-5f

// radix-partition params
#define BROWS  512
#define NB     ((NN + BROWS - 1) / BROWS)   // 196 buckets
#define PCHUNK 8192                          // edges per chunk (k_bhist & k_part)

// frag-buffer offsets (shorts)
#define OFF_W1 0
#define OFF_W2 16384
#define OFF_WG 32768
#define OFF_WQ 40960
#define OFF_WK 45056
#define OFF_WV 49152
#define OFF_WO 53248
#define S_TOTAL 57344

typedef __attribute__((ext_vector_type(8))) short bf16x8;
typedef __attribute__((ext_vector_type(4))) float f32x4;

__device__ __forceinline__ short f2b(float f) {
    return __builtin_bit_cast(short, __float2bfloat16(f));
}
__device__ __forceinline__ unsigned short f2bu(float f) {
    return __builtin_bit_cast(unsigned short, __float2bfloat16(f));
}
__device__ __forceinline__ float b2f(unsigned short u) {
    return __builtin_bit_cast(float, ((unsigned)u) << 16);
}
__device__ __forceinline__ float gsum16(float v) {
    v += __shfl_xor(v, 1, 64);
    v += __shfl_xor(v, 2, 64);
    v += __shfl_xor(v, 4, 64);
    v += __shfl_xor(v, 8, 64);
    return v;
}

// ---------------- weight fragment prep (bf16, B-operand layout) ----------------
// B-frag: lane l, elem i -> B[k][n], n = nt*16 + (l&15), k = kt*32 + (l>>4)*8 + i
__global__ __launch_bounds__(256) void k_prep(
    const float* __restrict__ W1, const float* __restrict__ W2,
    const float* __restrict__ Wg,
    const float* __restrict__ Wq, const float* __restrict__ Wk,
    const float* __restrict__ Wv, const float* __restrict__ Wo,
    short* __restrict__ S)
{
    int idx = blockIdx.x * 256 + threadIdx.x;
    for (; idx < S_TOTAL; idx += gridDim.x * 256) {
        float v;
        if (idx < OFF_W2) {                 // W1 [64 x 256]
            int f = idx >> 9, rem = idx & 511;
            int l = rem >> 3, i = rem & 7;
            int nt = f >> 1, kt = f & 1;
            v = W1[(kt * 32 + (l >> 4) * 8 + i) * DFF + nt * 16 + (l & 15)];
        } else if (idx < OFF_WG) {          // W2 [256 x 64]
            int j = idx - OFF_W2;
            int f = j >> 9, rem = j & 511;
            int l = rem >> 3, i = rem & 7;
            int nt = f >> 3, kt = f & 7;
            v = W2[(kt * 32 + (l >> 4) * 8 + i) * D + nt * 16 + (l & 15)];
        } else if (idx < OFF_WQ) {          // Wg [128 x 64]
            int j = idx - OFF_WG;
            int f = j >> 9, rem = j & 511;
            int l = rem >> 3, i = rem & 7;
            int nt = f >> 2, kt = f & 3;
            v = Wg[(kt * 32 + (l >> 4) * 8 + i) * D + nt * 16 + (l & 15)];
        } else {                            // Wq/Wk/Wv/Wo [64 x 64]
            int j = idx - OFF_WQ;
            const float* W = (j < 4096) ? Wq : (j < 8192) ? Wk : (j < 12288) ? Wv : Wo;
            j &= 4095;
            int f = j >> 9, rem = j & 511;
            int l = rem >> 3, i = rem & 7;
            int nt = f >> 1, kt = f & 1;
            v = W[(kt * 32 + (l >> 4) * 8 + i) * D + nt * 16 + (l & 15)];
        }
        S[idx] = f2b(v);
    }
}

// ---------------- per-chunk bucket histogram (dense write, NO global atomics) ----------------
__global__ __launch_bounds__(256) void k_bhist(
    const int* __restrict__ rows, int* __restrict__ partial, int E)
{
    __shared__ int h[NB];
    for (int t = threadIdx.x; t < NB; t += 256) h[t] = 0;
    __syncthreads();
    const int i0 = blockIdx.x * PCHUNK;
    const int n = min(PCHUNK, E - i0);
    for (int t = threadIdx.x; t < n; t += 256)
        atomicAdd(&h[__builtin_nontemporal_load(rows + i0 + t) >> 9], 1);
    __syncthreads();
    for (int t = threadIdx.x; t < NB; t += 256)
        partial[blockIdx.x * NB + t] = h[t];
}

// ---------------- 2D prefix: bbase (bucket scan) + per-chunk bases in-place ----------------
__global__ __launch_bounds__(256) void k_pscan(
    int* __restrict__ partial, int* __restrict__ bbase,
    int* __restrict__ offsets, int npb)
{
    __shared__ int wsum[4];
    const int t = threadIdx.x;
    const int lane = t & 63, wv = t >> 6;
    int total = 0;
    if (t < NB)
        for (int p = 0; p < npb; ++p) total += partial[p * NB + t];
    int sv = total;
    #pragma unroll
    for (int off = 1; off < 64; off <<= 1) {
        int u = __shfl_up(sv, off, 64);
        if (lane >= off) sv += u;
    }
    if (lane == 63) wsum[wv] = sv;
    __syncthreads();
    int wofs = 0;
    for (int k = 0; k < wv; ++k) wofs += wsum[k];
    int excl = wofs + sv - total;
    if (t < NB) bbase[t] = excl;
    if (t == 0) {
        int tot = wsum[0] + wsum[1] + wsum[2] + wsum[3];
        bbase[NB] = tot;
        offsets[NN] = tot;
    }
    if (t < NB) {
        int run = excl;
        for (int p = 0; p < npb; ++p) {
            int c = partial[p * NB + t];
            partial[p * NB + t] = run;
            run += c;
        }
    }
}

// ---------------- phase 1: radix-partition edges by bucket (row>>9) ----------------
// Per-chunk bases precomputed by k_pscan -> zero global atomics; single pass.
__global__ __launch_bounds__(256) void k_part(
    const int* __restrict__ rows, const int* __restrict__ cols,
    const float* __restrict__ ev, const int* __restrict__ pbase,
    int2* __restrict__ part, int E)
{
    __shared__ int base[NB];
    __shared__ int lcnt[NB];
    const int tid = threadIdx.x;
    const int i0 = blockIdx.x * PCHUNK;
    const int n = min(PCHUNK, E - i0);
    for (int t = tid; t < NB; t += 256) {
        base[t] = pbase[blockIdx.x * NB + t];
        lcnt[t] = 0;
    }
    __syncthreads();
    for (int t = tid; t < n; t += 256) {
        int r = __builtin_nontemporal_load(rows + i0 + t);
        int c = __builtin_nontemporal_load(cols + i0 + t);
        float w = __builtin_nontemporal_load(ev + i0 + t);
        int b = r >> 9;
        int lpos = atomicAdd(&lcnt[b], 1);
        part[base[b] + lpos] = make_int2(((r & (BROWS - 1)) << 17) | c, __float_as_int(w));
    }
}

// ---------------- phase 2: in-bucket row offsets (LDS scan) + final placement ----------------
__global__ __launch_bounds__(256) void k_fill2(
    const int* __restrict__ bbase, const int2* __restrict__ part,
    int* __restrict__ offsets, int2* __restrict__ payload)
{
    __shared__ int lcnt[BROWS];
    __shared__ int lcur[BROWS];
    __shared__ int wsum[4];
    const int b = blockIdx.x;
    const int row0 = b * BROWS;
    const int nrows = min(BROWS, NN - row0);
    const int tid = threadIdx.x;
    for (int t = tid; t < BROWS; t += 256) lcnt[t] = 0;
    __syncthreads();
    const int e0 = bbase[b], e1 = bbase[b + 1];
    for (int i = e0 + tid; i < e1; i += 256)
        atomicAdd(&lcnt[(unsigned)part[i].x >> 17], 1);
    __syncthreads();
    // exclusive scan of 512 LDS counters: thread t owns pair (2t, 2t+1)
    int c0 = lcnt[2 * tid], c1 = lcnt[2 * tid + 1];
    int s = c0 + c1;
    const int lane = tid & 63, wv = tid >> 6;
    int sv = s;
    #pragma unroll
    for (int off = 1; off < 64; off <<= 1) {
        int u = __shfl_up(sv, off, 64);
        if (lane >= off) sv += u;
    }
    if (lane == 63) wsum[wv] = sv;
    __syncthreads();
    int wofs = 0;
    for (int k = 0; k < wv; ++k) wofs += wsum[k];
    int o0 = e0 + wofs + sv - s;
    int o1 = o0 + c0;
    lcur[2 * tid] = o0;
    lcur[2 * tid + 1] = o1;
    if (2 * tid < nrows)     offsets[row0 + 2 * tid]     = o0;
    if (2 * tid + 1 < nrows) offsets[row0 + 2 * tid + 1] = o1;
    __syncthreads();
    for (int i = e0 + tid; i < e1; i += 256) {
        int2 rec = part[i];
        int rowoff = (unsigned)rec.x >> 17;
        int pos = atomicAdd(&lcur[rowoff], 1);
        payload[pos] = make_int2(rec.x & 0x1FFFF, rec.y);
    }
}

// ---------------- segment gather-reduce (2-deep pipelined) ----------------
__global__ __launch_bounds__(256) void k_gather(
    const int* __restrict__ offsets, const int2* __restrict__ payload,
    const unsigned short* __restrict__ h2b, unsigned short* __restrict__ hnb)
{
    const int lane = threadIdx.x & 63;
    const int g = lane >> 4, c0 = lane & 15;
    int w = (blockIdx.x * 256 + threadIdx.x) >> 6;
    const int nw = (gridDim.x * 256) >> 6;
    for (int row = w; row < NN; row += nw) {
        const int b = offsets[row], e = offsets[row + 1];
        float ax = 0.f, ay = 0.f, az = 0.f, aw = 0.f;
        int i = b + g;
        for (; i + 4 < e; i += 8) {
            int2 p0 = payload[i];
            int2 p1 = payload[i + 4];
            float w0 = __int_as_float(p0.y);
            float w1 = __int_as_float(p1.y);
            const ushort4 u0 = *(const ushort4*)(h2b + (size_t)p0.x * 64 + c0 * 4);
            const ushort4 u1 = *(const ushort4*)(h2b + (size_t)p1.x * 64 + c0 * 4);
            ax = fmaf(b2f(u0.x), w0, ax); ay = fmaf(b2f(u0.y), w0, ay);
            az = fmaf(b2f(u0.z), w0, az); aw = fmaf(b2f(u0.w), w0, aw);
            ax = fmaf(b2f(u1.x), w1, ax); ay = fmaf(b2f(u1.y), w1, ay);
            az = fmaf(b2f(u1.z), w1, az); aw = fmaf(b2f(u1.w), w1, aw);
        }
        if (i < e) {
            int2 p = payload[i];
            float wt = __int_as_float(p.y);
            const ushort4 u = *(const ushort4*)(h2b + (size_t)p.x * 64 + c0 * 4);
            ax = fmaf(b2f(u.x), wt, ax); ay = fmaf(b2f(u.y), wt, ay);
            az = fmaf(b2f(u.z), wt, az); aw = fmaf(b2f(u.w), wt, aw);
        }
        ax += __shfl_xor(ax, 16, 64); ax += __shfl_xor(ax, 32, 64);
        ay += __shfl_xor(ay, 16, 64); ay += __shfl_xor(ay, 32, 64);
        az += __shfl_xor(az, 16, 64); az += __shfl_xor(az, 32, 64);
        aw += __shfl_xor(aw, 16, 64); aw += __shfl_xor(aw, 32, 64);
        if (g == 0) {
            ushort4 o;
            o.x = f2bu(ax); o.y = f2bu(ay); o.z = f2bu(az); o.w = f2bu(aw);
            *(ushort4*)(hnb + (size_t)row * 64 + c0 * 4) = o;
        }
    }
}

// ---------------- Q/K/V projection via MFMA -> bf16 ----------------
__global__ __launch_bounds__(256) void k_projqkv_mfma(
    const float* __restrict__ x, const short* __restrict__ S,
    const float* __restrict__ bq, const float* __restrict__ bk,
    const float* __restrict__ bv,
    unsigned short* __restrict__ Qp, unsigned short* __restrict__ Kp,
    unsigned short* __restrict__ Vp)
{
    const int lane = threadIdx.x & 63;
    const int c0 = lane & 15;
    const int g  = lane >> 4;
    const bf16x8* wq = (const bf16x8*)(S + OFF_WQ);
    const bf16x8* wk = (const bf16x8*)(S + OFF_WK);
    const bf16x8* wv = (const bf16x8*)(S + OFF_WV);

    float bqv[4], bkv[4], bvv[4];
    #pragma unroll
    for (int nt = 0; nt < 4; ++nt) {
        bqv[nt] = bq[nt * 16 + c0];
        bkv[nt] = bk[nt * 16 + c0];
        bvv[nt] = bv[nt * 16 + c0];
    }

    int wid = (blockIdx.x * 256 + threadIdx.x) >> 6;
    const int nwaves = (gridDim.x * 256) >> 6;
    for (int tile = wid; tile < NN / 16; tile += nwaves) {
        const int row0 = tile * 16;
        const float* ar = x + (size_t)(row0 + c0) * D + g * 8;
        bf16x8 a0, a1;
        {
            float4 f0 = *(const float4*)(ar);
            float4 f1 = *(const float4*)(ar + 4);
            float4 f2 = *(const float4*)(ar + 32);
            float4 f3 = *(const float4*)(ar + 36);
            a0[0] = f2b(f0.x); a0[1] = f2b(f0.y); a0[2] = f2b(f0.z); a0[3] = f2b(f0.w);
            a0[4] = f2b(f1.x); a0[5] = f2b(f1.y); a0[6] = f2b(f1.z); a0[7] = f2b(f1.w);
            a1[0] = f2b(f2.x); a1[1] = f2b(f2.y); a1[2] = f2b(f2.z); a1[3] = f2b(f2.w);
            a1[4] = f2b(f3.x); a1[5] = f2b(f3.y); a1[6] = f2b(f3.z); a1[7] = f2b(f3.w);
        }
        f32x4 aq[4], ak[4], av[4];
        #pragma unroll
        for (int nt = 0; nt < 4; ++nt) {
            f32x4 cq = {bqv[nt], bqv[nt], bqv[nt], bqv[nt]};
            cq = __builtin_amdgcn_mfma_f32_16x16x32_bf16(a0, wq[(nt * 2 + 0) * 64 + lane], cq, 0, 0, 0);
            cq = __builtin_amdgcn_mfma_f32_16x16x32_bf16(a1, wq[(nt * 2 + 1) * 64 + lane], cq, 0, 0, 0);
            aq[nt] = cq;
            f32x4 ck = {bkv[nt], bkv[nt], bkv[nt], bkv[nt]};
            ck = __builtin_amdgcn_mfma_f32_16x16x32_bf16(a0, wk[(nt * 2 + 0) * 64 + lane], ck, 0, 0, 0);
            ck = __builtin_amdgcn_mfma_f32_16x16x32_bf16(a1, wk[(nt * 2 + 1) * 64 + lane], ck, 0, 0, 0);
            ak[nt] = ck;
            f32x4 cv = {bvv[nt], bvv[nt], bvv[nt], bvv[nt]};
            cv = __builtin_amdgcn_mfma_f32_16x16x32_bf16(a0, wv[(nt * 2 + 0) * 64 + lane], cv, 0, 0, 0);
            cv = __builtin_amdgcn_mfma_f32_16x16x32_bf16(a1, wv[(nt * 2 + 1) * 64 + lane], cv, 0, 0, 0);
            av[nt] = cv;
        }
        const int r0 = row0 + g * 4;
        #pragma unroll
        for (int r = 0; r < 4; ++r) {
            #pragma unroll
            for (int nt = 0; nt < 4; ++nt) {
                Qp[(size_t)(r0 + r) * D + nt * 16 + c0] = f2bu(aq[nt][r]);
                Kp[(size_t)(r0 + r) * D + nt * 16 + c0] = f2bu(ak[nt][r]);
                Vp[(size_t)(r0 + r) * D + nt * 16 + c0] = f2bu(av[nt][r]);
            }
        }
    }
}

// ---------------- attention core: gathers + per-head softmax + PV -> ob (bf16) ----------------
__global__ __launch_bounds__(256) void k_attn_lite(
    const unsigned short* __restrict__ Qp,
    const unsigned short* __restrict__ Kp, const unsigned short* __restrict__ Vp,
    const int* __restrict__ samp, unsigned short* __restrict__ ob)
{
    const int lane = threadIdx.x & 63;
    const int g = lane >> 4, c0 = lane & 15;
    int w = (blockIdx.x * 256 + threadIdx.x) >> 6;
    const int nw = (gridDim.x * 256) >> 6;
    for (int row = w; row < NN; row += nw) {
        int idx_reg = (lane < KS) ? samp[row * KS + lane] : 0;
        const ushort4 qv = *(const ushort4*)(Qp + (size_t)row * D + c0 * 4);
        float q0 = b2f(qv.x), q1 = b2f(qv.y), q2 = b2f(qv.z), q3 = b2f(qv.w);

        // group g handles samples g*5 .. g*5+4
        float s[5];
        ushort4 v4[5];
        #pragma unroll
        for (int t = 0; t < 5; ++t) {
            int idx = __shfl(idx_reg, g * 5 + t, 64);
            const ushort4 kk = *(const ushort4*)(Kp + (size_t)idx * D + c0 * 4);
            v4[t] = *(const ushort4*)(Vp + (size_t)idx * D + c0 * 4);
            float sc = q0 * b2f(kk.x);
            sc = fmaf(q1, b2f(kk.y), sc);
            sc = fmaf(q2, b2f(kk.z), sc);
            sc = fmaf(q3, b2f(kk.w), sc);
            // per-head dot: head = c0>>2 spans lanes (c0&~3)..(c0|3)
            sc += __shfl_xor(sc, 1, 64);
            sc += __shfl_xor(sc, 2, 64);
            s[t] = sc * 0.25f;   // 1/sqrt(DH=16)
        }
        // per-head softmax over 20 samples (5 local x 4 groups; xor16/32 keep c0 => within-head)
        float m = fmaxf(fmaxf(fmaxf(s[0], s[1]), fmaxf(s[2], s[3])), s[4]);
        m = fmaxf(m, __shfl_xor(m, 16, 64));
        m = fmaxf(m, __shfl_xor(m, 32, 64));
        float o0 = 0.f, o1 = 0.f, o2 = 0.f, o3 = 0.f, ssum = 0.f;
        #pragma unroll
        for (int t = 0; t < 5; ++t) {
            float p = __expf(s[t] - m);
            ssum += p;
            o0 = fmaf(p, b2f(v4[t].x), o0);
            o1 = fmaf(p, b2f(v4[t].y), o1);
            o2 = fmaf(p, b2f(v4[t].z), o2);
            o3 = fmaf(p, b2f(v4[t].w), o3);
        }
        ssum += __shfl_xor(ssum, 16, 64);
        ssum += __shfl_xor(ssum, 32, 64);
        float inv = 1.0f / ssum;
        o0 += __shfl_xor(o0, 16, 64); o0 += __shfl_xor(o0, 32, 64);
        o1 += __shfl_xor(o1, 16, 64); o1 += __shfl_xor(o1, 32, 64);
        o2 += __shfl_xor(o2, 16, 64); o2 += __shfl_xor(o2, 32, 64);
        o3 += __shfl_xor(o3, 16, 64); o3 += __shfl_xor(o3, 32, 64);
        if (g == 0) {
            ushort4 o;
            o.x = f2bu(o0 * inv); o.y = f2bu(o1 * inv);
            o.z = f2bu(o2 * inv); o.w = f2bu(o3 * inv);
            *(ushort4*)(ob + (size_t)row * D + c0 * 4) = o;
        }
    }
}

// ---------------- Wo projection + residual + LN1 via MFMA -> hb fp32 ----------------
__global__ __launch_bounds__(256) void k_attno_mfma(
    const unsigned short* __restrict__ ob, const float* __restrict__ x,
    const short* __restrict__ S,
    const float* __restrict__ bo, const float* __restrict__ g1,
    const float* __restrict__ be1,
    float* __restrict__ hb)
{
    const int lane = threadIdx.x & 63;
    const int c0 = lane & 15;
    const int g  = lane >> 4;
    const bf16x8* wp = (const bf16x8*)(S + OFF_WO);

    float bov[4], g1v[4], b1v[4];
    #pragma unroll
    for (int nt = 0; nt < 4; ++nt) {
        bov[nt] = bo[nt * 16 + c0];
        g1v[nt] = g1[nt * 16 + c0];
        b1v[nt] = be1[nt * 16 + c0];
    }

    int wid = (blockIdx.x * 256 + threadIdx.x) >> 6;
    const int nwaves = (gridDim.x * 256) >> 6;
    for (int tile = wid; tile < NN / 16; tile += nwaves) {
        const int row0 = tile * 16;
        bf16x8 a[2];
        #pragma unroll
        for (int kt = 0; kt < 2; ++kt)
            a[kt] = *(const bf16x8*)&ob[(size_t)(row0 + c0) * D + kt * 32 + g * 8];
        f32x4 acc[4];
        #pragma unroll
        for (int nt = 0; nt < 4; ++nt) {
            f32x4 c = {bov[nt], bov[nt], bov[nt], bov[nt]};
            #pragma unroll
            for (int kt = 0; kt < 2; ++kt)
                c = __builtin_amdgcn_mfma_f32_16x16x32_bf16(a[kt], wp[(nt * 2 + kt) * 64 + lane], c, 0, 0, 0);
            acc[nt] = c;
        }
        const int r0 = row0 + g * 4;
        #pragma unroll
        for (int r = 0; r < 4; ++r) {
            float rv[4];
            float s = 0.f;
            #pragma unroll
            for (int nt = 0; nt < 4; ++nt) {
                rv[nt] = acc[nt][r] + x[(size_t)(r0 + r) * D + nt * 16 + c0];
                s += rv[nt];
            }
            s = gsum16(s);
            float mu = s * (1.f / 64.f);
            float q = 0.f;
            #pragma unroll
            for (int nt = 0; nt < 4; ++nt) { float d = rv[nt] - mu; q += d * d; }
            q = gsum16(q);
            float inv = rsqrtf(q * (1.f / 64.f) + EPS);
            #pragma unroll
            for (int nt = 0; nt < 4; ++nt)
                hb[(size_t)(r0 + r) * D + nt * 16 + c0] = (rv[nt] - mu) * inv * g1v[nt] + b1v[nt];
        }
    }
}

// ---------------- FFN via MFMA -> bf16 h2 ----------------
__global__ __launch_bounds__(256) void k_ffn_mfma(
    const float* __restrict__ hb,
    const short* __restrict__ wf,
    const float* __restrict__ bf1, const float* __restrict__ bf2,
    const float* __restrict__ g2, const float* __restrict__ be2,
    unsigned short* __restrict__ h2b)
{
    __shared__ __align__(16) short Tl[4][16][264];
    const int lane = threadIdx.x & 63;
    const int wv   = threadIdx.x >> 6;
    const int c0   = lane & 15;
    const int g    = lane >> 4;
    const bf16x8* w1p = (const bf16x8*)(wf + OFF_W1);
    const bf16x8* w2p = (const bf16x8*)(wf + OFF_W2);

    float b1v[16];
    #pragma unroll
    for (int nt = 0; nt < 16; ++nt) b1v[nt] = bf1[nt * 16 + c0];
    float b2v[4], g2v[4], bev[4];
    #pragma unroll
    for (int nt = 0; nt < 4; ++nt) {
        b2v[nt] = bf2[nt * 16 + c0];
        g2v[nt] = g2[nt * 16 + c0];
        bev[nt] = be2[nt * 16 + c0];
    }

    int wid = (blockIdx.x * 256 + threadIdx.x) >> 6;
    const int nwaves = (gridDim.x * 256) >> 6;
    for (int tile = wid; tile < NN / 16; tile += nwaves) {
        const int row0 = tile * 16;
        const float* ar = hb + (size_t)(row0 + c0) * D + g * 8;
        bf16x8 a0, a1;
        {
            float4 f0 = *(const float4*)(ar);
            float4 f1 = *(const float4*)(ar + 4);
            float4 f2 = *(const float4*)(ar + 32);
            float4 f3 = *(const float4*)(ar + 36);
            a0[0] = f2b(f0.x); a0[1] = f2b(f0.y); a0[2] = f2b(f0.z); a0[3] = f2b(f0.w);
            a0[4] = f2b(f1.x); a0[5] = f2b(f1.y); a0[6] = f2b(f1.z); a0[7] = f2b(f1.w);
            a1[0] = f2b(f2.x); a1[1] = f2b(f2.y); a1[2] = f2b(f2.z); a1[3] = f2b(f2.w);
            a1[4] = f2b(f3.x); a1[5] = f2b(f3.y); a1[6] = f2b(f3.z); a1[7] = f2b(f3.w);
        }
        f32x4 acc1[16];
        #pragma unroll
        for (int nt = 0; nt < 16; ++nt) {
            float b = b1v[nt];
            f32x4 c = {b, b, b, b};
            c = __builtin_amdgcn_mfma_f32_16x16x32_bf16(a0, w1p[(nt * 2 + 0) * 64 + lane], c, 0, 0, 0);
            c = __builtin_amdgcn_mfma_f32_16x16x32_bf16(a1, w1p[(nt * 2 + 1) * 64 + lane], c, 0, 0, 0);
            acc1[nt] = c;
        }
        #pragma unroll
        for (int nt = 0; nt < 16; ++nt) {
            #pragma unroll
            for (int r = 0; r < 4; ++r)
                Tl[wv][g * 4 + r][nt * 16 + c0] = f2b(fmaxf(acc1[nt][r], 0.f));
        }
        bf16x8 a2[8];
        #pragma unroll
        for (int kt = 0; kt < 8; ++kt)
            a2[kt] = *(const bf16x8*)&Tl[wv][c0][kt * 32 + g * 8];
        f32x4 acc2[4];
        #pragma unroll
        for (int nt = 0; nt < 4; ++nt) {
            float b = b2v[nt];
            f32x4 c = {b, b, b, b};
            #pragma unroll
            for (int kt = 0; kt < 8; ++kt)
                c = __builtin_amdgcn_mfma_f32_16x16x32_bf16(a2[kt], w2p[(nt * 8 + kt) * 64 + lane], c, 0, 0, 0);
            acc2[nt] = c;
        }
        const int r0 = row0 + g * 4;
        #pragma unroll
        for (int r = 0; r < 4; ++r) {
            float rv[4];
            float s = 0.f;
            #pragma unroll
            for (int nt = 0; nt < 4; ++nt) {
                rv[nt] = acc2[nt][r] + hb[(size_t)(r0 + r) * D + nt * 16 + c0];
                s += rv[nt];
            }
            s = gsum16(s);
            float mu = s * (1.f / 64.f);
            float q = 0.f;
            #pragma unroll
            for (int nt = 0; nt < 4; ++nt) { float d = rv[nt] - mu; q += d * d; }
            q = gsum16(q);
            float inv = rsqrtf(q * (1.f / 64.f) + EPS);
            #pragma unroll
            for (int nt = 0; nt < 4; ++nt)
                h2b[(size_t)(r0 + r) * D + nt * 16 + c0] = f2bu((rv[nt] - mu) * inv * g2v[nt] + bev[nt]);
        }
    }
}

// ---------------- GNN linear (MFMA, bf16 inputs) + relu + residual + LN -> fp32 out ----------------
__global__ __launch_bounds__(256) void k_gnn_mfma(
    const unsigned short* __restrict__ h2b, const unsigned short* __restrict__ hnb,
    const short* __restrict__ S,
    const float* __restrict__ bg, const float* __restrict__ gg,
    const float* __restrict__ bgn,
    float* __restrict__ out)
{
    const int lane = threadIdx.x & 63;
    const int c0 = lane & 15;
    const int g  = lane >> 4;
    const bf16x8* wp = (const bf16x8*)(S + OFF_WG);

    float bgv[4], ggv[4], bnv[4];
    #pragma unroll
    for (int nt = 0; nt < 4; ++nt) {
        bgv[nt] = bg[nt * 16 + c0];
        ggv[nt] = gg[nt * 16 + c0];
        bnv[nt] = bgn[nt * 16 + c0];
    }

    int wid = (blockIdx.x * 256 + threadIdx.x) >> 6;
    const int nwaves = (gridDim.x * 256) >> 6;
    for (int tile = wid; tile < NN / 16; tile += nwaves) {
        const int row0 = tile * 16;
        bf16x8 a[4];
        #pragma unroll
        for (int kt = 0; kt < 2; ++kt) {
            a[kt]     = *(const bf16x8*)&h2b[(size_t)(row0 + c0) * 64 + kt * 32 + g * 8];
            a[2 + kt] = *(const bf16x8*)&hnb[(size_t)(row0 + c0) * 64 + kt * 32 + g * 8];
        }
        f32x4 acc[4];
        #pragma unroll
        for (int nt = 0; nt < 4; ++nt) {
            float b = bgv[nt];
            f32x4 c = {b, b, b, b};
            #pragma unroll
            for (int kt = 0; kt < 4; ++kt)
                c = __builtin_amdgcn_mfma_f32_16x16x32_bf16(a[kt], wp[(nt * 4 + kt) * 64 + lane], c, 0, 0, 0);
            acc[nt] = c;
        }
        const int r0 = row0 + g * 4;
        #pragma unroll
        for (int r = 0; r < 4; ++r) {
            float rv[4];
            float s = 0.f;
            #pragma unroll
            for (int nt = 0; nt < 4; ++nt) {
                float hn = fmaxf(acc[nt][r], 0.f);
                rv[nt] = hn + b2f(h2b[(size_t)(r0 + r) * 64 + nt * 16 + c0]);
                s += rv[nt];
            }
            s = gsum16(s);
            float mu = s * (1.f / 64.f);
            float q = 0.f;
            #pragma unroll
            for (int nt = 0; nt < 4; ++nt) { float d = rv[nt] - mu; q += d * d; }
            q = gsum16(q);
            float inv = rsqrtf(q * (1.f / 64.f) + EPS);
            #pragma unroll
            for (int nt = 0; nt < 4; ++nt)
                out[(size_t)(r0 + r) * D + nt * 16 + c0] = (rv[nt] - mu) * inv * ggv[nt] + bnv[nt];
        }
    }
}

// ---------------- attention_samples passthrough (as fp32) ----------------
__global__ __launch_bounds__(256) void k_samples(
    const int* __restrict__ samp, float* __restrict__ out, int n)
{
    int i = blockIdx.x * blockDim.x + threadIdx.x;
    const int stride = gridDim.x * blockDim.x;
    for (; i < n; i += stride) out[i] = (float)samp[i];
}

extern "C" void kernel_launch(void* const* d_in, const int* in_sizes, int n_in,
                              void* d_out, int out_size, void* d_ws, size_t ws_size,
                              hipStream_t stream)
{
    const float* x   = (const float*)d_in[0];
    const int*   rows = (const int*)d_in[1];
    const int*   cols = (const int*)d_in[2];
    const float* ev  = (const float*)d_in[3];
    const int*   samp = (const int*)d_in[4];
    const float* Wq  = (const float*)d_in[5];
    const float* bq  = (const float*)d_in[6];
    const float* Wk  = (const float*)d_in[7];
    const float* bk  = (const float*)d_in[8];
    const float* Wv  = (const float*)d_in[9];
    const float* bv  = (const float*)d_in[10];
    const float* Wo  = (const float*)d_in[11];
    const float* bo  = (const float*)d_in[12];
    const float* g1  = (const float*)d_in[13];
    const float* be1 = (const float*)d_in[14];
    const float* g2  = (const float*)d_in[15];
    const float* be2 = (const float*)d_in[16];
    const float* W1  = (const float*)d_in[17];
    const float* bf1 = (const float*)d_in[18];
    const float* W2  = (const float*)d_in[19];
    const float* bf2 = (const float*)d_in[20];
    const float* Wg  = (const float*)d_in[21];
    const float* bg  = (const float*)d_in[22];
    const float* gg  = (const float*)d_in[23];
    const float* bgn = (const float*)d_in[24];
    const int E = in_sizes[1];
    const int npb = (E + PCHUNK - 1) / PCHUNK;

    // ws layout: 3 buffers of NN*D floats (76.8 MB)
    float* buf0 = (float*)d_ws;                   // [Kp_b | Vp_b] bf16 -> payload (int2[E])
    float* buf1 = buf0 + (size_t)NN * D;          // [Qp_b -> hnb_b | ob -> h2b] bf16
    float* buf2 = buf1 + (size_t)NN * D;          // hb fp32 -> part (int2[E])
    unsigned short* Kp_b = (unsigned short*)buf0;
    unsigned short* Vp_b = Kp_b + (size_t)NN * D;
    int2* payload = (int2*)buf0;                       // overwrites Kp/Vp after attn
    unsigned short* Qp_b  = (unsigned short*)buf1;     // dead after attn -> hnb slot
    unsigned short* hnb_b = (unsigned short*)buf1;
    unsigned short* ob    = (unsigned short*)(buf1 + (size_t)NN * D / 2); // dead after attno -> h2b slot
    unsigned short* h2b   = ob;
    float* hb = buf2;
    int2* part = (int2*)buf2;                          // overwrites hb after ffn

    float* out = (float*)d_out;
    // scratch in samples region of d_out (rewritten by k_samples each call)
    short* S     = (short*)(out + (size_t)NN * D);   // S_TOTAL shorts
    int* offsets = (int*)(S + S_TOTAL);              // NN+1
    int* bbase   = offsets + NN + 1;                 // NB+1
    int* partial = bbase + NB + 1;                   // npb*NB

    k_prep<<<56, 256, 0, stream>>>(W1, W2, Wg, Wq, Wk, Wv, Wo, S);
    k_bhist<<<npb, 256, 0, stream>>>(rows, partial, E);
    k_pscan<<<1, 256, 0, stream>>>(partial, bbase, offsets, npb);
    k_projqkv_mfma<<<1563, 256, 0, stream>>>(x, S, bq, bk, bv, Qp_b, Kp_b, Vp_b);
    k_attn_lite<<<4096, 256, 0, stream>>>(Qp_b, Kp_b, Vp_b, samp, ob);
    k_attno_mfma<<<1563, 256, 0, stream>>>(ob, x, S, bo, g1, be1, hb);
    k_ffn_mfma<<<1563, 256, 0, stream>>>(hb, S, bf1, bf2, g2, be2, h2b);
    k_part<<<npb, 256, 0, stream>>>(rows, cols, ev, partial, part, E);
    k_fill2<<<NB, 256, 0, stream>>>(bbase, part, offsets, payload);
    k_gather<<<4096, 256, 0, stream>>>(offsets, payload, h2b, hnb_b);
    k_gnn_mfma<<<1563, 256, 0, stream>>>(h2b, hnb_b, S, bg, gg, bgn, out);
    k_samples<<<2048, 256, 0, stream>>>(samp, out + (size_t)NN * D, NN * KS);
}

// Round 12
// 331.618 us; speedup vs baseline: 8.2602x; 1.2557x over previous
//
#include <hip/hip_runtime.h>
#include <hip/hip_bf16.h>

#define NN  100000
#define D   64
#define KS  20
#define DFF 256
#define EPS 1e-5f

// radix-partition params
#define BROWS  512
#define NB     ((NN + BROWS - 1) / BROWS)   // 196 buckets
#define PCHUNK 8192                          // edges per chunk (k_bhist & k_part)

// frag-buffer offsets (shorts)
#define OFF_W1 0
#define OFF_W2 16384
#define OFF_WG 32768
#define OFF_WQ 40960
#define OFF_WK 45056
#define OFF_WV 49152
#define OFF_WO 53248
#define S_TOTAL 57344

typedef __attribute__((ext_vector_type(8))) short bf16x8;
typedef __attribute__((ext_vector_type(4))) float f32x4;

__device__ __forceinline__ short f2b(float f) {
    return __builtin_bit_cast(short, __float2bfloat16(f));
}
__device__ __forceinline__ unsigned short f2bu(float f) {
    return __builtin_bit_cast(unsigned short, __float2bfloat16(f));
}
__device__ __forceinline__ float b2f(unsigned short u) {
    return __builtin_bit_cast(float, ((unsigned)u) << 16);
}
__device__ __forceinline__ float gsum16(float v) {
    v += __shfl_xor(v, 1, 64);
    v += __shfl_xor(v, 2, 64);
    v += __shfl_xor(v, 4, 64);
    v += __shfl_xor(v, 8, 64);
    return v;
}

// ---------------- weight fragment prep (bf16, B-operand layout) ----------------
// B-frag: lane l, elem i -> B[k][n], n = nt*16 + (l&15), k = kt*32 + (l>>4)*8 + i
__global__ __launch_bounds__(256) void k_prep(
    const float* __restrict__ W1, const float* __restrict__ W2,
    const float* __restrict__ Wg,
    const float* __restrict__ Wq, const float* __restrict__ Wk,
    const float* __restrict__ Wv, const float* __restrict__ Wo,
    short* __restrict__ S)
{
    int idx = blockIdx.x * 256 + threadIdx.x;
    for (; idx < S_TOTAL; idx += gridDim.x * 256) {
        float v;
        if (idx < OFF_W2) {                 // W1 [64 x 256]
            int f = idx >> 9, rem = idx & 511;
            int l = rem >> 3, i = rem & 7;
            int nt = f >> 1, kt = f & 1;
            v = W1[(kt * 32 + (l >> 4) * 8 + i) * DFF + nt * 16 + (l & 15)];
        } else if (idx < OFF_WG) {          // W2 [256 x 64]
            int j = idx - OFF_W2;
            int f = j >> 9, rem = j & 511;
            int l = rem >> 3, i = rem & 7;
            int nt = f >> 3, kt = f & 7;
            v = W2[(kt * 32 + (l >> 4) * 8 + i) * D + nt * 16 + (l & 15)];
        } else if (idx < OFF_WQ) {          // Wg [128 x 64]
            int j = idx - OFF_WG;
            int f = j >> 9, rem = j & 511;
            int l = rem >> 3, i = rem & 7;
            int nt = f >> 2, kt = f & 3;
            v = Wg[(kt * 32 + (l >> 4) * 8 + i) * D + nt * 16 + (l & 15)];
        } else {                            // Wq/Wk/Wv/Wo [64 x 64]
            int j = idx - OFF_WQ;
            const float* W = (j < 4096) ? Wq : (j < 8192) ? Wk : (j < 12288) ? Wv : Wo;
            j &= 4095;
            int f = j >> 9, rem = j & 511;
            int l = rem >> 3, i = rem & 7;
            int nt = f >> 1, kt = f & 1;
            v = W[(kt * 32 + (l >> 4) * 8 + i) * D + nt * 16 + (l & 15)];
        }
        S[idx] = f2b(v);
    }
}

// ---------------- per-chunk bucket histogram (dense write, NO global atomics) ----------------
__global__ __launch_bounds__(256) void k_bhist(
    const int* __restrict__ rows, int* __restrict__ partial, int E)
{
    __shared__ int h[NB];
    for (int t = threadIdx.x; t < NB; t += 256) h[t] = 0;
    __syncthreads();
    const int i0 = blockIdx.x * PCHUNK;
    const int n = min(PCHUNK, E - i0);
    for (int t = threadIdx.x; t < n; t += 256)
        atomicAdd(&h[__builtin_nontemporal_load(rows + i0 + t) >> 9], 1);
    __syncthreads();
    for (int t = threadIdx.x; t < NB; t += 256)
        partial[blockIdx.x * NB + t] = h[t];
}

// ---------------- parallel 2D prefix, stage A: per-bucket scan over chunks ----------------
// One block per bucket b: scan partial[p][b] over p (parallel, 512/round),
// rewrite in place as RELATIVE exclusive base; emit btot[b] = bucket total.
__global__ __launch_bounds__(256) void k_pscan_a(
    int* __restrict__ partial, int* __restrict__ btot, int npb)
{
    __shared__ int wsum[4];
    __shared__ int s_carry;
    const int b = blockIdx.x;
    const int tid = threadIdx.x;
    const int lane = tid & 63, wv = tid >> 6;
    if (tid == 0) s_carry = 0;
    __syncthreads();
    for (int base = 0; base < npb; base += 512) {
        int p0 = base + 2 * tid, p1 = p0 + 1;
        int c0 = (p0 < npb) ? partial[p0 * NB + b] : 0;
        int c1 = (p1 < npb) ? partial[p1 * NB + b] : 0;
        int s = c0 + c1;
        int sv = s;
        #pragma unroll
        for (int off = 1; off < 64; off <<= 1) {
            int u = __shfl_up(sv, off, 64);
            if (lane >= off) sv += u;
        }
        if (lane == 63) wsum[wv] = sv;
        __syncthreads();
        int wofs = 0;
        for (int k = 0; k < wv; ++k) wofs += wsum[k];
        int o0 = s_carry + wofs + sv - s;
        int o1 = o0 + c0;
        if (p0 < npb) partial[p0 * NB + b] = o0;
        if (p1 < npb) partial[p1 * NB + b] = o1;
        __syncthreads();
        if (tid == 0) s_carry += wsum[0] + wsum[1] + wsum[2] + wsum[3];
        __syncthreads();
    }
    if (tid == 0) btot[b] = s_carry;
}

// ---------------- stage B: bucket scan of totals -> bbase; offsets[NN]=E ----------------
__global__ __launch_bounds__(256) void k_pscan_b(
    const int* __restrict__ btot, int* __restrict__ bbase,
    int* __restrict__ offsets)
{
    __shared__ int wsum[4];
    const int t = threadIdx.x;
    const int lane = t & 63, wv = t >> 6;
    int v = (t < NB) ? btot[t] : 0;
    int sv = v;
    #pragma unroll
    for (int off = 1; off < 64; off <<= 1) {
        int u = __shfl_up(sv, off, 64);
        if (lane >= off) sv += u;
    }
    if (lane == 63) wsum[wv] = sv;
    __syncthreads();
    int wofs = 0;
    for (int k = 0; k < wv; ++k) wofs += wsum[k];
    int excl = wofs + sv - v;
    if (t < NB) bbase[t] = excl;
    if (t == 0) {
        int tot = wsum[0] + wsum[1] + wsum[2] + wsum[3];
        bbase[NB] = tot;
        offsets[NN] = tot;
    }
}

// ---------------- phase 1: radix-partition edges by bucket (row>>9) ----------------
// Per-chunk bases = bbase[t] + relative base; zero global atomics; single pass.
__global__ __launch_bounds__(256) void k_part(
    const int* __restrict__ rows, const int* __restrict__ cols,
    const float* __restrict__ ev, const int* __restrict__ pbase,
    const int* __restrict__ bbase,
    int2* __restrict__ part, int E)
{
    __shared__ int base[NB];
    __shared__ int lcnt[NB];
    const int tid = threadIdx.x;
    const int i0 = blockIdx.x * PCHUNK;
    const int n = min(PCHUNK, E - i0);
    for (int t = tid; t < NB; t += 256) {
        base[t] = bbase[t] + pbase[blockIdx.x * NB + t];
        lcnt[t] = 0;
    }
    __syncthreads();
    for (int t = tid; t < n; t += 256) {
        int r = __builtin_nontemporal_load(rows + i0 + t);
        int c = __builtin_nontemporal_load(cols + i0 + t);
        float w = __builtin_nontemporal_load(ev + i0 + t);
        int b = r >> 9;
        int lpos = atomicAdd(&lcnt[b], 1);
        part[base[b] + lpos] = make_int2(((r & (BROWS - 1)) << 17) | c, __float_as_int(w));
    }
}

// ---------------- phase 2: in-bucket row offsets (LDS scan) + final placement ----------------
__global__ __launch_bounds__(256) void k_fill2(
    const int* __restrict__ bbase, const int2* __restrict__ part,
    int* __restrict__ offsets, int2* __restrict__ payload)
{
    __shared__ int lcnt[BROWS];
    __shared__ int lcur[BROWS];
    __shared__ int wsum[4];
    const int b = blockIdx.x;
    const int row0 = b * BROWS;
    const int nrows = min(BROWS, NN - row0);
    const int tid = threadIdx.x;
    for (int t = tid; t < BROWS; t += 256) lcnt[t] = 0;
    __syncthreads();
    const int e0 = bbase[b], e1 = bbase[b + 1];
    for (int i = e0 + tid; i < e1; i += 256)
        atomicAdd(&lcnt[(unsigned)part[i].x >> 17], 1);
    __syncthreads();
    // exclusive scan of 512 LDS counters: thread t owns pair (2t, 2t+1)
    int c0 = lcnt[2 * tid], c1 = lcnt[2 * tid + 1];
    int s = c0 + c1;
    const int lane = tid & 63, wv = tid >> 6;
    int sv = s;
    #pragma unroll
    for (int off = 1; off < 64; off <<= 1) {
        int u = __shfl_up(sv, off, 64);
        if (lane >= off) sv += u;
    }
    if (lane == 63) wsum[wv] = sv;
    __syncthreads();
    int wofs = 0;
    for (int k = 0; k < wv; ++k) wofs += wsum[k];
    int o0 = e0 + wofs + sv - s;
    int o1 = o0 + c0;
    lcur[2 * tid] = o0;
    lcur[2 * tid + 1] = o1;
    if (2 * tid < nrows)     offsets[row0 + 2 * tid]     = o0;
    if (2 * tid + 1 < nrows) offsets[row0 + 2 * tid + 1] = o1;
    __syncthreads();
    for (int i = e0 + tid; i < e1; i += 256) {
        int2 rec = part[i];
        int rowoff = (unsigned)rec.x >> 17;
        int pos = atomicAdd(&lcur[rowoff], 1);
        payload[pos] = make_int2(rec.x & 0x1FFFF, rec.y);
    }
}

// ---------------- segment gather-reduce (2-deep pipelined) ----------------
__global__ __launch_bounds__(256) void k_gather(
    const int* __restrict__ offsets, const int2* __restrict__ payload,
    const unsigned short* __restrict__ h2b, unsigned short* __restrict__ hnb)
{
    const int lane = threadIdx.x & 63;
    const int g = lane >> 4, c0 = lane & 15;
    int w = (blockIdx.x * 256 + threadIdx.x) >> 6;
    const int nw = (gridDim.x * 256) >> 6;
    for (int row = w; row < NN; row += nw) {
        const int b = offsets[row], e = offsets[row + 1];
        float ax = 0.f, ay = 0.f, az = 0.f, aw = 0.f;
        int i = b + g;
        for (; i + 4 < e; i += 8) {
            int2 p0 = payload[i];
            int2 p1 = payload[i + 4];
            float w0 = __int_as_float(p0.y);
            float w1 = __int_as_float(p1.y);
            const ushort4 u0 = *(const ushort4*)(h2b + (size_t)p0.x * 64 + c0 * 4);
            const ushort4 u1 = *(const ushort4*)(h2b + (size_t)p1.x * 64 + c0 * 4);
            ax = fmaf(b2f(u0.x), w0, ax); ay = fmaf(b2f(u0.y), w0, ay);
            az = fmaf(b2f(u0.z), w0, az); aw = fmaf(b2f(u0.w), w0, aw);
            ax = fmaf(b2f(u1.x), w1, ax); ay = fmaf(b2f(u1.y), w1, ay);
            az = fmaf(b2f(u1.z), w1, az); aw = fmaf(b2f(u1.w), w1, aw);
        }
        if (i < e) {
            int2 p = payload[i];
            float wt = __int_as_float(p.y);
            const ushort4 u = *(const ushort4*)(h2b + (size_t)p.x * 64 + c0 * 4);
            ax = fmaf(b2f(u.x), wt, ax); ay = fmaf(b2f(u.y), wt, ay);
            az = fmaf(b2f(u.z), wt, az); aw = fmaf(b2f(u.w), wt, aw);
        }
        ax += __shfl_xor(ax, 16, 64); ax += __shfl_xor(ax, 32, 64);
        ay += __shfl_xor(ay, 16, 64); ay += __shfl_xor(ay, 32, 64);
        az += __shfl_xor(az, 16, 64); az += __shfl_xor(az, 32, 64);
        aw += __shfl_xor(aw, 16, 64); aw += __shfl_xor(aw, 32, 64);
        if (g == 0) {
            ushort4 o;
            o.x = f2bu(ax); o.y = f2bu(ay); o.z = f2bu(az); o.w = f2bu(aw);
            *(ushort4*)(hnb + (size_t)row * 64 + c0 * 4) = o;
        }
    }
}

// ---------------- Q/K/V projection via MFMA -> bf16 ----------------
__global__ __launch_bounds__(256) void k_projqkv_mfma(
    const float* __restrict__ x, const short* __restrict__ S,
    const float* __restrict__ bq, const float* __restrict__ bk,
    const float* __restrict__ bv,
    unsigned short* __restrict__ Qp, unsigned short* __restrict__ Kp,
    unsigned short* __restrict__ Vp)
{
    const int lane = threadIdx.x & 63;
    const int c0 = lane & 15;
    const int g  = lane >> 4;
    const bf16x8* wq = (const bf16x8*)(S + OFF_WQ);
    const bf16x8* wk = (const bf16x8*)(S + OFF_WK);
    const bf16x8* wv = (const bf16x8*)(S + OFF_WV);

    float bqv[4], bkv[4], bvv[4];
    #pragma unroll
    for (int nt = 0; nt < 4; ++nt) {
        bqv[nt] = bq[nt * 16 + c0];
        bkv[nt] = bk[nt * 16 + c0];
        bvv[nt] = bv[nt * 16 + c0];
    }

    int wid = (blockIdx.x * 256 + threadIdx.x) >> 6;
    const int nwaves = (gridDim.x * 256) >> 6;
    for (int tile = wid; tile < NN / 16; tile += nwaves) {
        const int row0 = tile * 16;
        const float* ar = x + (size_t)(row0 + c0) * D + g * 8;
        bf16x8 a0, a1;
        {
            float4 f0 = *(const float4*)(ar);
            float4 f1 = *(const float4*)(ar + 4);
            float4 f2 = *(const float4*)(ar + 32);
            float4 f3 = *(const float4*)(ar + 36);
            a0[0] = f2b(f0.x); a0[1] = f2b(f0.y); a0[2] = f2b(f0.z); a0[3] = f2b(f0.w);
            a0[4] = f2b(f1.x); a0[5] = f2b(f1.y); a0[6] = f2b(f1.z); a0[7] = f2b(f1.w);
            a1[0] = f2b(f2.x); a1[1] = f2b(f2.y); a1[2] = f2b(f2.z); a1[3] = f2b(f2.w);
            a1[4] = f2b(f3.x); a1[5] = f2b(f3.y); a1[6] = f2b(f3.z); a1[7] = f2b(f3.w);
        }
        f32x4 aq[4], ak[4], av[4];
        #pragma unroll
        for (int nt = 0; nt < 4; ++nt) {
            f32x4 cq = {bqv[nt], bqv[nt], bqv[nt], bqv[nt]};
            cq = __builtin_amdgcn_mfma_f32_16x16x32_bf16(a0, wq[(nt * 2 + 0) * 64 + lane], cq, 0, 0, 0);
            cq = __builtin_amdgcn_mfma_f32_16x16x32_bf16(a1, wq[(nt * 2 + 1) * 64 + lane], cq, 0, 0, 0);
            aq[nt] = cq;
            f32x4 ck = {bkv[nt], bkv[nt], bkv[nt], bkv[nt]};
            ck = __builtin_amdgcn_mfma_f32_16x16x32_bf16(a0, wk[(nt * 2 + 0) * 64 + lane], ck, 0, 0, 0);
            ck = __builtin_amdgcn_mfma_f32_16x16x32_bf16(a1, wk[(nt * 2 + 1) * 64 + lane], ck, 0, 0, 0);
            ak[nt] = ck;
            f32x4 cv = {bvv[nt], bvv[nt], bvv[nt], bvv[nt]};
            cv = __builtin_amdgcn_mfma_f32_16x16x32_bf16(a0, wv[(nt * 2 + 0) * 64 + lane], cv, 0, 0, 0);
            cv = __builtin_amdgcn_mfma_f32_16x16x32_bf16(a1, wv[(nt * 2 + 1) * 64 + lane], cv, 0, 0, 0);
            av[nt] = cv;
        }
        const int r0 = row0 + g * 4;
        #pragma unroll
        for (int r = 0; r < 4; ++r) {
            #pragma unroll
            for (int nt = 0; nt < 4; ++nt) {
                Qp[(size_t)(r0 + r) * D + nt * 16 + c0] = f2bu(aq[nt][r]);
                Kp[(size_t)(r0 + r) * D + nt * 16 + c0] = f2bu(ak[nt][r]);
                Vp[(size_t)(r0 + r) * D + nt * 16 + c0] = f2bu(av[nt][r]);
            }
        }
    }
}

// ---------------- attention core: gathers + per-head softmax + PV -> ob (bf16) ----------------
__global__ __launch_bounds__(256) void k_attn_lite(
    const unsigned short* __restrict__ Qp,
    const unsigned short* __restrict__ Kp, const unsigned short* __restrict__ Vp,
    const int* __restrict__ samp, unsigned short* __restrict__ ob)
{
    const int lane = threadIdx.x & 63;
    const int g = lane >> 4, c0 = lane & 15;
    int w = (blockIdx.x * 256 + threadIdx.x) >> 6;
    const int nw = (gridDim.x * 256) >> 6;
    for (int row = w; row < NN; row += nw) {
        int idx_reg = (lane < KS) ? samp[row * KS + lane] : 0;
        const ushort4 qv = *(const ushort4*)(Qp + (size_t)row * D + c0 * 4);
        float q0 = b2f(qv.x), q1 = b2f(qv.y), q2 = b2f(qv.z), q3 = b2f(qv.w);

        // group g handles samples g*5 .. g*5+4
        float s[5];
        ushort4 v4[5];
        #pragma unroll
        for (int t = 0; t < 5; ++t) {
            int idx = __shfl(idx_reg, g * 5 + t, 64);
            const ushort4 kk = *(const ushort4*)(Kp + (size_t)idx * D + c0 * 4);
            v4[t] = *(const ushort4*)(Vp + (size_t)idx * D + c0 * 4);
            float sc = q0 * b2f(kk.x);
            sc = fmaf(q1, b2f(kk.y), sc);
            sc = fmaf(q2, b2f(kk.z), sc);
            sc = fmaf(q3, b2f(kk.w), sc);
            // per-head dot: head = c0>>2 spans lanes (c0&~3)..(c0|3)
            sc += __shfl_xor(sc, 1, 64);
            sc += __shfl_xor(sc, 2, 64);
            s[t] = sc * 0.25f;   // 1/sqrt(DH=16)
        }
        // per-head softmax over 20 samples (5 local x 4 groups; xor16/32 keep c0 => within-head)
        float m = fmaxf(fmaxf(fmaxf(s[0], s[1]), fmaxf(s[2], s[3])), s[4]);
        m = fmaxf(m, __shfl_xor(m, 16, 64));
        m = fmaxf(m, __shfl_xor(m, 32, 64));
        float o0 = 0.f, o1 = 0.f, o2 = 0.f, o3 = 0.f, ssum = 0.f;
        #pragma unroll
        for (int t = 0; t < 5; ++t) {
            float p = __expf(s[t] - m);
            ssum += p;
            o0 = fmaf(p, b2f(v4[t].x), o0);
            o1 = fmaf(p, b2f(v4[t].y), o1);
            o2 = fmaf(p, b2f(v4[t].z), o2);
            o3 = fmaf(p, b2f(v4[t].w), o3);
        }
        ssum += __shfl_xor(ssum, 16, 64);
        ssum += __shfl_xor(ssum, 32, 64);
        float inv = 1.0f / ssum;
        o0 += __shfl_xor(o0, 16, 64); o0 += __shfl_xor(o0, 32, 64);
        o1 += __shfl_xor(o1, 16, 64); o1 += __shfl_xor(o1, 32, 64);
        o2 += __shfl_xor(o2, 16, 64); o2 += __shfl_xor(o2, 32, 64);
        o3 += __shfl_xor(o3, 16, 64); o3 += __shfl_xor(o3, 32, 64);
        if (g == 0) {
            ushort4 o;
            o.x = f2bu(o0 * inv); o.y = f2bu(o1 * inv);
            o.z = f2bu(o2 * inv); o.w = f2bu(o3 * inv);
            *(ushort4*)(ob + (size_t)row * D + c0 * 4) = o;
        }
    }
}

// ---------------- Wo projection + residual + LN1 via MFMA -> hb fp32 ----------------
__global__ __launch_bounds__(256) void k_attno_mfma(
    const unsigned short* __restrict__ ob, const float* __restrict__ x,
    const short* __restrict__ S,
    const float* __restrict__ bo, const float* __restrict__ g1,
    const float* __restrict__ be1,
    float* __restrict__ hb)
{
    const int lane = threadIdx.x & 63;
    const int c0 = lane & 15;
    const int g  = lane >> 4;
    const bf16x8* wp = (const bf16x8*)(S + OFF_WO);

    float bov[4], g1v[4], b1v[4];
    #pragma unroll
    for (int nt = 0; nt < 4; ++nt) {
        bov[nt] = bo[nt * 16 + c0];
        g1v[nt] = g1[nt * 16 + c0];
        b1v[nt] = be1[nt * 16 + c0];
    }

    int wid = (blockIdx.x * 256 + threadIdx.x) >> 6;
    const int nwaves = (gridDim.x * 256) >> 6;
    for (int tile = wid; tile < NN / 16; tile += nwaves) {
        const int row0 = tile * 16;
        bf16x8 a[2];
        #pragma unroll
        for (int kt = 0; kt < 2; ++kt)
            a[kt] = *(const bf16x8*)&ob[(size_t)(row0 + c0) * D + kt * 32 + g * 8];
        f32x4 acc[4];
        #pragma unroll
        for (int nt = 0; nt < 4; ++nt) {
            f32x4 c = {bov[nt], bov[nt], bov[nt], bov[nt]};
            #pragma unroll
            for (int kt = 0; kt < 2; ++kt)
                c = __builtin_amdgcn_mfma_f32_16x16x32_bf16(a[kt], wp[(nt * 2 + kt) * 64 + lane], c, 0, 0, 0);
            acc[nt] = c;
        }
        const int r0 = row0 + g * 4;
        #pragma unroll
        for (int r = 0; r < 4; ++r) {
            float rv[4];
            float s = 0.f;
            #pragma unroll
            for (int nt = 0; nt < 4; ++nt) {
                rv[nt] = acc[nt][r] + x[(size_t)(r0 + r) * D + nt * 16 + c0];
                s += rv[nt];
            }
            s = gsum16(s);
            float mu = s * (1.f / 64.f);
            float q = 0.f;
            #pragma unroll
            for (int nt = 0; nt < 4; ++nt) { float d = rv[nt] - mu; q += d * d; }
            q = gsum16(q);
            float inv = rsqrtf(q * (1.f / 64.f) + EPS);
            #pragma unroll
            for (int nt = 0; nt < 4; ++nt)
                hb[(size_t)(r0 + r) * D + nt * 16 + c0] = (rv[nt] - mu) * inv * g1v[nt] + b1v[nt];
        }
    }
}

// ---------------- FFN via MFMA -> bf16 h2 ----------------
__global__ __launch_bounds__(256) void k_ffn_mfma(
    const float* __restrict__ hb,
    const short* __restrict__ wf,
    const float* __restrict__ bf1, const float* __restrict__ bf2,
    const float* __restrict__ g2, const float* __restrict__ be2,
    unsigned short* __restrict__ h2b)
{
    __shared__ __align__(16) short Tl[4][16][264];
    const int lane = threadIdx.x & 63;
    const int wv   = threadIdx.x >> 6;
    const int c0   = lane & 15;
    const int g    = lane >> 4;
    const bf16x8* w1p = (const bf16x8*)(wf + OFF_W1);
    const bf16x8* w2p = (const bf16x8*)(wf + OFF_W2);

    float b1v[16];
    #pragma unroll
    for (int nt = 0; nt < 16; ++nt) b1v[nt] = bf1[nt * 16 + c0];
    float b2v[4], g2v[4], bev[4];
    #pragma unroll
    for (int nt = 0; nt < 4; ++nt) {
        b2v[nt] = bf2[nt * 16 + c0];
        g2v[nt] = g2[nt * 16 + c0];
        bev[nt] = be2[nt * 16 + c0];
    }

    int wid = (blockIdx.x * 256 + threadIdx.x) >> 6;
    const int nwaves = (gridDim.x * 256) >> 6;
    for (int tile = wid; tile < NN / 16; tile += nwaves) {
        const int row0 = tile * 16;
        const float* ar = hb + (size_t)(row0 + c0) * D + g * 8;
        bf16x8 a0, a1;
        {
            float4 f0 = *(const float4*)(ar);
            float4 f1 = *(const float4*)(ar + 4);
            float4 f2 = *(const float4*)(ar + 32);
            float4 f3 = *(const float4*)(ar + 36);
            a0[0] = f2b(f0.x); a0[1] = f2b(f0.y); a0[2] = f2b(f0.z); a0[3] = f2b(f0.w);
            a0[4] = f2b(f1.x); a0[5] = f2b(f1.y); a0[6] = f2b(f1.z); a0[7] = f2b(f1.w);
            a1[0] = f2b(f2.x); a1[1] = f2b(f2.y); a1[2] = f2b(f2.z); a1[3] = f2b(f2.w);
            a1[4] = f2b(f3.x); a1[5] = f2b(f3.y); a1[6] = f2b(f3.z); a1[7] = f2b(f3.w);
        }
        f32x4 acc1[16];
        #pragma unroll
        for (int nt = 0; nt < 16; ++nt) {
            float b = b1v[nt];
            f32x4 c = {b, b, b, b};
            c = __builtin_amdgcn_mfma_f32_16x16x32_bf16(a0, w1p[(nt * 2 + 0) * 64 + lane], c, 0, 0, 0);
            c = __builtin_amdgcn_mfma_f32_16x16x32_bf16(a1, w1p[(nt * 2 + 1) * 64 + lane], c, 0, 0, 0);
            acc1[nt] = c;
        }
        #pragma unroll
        for (int nt = 0; nt < 16; ++nt) {
            #pragma unroll
            for (int r = 0; r < 4; ++r)
                Tl[wv][g * 4 + r][nt * 16 + c0] = f2b(fmaxf(acc1[nt][r], 0.f));
        }
        bf16x8 a2[8];
        #pragma unroll
        for (int kt = 0; kt < 8; ++kt)
            a2[kt] = *(const bf16x8*)&Tl[wv][c0][kt * 32 + g * 8];
        f32x4 acc2[4];
        #pragma unroll
        for (int nt = 0; nt < 4; ++nt) {
            float b = b2v[nt];
            f32x4 c = {b, b, b, b};
            #pragma unroll
            for (int kt = 0; kt < 8; ++kt)
                c = __builtin_amdgcn_mfma_f32_16x16x32_bf16(a2[kt], w2p[(nt * 8 + kt) * 64 + lane], c, 0, 0, 0);
            acc2[nt] = c;
        }
        const int r0 = row0 + g * 4;
        #pragma unroll
        for (int r = 0; r < 4; ++r) {
            float rv[4];
            float s = 0.f;
            #pragma unroll
            for (int nt = 0; nt < 4; ++nt) {
                rv[nt] = acc2[nt][r] + hb[(size_t)(r0 + r) * D + nt * 16 + c0];
                s += rv[nt];
            }
            s = gsum16(s);
            float mu = s * (1.f / 64.f);
            float q = 0.f;
            #pragma unroll
            for (int nt = 0; nt < 4; ++nt) { float d = rv[nt] - mu; q += d * d; }
            q = gsum16(q);
            float inv = rsqrtf(q * (1.f / 64.f) + EPS);
            #pragma unroll
            for (int nt = 0; nt < 4; ++nt)
                h2b[(size_t)(r0 + r) * D + nt * 16 + c0] = f2bu((rv[nt] - mu) * inv * g2v[nt] + bev[nt]);
        }
    }
}

// ---------------- GNN linear (MFMA, bf16 inputs) + relu + residual + LN -> fp32 out ----------------
__global__ __launch_bounds__(256) void k_gnn_mfma(
    const unsigned short* __restrict__ h2b, const unsigned short* __restrict__ hnb,
    const short* __restrict__ S,
    const float* __restrict__ bg, const float* __restrict__ gg,
    const float* __restrict__ bgn,
    float* __restrict__ out)
{
    const int lane = threadIdx.x & 63;
    const int c0 = lane & 15;
    const int g  = lane >> 4;
    const bf16x8* wp = (const bf16x8*)(S + OFF_WG);

    float bgv[4], ggv[4], bnv[4];
    #pragma unroll
    for (int nt = 0; nt < 4; ++nt) {
        bgv[nt] = bg[nt * 16 + c0];
        ggv[nt] = gg[nt * 16 + c0];
        bnv[nt] = bgn[nt * 16 + c0];
    }

    int wid = (blockIdx.x * 256 + threadIdx.x) >> 6;
    const int nwaves = (gridDim.x * 256) >> 6;
    for (int tile = wid; tile < NN / 16; tile += nwaves) {
        const int row0 = tile * 16;
        bf16x8 a[4];
        #pragma unroll
        for (int kt = 0; kt < 2; ++kt) {
            a[kt]     = *(const bf16x8*)&h2b[(size_t)(row0 + c0) * 64 + kt * 32 + g * 8];
            a[2 + kt] = *(const bf16x8*)&hnb[(size_t)(row0 + c0) * 64 + kt * 32 + g * 8];
        }
        f32x4 acc[4];
        #pragma unroll
        for (int nt = 0; nt < 4; ++nt) {
            float b = bgv[nt];
            f32x4 c = {b, b, b, b};
            #pragma unroll
            for (int kt = 0; kt < 4; ++kt)
                c = __builtin_amdgcn_mfma_f32_16x16x32_bf16(a[kt], wp[(nt * 4 + kt) * 64 + lane], c, 0, 0, 0);
            acc[nt] = c;
        }
        const int r0 = row0 + g * 4;
        #pragma unroll
        for (int r = 0; r < 4; ++r) {
            float rv[4];
            float s = 0.f;
            #pragma unroll
            for (int nt = 0; nt < 4; ++nt) {
                float hn = fmaxf(acc[nt][r], 0.f);
                rv[nt] = hn + b2f(h2b[(size_t)(r0 + r) * 64 + nt * 16 + c0]);
                s += rv[nt];
            }
            s = gsum16(s);
            float mu = s * (1.f / 64.f);
            float q = 0.f;
            #pragma unroll
            for (int nt = 0; nt < 4; ++nt) { float d = rv[nt] - mu; q += d * d; }
            q = gsum16(q);
            float inv = rsqrtf(q * (1.f / 64.f) + EPS);
            #pragma unroll
            for (int nt = 0; nt < 4; ++nt)
                out[(size_t)(r0 + r) * D + nt * 16 + c0] = (rv[nt] - mu) * inv * ggv[nt] + bnv[nt];
        }
    }
}

// ---------------- attention_samples passthrough (as fp32) ----------------
__global__ __launch_bounds__(256) void k_samples(
    const int* __restrict__ samp, float* __restrict__ out, int n)
{
    int i = blockIdx.x * blockDim.x + threadIdx.x;
    const int stride = gridDim.x * blockDim.x;
    for (; i < n; i += stride) out[i] = (float)samp[i];
}

extern "C" void kernel_launch(void* const* d_in, const int* in_sizes, int n_in,
                              void* d_out, int out_size, void* d_ws, size_t ws_size,
                              hipStream_t stream)
{
    const float* x   = (const float*)d_in[0];
    const int*   rows = (const int*)d_in[1];
    const int*   cols = (const int*)d_in[2];
    const float* ev  = (const float*)d_in[3];
    const int*   samp = (const int*)d_in[4];
    const float* Wq  = (const float*)d_in[5];
    const float* bq  = (const float*)d_in[6];
    const float* Wk  = (const float*)d_in[7];
    const float* bk  = (const float*)d_in[8];
    const float* Wv  = (const float*)d_in[9];
    const float* bv  = (const float*)d_in[10];
    const float* Wo  = (const float*)d_in[11];
    const float* bo  = (const float*)d_in[12];
    const float* g1  = (const float*)d_in[13];
    const float* be1 = (const float*)d_in[14];
    const float* g2  = (const float*)d_in[15];
    const float* be2 = (const float*)d_in[16];
    const float* W1  = (const float*)d_in[17];
    const float* bf1 = (const float*)d_in[18];
    const float* W2  = (const float*)d_in[19];
    const float* bf2 = (const float*)d_in[20];
    const float* Wg  = (const float*)d_in[21];
    const float* bg  = (const float*)d_in[22];
    const float* gg  = (const float*)d_in[23];
    const float* bgn = (const float*)d_in[24];
    const int E = in_sizes[1];
    const int npb = (E + PCHUNK - 1) / PCHUNK;

    // ws layout: 3 buffers of NN*D floats (76.8 MB)
    float* buf0 = (float*)d_ws;                   // [Kp_b | Vp_b] bf16 -> payload (int2[E])
    float* buf1 = buf0 + (size_t)NN * D;          // [Qp_b -> hnb_b | ob -> h2b] bf16
    float* buf2 = buf1 + (size_t)NN * D;          // hb fp32 -> part (int2[E])
    unsigned short* Kp_b = (unsigned short*)buf0;
    unsigned short* Vp_b = Kp_b + (size_t)NN * D;
    int2* payload = (int2*)buf0;                       // overwrites Kp/Vp after attn
    unsigned short* Qp_b  = (unsigned short*)buf1;     // dead after attn -> hnb slot
    unsigned short* hnb_b = (unsigned short*)buf1;
    unsigned short* ob    = (unsigned short*)(buf1 + (size_t)NN * D / 2); // dead after attno -> h2b slot
    unsigned short* h2b   = ob;
    float* hb = buf2;
    int2* part = (int2*)buf2;                          // overwrites hb after ffn

    float* out = (float*)d_out;
    // scratch in samples region of d_out (rewritten by k_samples each call)
    short* S     = (short*)(out + (size_t)NN * D);   // S_TOTAL shorts
    int* offsets = (int*)(S + S_TOTAL);              // NN+1
    int* bbase   = offsets + NN + 1;                 // NB+1
    int* btot    = bbase + NB + 1;                   // NB
    int* partial = btot + NB;                        // npb*NB

    k_prep<<<56, 256, 0, stream>>>(W1, W2, Wg, Wq, Wk, Wv, Wo, S);
    k_bhist<<<npb, 256, 0, stream>>>(rows, partial, E);
    k_pscan_a<<<NB, 256, 0, stream>>>(partial, btot, npb);
    k_pscan_b<<<1, 256, 0, stream>>>(btot, bbase, offsets);
    k_projqkv_mfma<<<1563, 256, 0, stream>>>(x, S, bq, bk, bv, Qp_b, Kp_b, Vp_b);
    k_attn_lite<<<4096, 256, 0, stream>>>(Qp_b, Kp_b, Vp_b, samp, ob);
    k_attno_mfma<<<1563, 256, 0, stream>>>(ob, x, S, bo, g1, be1, hb);
    k_ffn_mfma<<<1563, 256, 0, stream>>>(hb, S, bf1, bf2, g2, be2, h2b);
    k_part<<<npb, 256, 0, stream>>>(rows, cols, ev, partial, bbase, part, E);
    k_fill2<<<NB, 256, 0, stream>>>(bbase, part, offsets, payload);
    k_gather<<<4096, 256, 0, stream>>>(offsets, payload, h2b, hnb_b);
    k_gnn_mfma<<<1563, 256, 0, stream>>>(h2b, hnb_b, S, bg, gg, bgn, out);
    k_samples<<<2048, 256, 0, stream>>>(samp, out + (size_t)NN * D, NN * KS);
}

// Round 13
// 324.633 us; speedup vs baseline: 8.4380x; 1.0215x over previous
//
#include <hip/hip_runtime.h>
#include <hip/hip_bf16.h>

#define NN  100000
#define D   64
#define KS  20
#define DFF 256
#define EPS 1e-5f

// radix-partition params
#define BROWS  512
#define NB     ((NN + BROWS - 1) / BROWS)   // 196 buckets
#define PCHUNK 8192                          // edges per chunk (k_bhist & k_part)

// frag-buffer offsets (shorts)
#define OFF_W1 0
#define OFF_W2 16384
#define OFF_WG 32768
#define OFF_WQ 40960
#define OFF_WK 45056
#define OFF_WV 49152
#define OFF_WO 53248
#define S_TOTAL 57344

typedef __attribute__((ext_vector_type(8))) short bf16x8;
typedef __attribute__((ext_vector_type(4))) float f32x4;

__device__ __forceinline__ short f2b(float f) {
    return __builtin_bit_cast(short, __float2bfloat16(f));
}
__device__ __forceinline__ unsigned short f2bu(float f) {
    return __builtin_bit_cast(unsigned short, __float2bfloat16(f));
}
__device__ __forceinline__ float b2f(unsigned short u) {
    return __builtin_bit_cast(float, ((unsigned)u) << 16);
}
__device__ __forceinline__ unsigned char f2fp8(float v) {
    int p = __builtin_amdgcn_cvt_pk_fp8_f32(v, v, 0, false);
    return (unsigned char)(p & 0xFF);
}
__device__ __forceinline__ float gsum16(float v) {
    v += __shfl_xor(v, 1, 64);
    v += __shfl_xor(v, 2, 64);
    v += __shfl_xor(v, 4, 64);
    v += __shfl_xor(v, 8, 64);
    return v;
}

// ---------------- weight fragment prep (bf16, B-operand layout) ----------------
// B-frag: lane l, elem i -> B[k][n], n = nt*16 + (l&15), k = kt*32 + (l>>4)*8 + i
__global__ __launch_bounds__(256) void k_prep(
    const float* __restrict__ W1, const float* __restrict__ W2,
    const float* __restrict__ Wg,
    const float* __restrict__ Wq, const float* __restrict__ Wk,
    const float* __restrict__ Wv, const float* __restrict__ Wo,
    short* __restrict__ S)
{
    int idx = blockIdx.x * 256 + threadIdx.x;
    for (; idx < S_TOTAL; idx += gridDim.x * 256) {
        float v;
        if (idx < OFF_W2) {                 // W1 [64 x 256]
            int f = idx >> 9, rem = idx & 511;
            int l = rem >> 3, i = rem & 7;
            int nt = f >> 1, kt = f & 1;
            v = W1[(kt * 32 + (l >> 4) * 8 + i) * DFF + nt * 16 + (l & 15)];
        } else if (idx < OFF_WG) {          // W2 [256 x 64]
            int j = idx - OFF_W2;
            int f = j >> 9, rem = j & 511;
            int l = rem >> 3, i = rem & 7;
            int nt = f >> 3, kt = f & 7;
            v = W2[(kt * 32 + (l >> 4) * 8 + i) * D + nt * 16 + (l & 15)];
        } else if (idx < OFF_WQ) {          // Wg [128 x 64]
            int j = idx - OFF_WG;
            int f = j >> 9, rem = j & 511;
            int l = rem >> 3, i = rem & 7;
            int nt = f >> 2, kt = f & 3;
            v = Wg[(kt * 32 + (l >> 4) * 8 + i) * D + nt * 16 + (l & 15)];
        } else {                            // Wq/Wk/Wv/Wo [64 x 64]
            int j = idx - OFF_WQ;
            const float* W = (j < 4096) ? Wq : (j < 8192) ? Wk : (j < 12288) ? Wv : Wo;
            j &= 4095;
            int f = j >> 9, rem = j & 511;
            int l = rem >> 3, i = rem & 7;
            int nt = f >> 1, kt = f & 1;
            v = W[(kt * 32 + (l >> 4) * 8 + i) * D + nt * 16 + (l & 15)];
        }
        S[idx] = f2b(v);
    }
}

// ---------------- per-chunk bucket histogram (dense write, NO global atomics) ----------------
__global__ __launch_bounds__(256) void k_bhist(
    const int* __restrict__ rows, int* __restrict__ partial, int E)
{
    __shared__ int h[NB];
    for (int t = threadIdx.x; t < NB; t += 256) h[t] = 0;
    __syncthreads();
    const int i0 = blockIdx.x * PCHUNK;
    const int n = min(PCHUNK, E - i0);
    for (int t = threadIdx.x; t < n; t += 256)
        atomicAdd(&h[__builtin_nontemporal_load(rows + i0 + t) >> 9], 1);
    __syncthreads();
    for (int t = threadIdx.x; t < NB; t += 256)
        partial[blockIdx.x * NB + t] = h[t];
}

// ---------------- parallel 2D prefix, stage A: per-bucket scan over chunks ----------------
__global__ __launch_bounds__(256) void k_pscan_a(
    int* __restrict__ partial, int* __restrict__ btot, int npb)
{
    __shared__ int wsum[4];
    __shared__ int s_carry;
    const int b = blockIdx.x;
    const int tid = threadIdx.x;
    const int lane = tid & 63, wv = tid >> 6;
    if (tid == 0) s_carry = 0;
    __syncthreads();
    for (int base = 0; base < npb; base += 512) {
        int p0 = base + 2 * tid, p1 = p0 + 1;
        int c0 = (p0 < npb) ? partial[p0 * NB + b] : 0;
        int c1 = (p1 < npb) ? partial[p1 * NB + b] : 0;
        int s = c0 + c1;
        int sv = s;
        #pragma unroll
        for (int off = 1; off < 64; off <<= 1) {
            int u = __shfl_up(sv, off, 64);
            if (lane >= off) sv += u;
        }
        if (lane == 63) wsum[wv] = sv;
        __syncthreads();
        int wofs = 0;
        for (int k = 0; k < wv; ++k) wofs += wsum[k];
        int o0 = s_carry + wofs + sv - s;
        int o1 = o0 + c0;
        if (p0 < npb) partial[p0 * NB + b] = o0;
        if (p1 < npb) partial[p1 * NB + b] = o1;
        __syncthreads();
        if (tid == 0) s_carry += wsum[0] + wsum[1] + wsum[2] + wsum[3];
        __syncthreads();
    }
    if (tid == 0) btot[b] = s_carry;
}

// ---------------- stage B: bucket scan of totals -> bbase; offsets[NN]=E ----------------
__global__ __launch_bounds__(256) void k_pscan_b(
    const int* __restrict__ btot, int* __restrict__ bbase,
    int* __restrict__ offsets)
{
    __shared__ int wsum[4];
    const int t = threadIdx.x;
    const int lane = t & 63, wv = t >> 6;
    int v = (t < NB) ? btot[t] : 0;
    int sv = v;
    #pragma unroll
    for (int off = 1; off < 64; off <<= 1) {
        int u = __shfl_up(sv, off, 64);
        if (lane >= off) sv += u;
    }
    if (lane == 63) wsum[wv] = sv;
    __syncthreads();
    int wofs = 0;
    for (int k = 0; k < wv; ++k) wofs += wsum[k];
    int excl = wofs + sv - v;
    if (t < NB) bbase[t] = excl;
    if (t == 0) {
        int tot = wsum[0] + wsum[1] + wsum[2] + wsum[3];
        bbase[NB] = tot;
        offsets[NN] = tot;
    }
}

// ---------------- phase 1: radix-partition edges by bucket (row>>9) ----------------
__global__ __launch_bounds__(256) void k_part(
    const int* __restrict__ rows, const int* __restrict__ cols,
    const float* __restrict__ ev, const int* __restrict__ pbase,
    const int* __restrict__ bbase,
    int2* __restrict__ part, int E)
{
    __shared__ int base[NB];
    __shared__ int lcnt[NB];
    const int tid = threadIdx.x;
    const int i0 = blockIdx.x * PCHUNK;
    const int n = min(PCHUNK, E - i0);
    for (int t = tid; t < NB; t += 256) {
        base[t] = bbase[t] + pbase[blockIdx.x * NB + t];
        lcnt[t] = 0;
    }
    __syncthreads();
    for (int t = tid; t < n; t += 256) {
        int r = __builtin_nontemporal_load(rows + i0 + t);
        int c = __builtin_nontemporal_load(cols + i0 + t);
        float w = __builtin_nontemporal_load(ev + i0 + t);
        int b = r >> 9;
        int lpos = atomicAdd(&lcnt[b], 1);
        part[base[b] + lpos] = make_int2(((r & (BROWS - 1)) << 17) | c, __float_as_int(w));
    }
}

// ---------------- phase 2: in-bucket row offsets (LDS scan) + final placement ----------------
__global__ __launch_bounds__(256) void k_fill2(
    const int* __restrict__ bbase, const int2* __restrict__ part,
    int* __restrict__ offsets, int2* __restrict__ payload)
{
    __shared__ int lcnt[BROWS];
    __shared__ int lcur[BROWS];
    __shared__ int wsum[4];
    const int b = blockIdx.x;
    const int row0 = b * BROWS;
    const int nrows = min(BROWS, NN - row0);
    const int tid = threadIdx.x;
    for (int t = tid; t < BROWS; t += 256) lcnt[t] = 0;
    __syncthreads();
    const int e0 = bbase[b], e1 = bbase[b + 1];
    for (int i = e0 + tid; i < e1; i += 256)
        atomicAdd(&lcnt[(unsigned)part[i].x >> 17], 1);
    __syncthreads();
    int c0 = lcnt[2 * tid], c1 = lcnt[2 * tid + 1];
    int s = c0 + c1;
    const int lane = tid & 63, wv = tid >> 6;
    int sv = s;
    #pragma unroll
    for (int off = 1; off < 64; off <<= 1) {
        int u = __shfl_up(sv, off, 64);
        if (lane >= off) sv += u;
    }
    if (lane == 63) wsum[wv] = sv;
    __syncthreads();
    int wofs = 0;
    for (int k = 0; k < wv; ++k) wofs += wsum[k];
    int o0 = e0 + wofs + sv - s;
    int o1 = o0 + c0;
    lcur[2 * tid] = o0;
    lcur[2 * tid + 1] = o1;
    if (2 * tid < nrows)     offsets[row0 + 2 * tid]     = o0;
    if (2 * tid + 1 < nrows) offsets[row0 + 2 * tid + 1] = o1;
    __syncthreads();
    for (int i = e0 + tid; i < e1; i += 256) {
        int2 rec = part[i];
        int rowoff = (unsigned)rec.x >> 17;
        int pos = atomicAdd(&lcur[rowoff], 1);
        payload[pos] = make_int2(rec.x & 0x1FFFF, rec.y);
    }
}

// ---------------- segment gather-reduce (fp8 source, 2-deep pipelined) ----------------
__global__ __launch_bounds__(256) void k_gather(
    const int* __restrict__ offsets, const int2* __restrict__ payload,
    const unsigned char* __restrict__ h2f8, unsigned short* __restrict__ hnb)
{
    const int lane = threadIdx.x & 63;
    const int g = lane >> 4, c0 = lane & 15;
    int w = (blockIdx.x * 256 + threadIdx.x) >> 6;
    const int nw = (gridDim.x * 256) >> 6;
    for (int row = w; row < NN; row += nw) {
        const int b = offsets[row], e = offsets[row + 1];
        float ax = 0.f, ay = 0.f, az = 0.f, aw = 0.f;
        int i = b + g;
        for (; i + 4 < e; i += 8) {
            int2 p0 = payload[i];
            int2 p1 = payload[i + 4];
            float w0 = __int_as_float(p0.y);
            float w1 = __int_as_float(p1.y);
            const int u0 = *(const int*)(h2f8 + (size_t)p0.x * 64 + c0 * 4);
            const int u1 = *(const int*)(h2f8 + (size_t)p1.x * 64 + c0 * 4);
            ax = fmaf(__builtin_amdgcn_cvt_f32_fp8(u0, 0), w0, ax);
            ay = fmaf(__builtin_amdgcn_cvt_f32_fp8(u0, 1), w0, ay);
            az = fmaf(__builtin_amdgcn_cvt_f32_fp8(u0, 2), w0, az);
            aw = fmaf(__builtin_amdgcn_cvt_f32_fp8(u0, 3), w0, aw);
            ax = fmaf(__builtin_amdgcn_cvt_f32_fp8(u1, 0), w1, ax);
            ay = fmaf(__builtin_amdgcn_cvt_f32_fp8(u1, 1), w1, ay);
            az = fmaf(__builtin_amdgcn_cvt_f32_fp8(u1, 2), w1, az);
            aw = fmaf(__builtin_amdgcn_cvt_f32_fp8(u1, 3), w1, aw);
        }
        if (i < e) {
            int2 p = payload[i];
            float wt = __int_as_float(p.y);
            const int u = *(const int*)(h2f8 + (size_t)p.x * 64 + c0 * 4);
            ax = fmaf(__builtin_amdgcn_cvt_f32_fp8(u, 0), wt, ax);
            ay = fmaf(__builtin_amdgcn_cvt_f32_fp8(u, 1), wt, ay);
            az = fmaf(__builtin_amdgcn_cvt_f32_fp8(u, 2), wt, az);
            aw = fmaf(__builtin_amdgcn_cvt_f32_fp8(u, 3), wt, aw);
        }
        ax += __shfl_xor(ax, 16, 64); ax += __shfl_xor(ax, 32, 64);
        ay += __shfl_xor(ay, 16, 64); ay += __shfl_xor(ay, 32, 64);
        az += __shfl_xor(az, 16, 64); az += __shfl_xor(az, 32, 64);
        aw += __shfl_xor(aw, 16, 64); aw += __shfl_xor(aw, 32, 64);
        if (g == 0) {
            ushort4 o;
            o.x = f2bu(ax); o.y = f2bu(ay); o.z = f2bu(az); o.w = f2bu(aw);
            *(ushort4*)(hnb + (size_t)row * 64 + c0 * 4) = o;
        }
    }
}

// ---------------- Q/K/V projection via MFMA -> Q bf16, K/V fp8 ----------------
__global__ __launch_bounds__(256) void k_projqkv_mfma(
    const float* __restrict__ x, const short* __restrict__ S,
    const float* __restrict__ bq, const float* __restrict__ bk,
    const float* __restrict__ bv,
    unsigned short* __restrict__ Qp, unsigned char* __restrict__ Kp8,
    unsigned char* __restrict__ Vp8)
{
    const int lane = threadIdx.x & 63;
    const int c0 = lane & 15;
    const int g  = lane >> 4;
    const bf16x8* wq = (const bf16x8*)(S + OFF_WQ);
    const bf16x8* wk = (const bf16x8*)(S + OFF_WK);
    const bf16x8* wv = (const bf16x8*)(S + OFF_WV);

    float bqv[4], bkv[4], bvv[4];
    #pragma unroll
    for (int nt = 0; nt < 4; ++nt) {
        bqv[nt] = bq[nt * 16 + c0];
        bkv[nt] = bk[nt * 16 + c0];
        bvv[nt] = bv[nt * 16 + c0];
    }

    int wid = (blockIdx.x * 256 + threadIdx.x) >> 6;
    const int nwaves = (gridDim.x * 256) >> 6;
    for (int tile = wid; tile < NN / 16; tile += nwaves) {
        const int row0 = tile * 16;
        const float* ar = x + (size_t)(row0 + c0) * D + g * 8;
        bf16x8 a0, a1;
        {
            float4 f0 = *(const float4*)(ar);
            float4 f1 = *(const float4*)(ar + 4);
            float4 f2 = *(const float4*)(ar + 32);
            float4 f3 = *(const float4*)(ar + 36);
            a0[0] = f2b(f0.x); a0[1] = f2b(f0.y); a0[2] = f2b(f0.z); a0[3] = f2b(f0.w);
            a0[4] = f2b(f1.x); a0[5] = f2b(f1.y); a0[6] = f2b(f1.z); a0[7] = f2b(f1.w);
            a1[0] = f2b(f2.x); a1[1] = f2b(f2.y); a1[2] = f2b(f2.z); a1[3] = f2b(f2.w);
            a1[4] = f2b(f3.x); a1[5] = f2b(f3.y); a1[6] = f2b(f3.z); a1[7] = f2b(f3.w);
        }
        f32x4 aq[4], ak[4], av[4];
        #pragma unroll
        for (int nt = 0; nt < 4; ++nt) {
            f32x4 cq = {bqv[nt], bqv[nt], bqv[nt], bqv[nt]};
            cq = __builtin_amdgcn_mfma_f32_16x16x32_bf16(a0, wq[(nt * 2 + 0) * 64 + lane], cq, 0, 0, 0);
            cq = __builtin_amdgcn_mfma_f32_16x16x32_bf16(a1, wq[(nt * 2 + 1) * 64 + lane], cq, 0, 0, 0);
            aq[nt] = cq;
            f32x4 ck = {bkv[nt], bkv[nt], bkv[nt], bkv[nt]};
            ck = __builtin_amdgcn_mfma_f32_16x16x32_bf16(a0, wk[(nt * 2 + 0) * 64 + lane], ck, 0, 0, 0);
            ck = __builtin_amdgcn_mfma_f32_16x16x32_bf16(a1, wk[(nt * 2 + 1) * 64 + lane], ck, 0, 0, 0);
            ak[nt] = ck;
            f32x4 cv = {bvv[nt], bvv[nt], bvv[nt], bvv[nt]};
            cv = __builtin_amdgcn_mfma_f32_16x16x32_bf16(a0, wv[(nt * 2 + 0) * 64 + lane], cv, 0, 0, 0);
            cv = __builtin_amdgcn_mfma_f32_16x16x32_bf16(a1, wv[(nt * 2 + 1) * 64 + lane], cv, 0, 0, 0);
            av[nt] = cv;
        }
        const int r0 = row0 + g * 4;
        #pragma unroll
        for (int r = 0; r < 4; ++r) {
            #pragma unroll
            for (int nt = 0; nt < 4; ++nt) {
                Qp[(size_t)(r0 + r) * D + nt * 16 + c0] = f2bu(aq[nt][r]);
                Kp8[(size_t)(r0 + r) * D + nt * 16 + c0] = f2fp8(ak[nt][r]);
                Vp8[(size_t)(r0 + r) * D + nt * 16 + c0] = f2fp8(av[nt][r]);
            }
        }
    }
}

// ---------------- attention core: fp8 K/V gathers + per-head softmax + PV -> ob ----------------
__global__ __launch_bounds__(256) void k_attn_lite(
    const unsigned short* __restrict__ Qp,
    const unsigned char* __restrict__ Kp8, const unsigned char* __restrict__ Vp8,
    const int* __restrict__ samp, unsigned short* __restrict__ ob)
{
    const int lane = threadIdx.x & 63;
    const int g = lane >> 4, c0 = lane & 15;
    int w = (blockIdx.x * 256 + threadIdx.x) >> 6;
    const int nw = (gridDim.x * 256) >> 6;
    for (int row = w; row < NN; row += nw) {
        int idx_reg = (lane < KS) ? samp[row * KS + lane] : 0;
        const ushort4 qv = *(const ushort4*)(Qp + (size_t)row * D + c0 * 4);
        float q0 = b2f(qv.x), q1 = b2f(qv.y), q2 = b2f(qv.z), q3 = b2f(qv.w);

        // group g handles samples g*5 .. g*5+4
        float s[5];
        int v4[5];
        #pragma unroll
        for (int t = 0; t < 5; ++t) {
            int idx = __shfl(idx_reg, g * 5 + t, 64);
            const int ku = *(const int*)(Kp8 + (size_t)idx * D + c0 * 4);
            v4[t] = *(const int*)(Vp8 + (size_t)idx * D + c0 * 4);
            float sc = q0 * __builtin_amdgcn_cvt_f32_fp8(ku, 0);
            sc = fmaf(q1, __builtin_amdgcn_cvt_f32_fp8(ku, 1), sc);
            sc = fmaf(q2, __builtin_amdgcn_cvt_f32_fp8(ku, 2), sc);
            sc = fmaf(q3, __builtin_amdgcn_cvt_f32_fp8(ku, 3), sc);
            // per-head dot: head = c0>>2 spans lanes (c0&~3)..(c0|3)
            sc += __shfl_xor(sc, 1, 64);
            sc += __shfl_xor(sc, 2, 64);
            s[t] = sc * 0.25f;   // 1/sqrt(DH=16)
        }
        // per-head softmax over 20 samples (5 local x 4 groups; xor16/32 keep c0 => within-head)
        float m = fmaxf(fmaxf(fmaxf(s[0], s[1]), fmaxf(s[2], s[3])), s[4]);
        m = fmaxf(m, __shfl_xor(m, 16, 64));
        m = fmaxf(m, __shfl_xor(m, 32, 64));
        float o0 = 0.f, o1 = 0.f, o2 = 0.f, o3 = 0.f, ssum = 0.f;
        #pragma unroll
        for (int t = 0; t < 5; ++t) {
            float p = __expf(s[t] - m);
            ssum += p;
            o0 = fmaf(p, __builtin_amdgcn_cvt_f32_fp8(v4[t], 0), o0);
            o1 = fmaf(p, __builtin_amdgcn_cvt_f32_fp8(v4[t], 1), o1);
            o2 = fmaf(p, __builtin_amdgcn_cvt_f32_fp8(v4[t], 2), o2);
            o3 = fmaf(p, __builtin_amdgcn_cvt_f32_fp8(v4[t], 3), o3);
        }
        ssum += __shfl_xor(ssum, 16, 64);
        ssum += __shfl_xor(ssum, 32, 64);
        float inv = 1.0f / ssum;
        o0 += __shfl_xor(o0, 16, 64); o0 += __shfl_xor(o0, 32, 64);
        o1 += __shfl_xor(o1, 16, 64); o1 += __shfl_xor(o1, 32, 64);
        o2 += __shfl_xor(o2, 16, 64); o2 += __shfl_xor(o2, 32, 64);
        o3 += __shfl_xor(o3, 16, 64); o3 += __shfl_xor(o3, 32, 64);
        if (g == 0) {
            ushort4 o;
            o.x = f2bu(o0 * inv); o.y = f2bu(o1 * inv);
            o.z = f2bu(o2 * inv); o.w = f2bu(o3 * inv);
            *(ushort4*)(ob + (size_t)row * D + c0 * 4) = o;
        }
    }
}

// ---------------- Wo projection + residual + LN1 via MFMA -> hb fp32 ----------------
__global__ __launch_bounds__(256) void k_attno_mfma(
    const unsigned short* __restrict__ ob, const float* __restrict__ x,
    const short* __restrict__ S,
    const float* __restrict__ bo, const float* __restrict__ g1,
    const float* __restrict__ be1,
    float* __restrict__ hb)
{
    const int lane = threadIdx.x & 63;
    const int c0 = lane & 15;
    const int g  = lane >> 4;
    const bf16x8* wp = (const bf16x8*)(S + OFF_WO);

    float bov[4], g1v[4], b1v[4];
    #pragma unroll
    for (int nt = 0; nt < 4; ++nt) {
        bov[nt] = bo[nt * 16 + c0];
        g1v[nt] = g1[nt * 16 + c0];
        b1v[nt] = be1[nt * 16 + c0];
    }

    int wid = (blockIdx.x * 256 + threadIdx.x) >> 6;
    const int nwaves = (gridDim.x * 256) >> 6;
    for (int tile = wid; tile < NN / 16; tile += nwaves) {
        const int row0 = tile * 16;
        bf16x8 a[2];
        #pragma unroll
        for (int kt = 0; kt < 2; ++kt)
            a[kt] = *(const bf16x8*)&ob[(size_t)(row0 + c0) * D + kt * 32 + g * 8];
        f32x4 acc[4];
        #pragma unroll
        for (int nt = 0; nt < 4; ++nt) {
            f32x4 c = {bov[nt], bov[nt], bov[nt], bov[nt]};
            #pragma unroll
            for (int kt = 0; kt < 2; ++kt)
                c = __builtin_amdgcn_mfma_f32_16x16x32_bf16(a[kt], wp[(nt * 2 + kt) * 64 + lane], c, 0, 0, 0);
            acc[nt] = c;
        }
        const int r0 = row0 + g * 4;
        #pragma unroll
        for (int r = 0; r < 4; ++r) {
            float rv[4];
            float s = 0.f;
            #pragma unroll
            for (int nt = 0; nt < 4; ++nt) {
                rv[nt] = acc[nt][r] + x[(size_t)(r0 + r) * D + nt * 16 + c0];
                s += rv[nt];
            }
            s = gsum16(s);
            float mu = s * (1.f / 64.f);
            float q = 0.f;
            #pragma unroll
            for (int nt = 0; nt < 4; ++nt) { float d = rv[nt] - mu; q += d * d; }
            q = gsum16(q);
            float inv = rsqrtf(q * (1.f / 64.f) + EPS);
            #pragma unroll
            for (int nt = 0; nt < 4; ++nt)
                hb[(size_t)(r0 + r) * D + nt * 16 + c0] = (rv[nt] - mu) * inv * g1v[nt] + b1v[nt];
        }
    }
}

// ---------------- FFN via MFMA -> bf16 h2 + fp8 copy ----------------
__global__ __launch_bounds__(256) void k_ffn_mfma(
    const float* __restrict__ hb,
    const short* __restrict__ wf,
    const float* __restrict__ bf1, const float* __restrict__ bf2,
    const float* __restrict__ g2, const float* __restrict__ be2,
    unsigned short* __restrict__ h2b, unsigned char* __restrict__ h2f8)
{
    __shared__ __align__(16) short Tl[4][16][264];
    const int lane = threadIdx.x & 63;
    const int wv   = threadIdx.x >> 6;
    const int c0   = lane & 15;
    const int g    = lane >> 4;
    const bf16x8* w1p = (const bf16x8*)(wf + OFF_W1);
    const bf16x8* w2p = (const bf16x8*)(wf + OFF_W2);

    float b1v[16];
    #pragma unroll
    for (int nt = 0; nt < 16; ++nt) b1v[nt] = bf1[nt * 16 + c0];
    float b2v[4], g2v[4], bev[4];
    #pragma unroll
    for (int nt = 0; nt < 4; ++nt) {
        b2v[nt] = bf2[nt * 16 + c0];
        g2v[nt] = g2[nt * 16 + c0];
        bev[nt] = be2[nt * 16 + c0];
    }

    int wid = (blockIdx.x * 256 + threadIdx.x) >> 6;
    const int nwaves = (gridDim.x * 256) >> 6;
    for (int tile = wid; tile < NN / 16; tile += nwaves) {
        const int row0 = tile * 16;
        const float* ar = hb + (size_t)(row0 + c0) * D + g * 8;
        bf16x8 a0, a1;
        {
            float4 f0 = *(const float4*)(ar);
            float4 f1 = *(const float4*)(ar + 4);
            float4 f2 = *(const float4*)(ar + 32);
            float4 f3 = *(const float4*)(ar + 36);
            a0[0] = f2b(f0.x); a0[1] = f2b(f0.y); a0[2] = f2b(f0.z); a0[3] = f2b(f0.w);
            a0[4] = f2b(f1.x); a0[5] = f2b(f1.y); a0[6] = f2b(f1.z); a0[7] = f2b(f1.w);
            a1[0] = f2b(f2.x); a1[1] = f2b(f2.y); a1[2] = f2b(f2.z); a1[3] = f2b(f2.w);
            a1[4] = f2b(f3.x); a1[5] = f2b(f3.y); a1[6] = f2b(f3.z); a1[7] = f2b(f3.w);
        }
        f32x4 acc1[16];
        #pragma unroll
        for (int nt = 0; nt < 16; ++nt) {
            float b = b1v[nt];
            f32x4 c = {b, b, b, b};
            c = __builtin_amdgcn_mfma_f32_16x16x32_bf16(a0, w1p[(nt * 2 + 0) * 64 + lane], c, 0, 0, 0);
            c = __builtin_amdgcn_mfma_f32_16x16x32_bf16(a1, w1p[(nt * 2 + 1) * 64 + lane], c, 0, 0, 0);
            acc1[nt] = c;
        }
        #pragma unroll
        for (int nt = 0; nt < 16; ++nt) {
            #pragma unroll
            for (int r = 0; r < 4; ++r)
                Tl[wv][g * 4 + r][nt * 16 + c0] = f2b(fmaxf(acc1[nt][r], 0.f));
        }
        bf16x8 a2[8];
        #pragma unroll
        for (int kt = 0; kt < 8; ++kt)
            a2[kt] = *(const bf16x8*)&Tl[wv][c0][kt * 32 + g * 8];
        f32x4 acc2[4];
        #pragma unroll
        for (int nt = 0; nt < 4; ++nt) {
            float b = b2v[nt];
            f32x4 c = {b, b, b, b};
            #pragma unroll
            for (int kt = 0; kt < 8; ++kt)
                c = __builtin_amdgcn_mfma_f32_16x16x32_bf16(a2[kt], w2p[(nt * 8 + kt) * 64 + lane], c, 0, 0, 0);
            acc2[nt] = c;
        }
        const int r0 = row0 + g * 4;
        #pragma unroll
        for (int r = 0; r < 4; ++r) {
            float rv[4];
            float s = 0.f;
            #pragma unroll
            for (int nt = 0; nt < 4; ++nt) {
                rv[nt] = acc2[nt][r] + hb[(size_t)(r0 + r) * D + nt * 16 + c0];
                s += rv[nt];
            }
            s = gsum16(s);
            float mu = s * (1.f / 64.f);
            float q = 0.f;
            #pragma unroll
            for (int nt = 0; nt < 4; ++nt) { float d = rv[nt] - mu; q += d * d; }
            q = gsum16(q);
            float inv = rsqrtf(q * (1.f / 64.f) + EPS);
            #pragma unroll
            for (int nt = 0; nt < 4; ++nt) {
                float hv = (rv[nt] - mu) * inv * g2v[nt] + bev[nt];
                h2b[(size_t)(r0 + r) * D + nt * 16 + c0] = f2bu(hv);
                h2f8[(size_t)(r0 + r) * D + nt * 16 + c0] = f2fp8(hv);
            }
        }
    }
}

// ---------------- GNN linear (MFMA, bf16 inputs) + relu + residual + LN -> fp32 out ----------------
__global__ __launch_bounds__(256) void k_gnn_mfma(
    const unsigned short* __restrict__ h2b, const unsigned short* __restrict__ hnb,
    const short* __restrict__ S,
    const float* __restrict__ bg, const float* __restrict__ gg,
    const float* __restrict__ bgn,
    float* __restrict__ out)
{
    const int lane = threadIdx.x & 63;
    const int c0 = lane & 15;
    const int g  = lane >> 4;
    const bf16x8* wp = (const bf16x8*)(S + OFF_WG);

    float bgv[4], ggv[4], bnv[4];
    #pragma unroll
    for (int nt = 0; nt < 4; ++nt) {
        bgv[nt] = bg[nt * 16 + c0];
        ggv[nt] = gg[nt * 16 + c0];
        bnv[nt] = bgn[nt * 16 + c0];
    }

    int wid = (blockIdx.x * 256 + threadIdx.x) >> 6;
    const int nwaves = (gridDim.x * 256) >> 6;
    for (int tile = wid; tile < NN / 16; tile += nwaves) {
        const int row0 = tile * 16;
        bf16x8 a[4];
        #pragma unroll
        for (int kt = 0; kt < 2; ++kt) {
            a[kt]     = *(const bf16x8*)&h2b[(size_t)(row0 + c0) * 64 + kt * 32 + g * 8];
            a[2 + kt] = *(const bf16x8*)&hnb[(size_t)(row0 + c0) * 64 + kt * 32 + g * 8];
        }
        f32x4 acc[4];
        #pragma unroll
        for (int nt = 0; nt < 4; ++nt) {
            float b = bgv[nt];
            f32x4 c = {b, b, b, b};
            #pragma unroll
            for (int kt = 0; kt < 4; ++kt)
                c = __builtin_amdgcn_mfma_f32_16x16x32_bf16(a[kt], wp[(nt * 4 + kt) * 64 + lane], c, 0, 0, 0);
            acc[nt] = c;
        }
        const int r0 = row0 + g * 4;
        #pragma unroll
        for (int r = 0; r < 4; ++r) {
            float rv[4];
            float s = 0.f;
            #pragma unroll
            for (int nt = 0; nt < 4; ++nt) {
                float hn = fmaxf(acc[nt][r], 0.f);
                rv[nt] = hn + b2f(h2b[(size_t)(r0 + r) * 64 + nt * 16 + c0]);
                s += rv[nt];
            }
            s = gsum16(s);
            float mu = s * (1.f / 64.f);
            float q = 0.f;
            #pragma unroll
            for (int nt = 0; nt < 4; ++nt) { float d = rv[nt] - mu; q += d * d; }
            q = gsum16(q);
            float inv = rsqrtf(q * (1.f / 64.f) + EPS);
            #pragma unroll
            for (int nt = 0; nt < 4; ++nt)
                out[(size_t)(r0 + r) * D + nt * 16 + c0] = (rv[nt] - mu) * inv * ggv[nt] + bnv[nt];
        }
    }
}

// ---------------- attention_samples passthrough (as fp32) ----------------
__global__ __launch_bounds__(256) void k_samples(
    const int* __restrict__ samp, float* __restrict__ out, int n)
{
    int i = blockIdx.x * blockDim.x + threadIdx.x;
    const int stride = gridDim.x * blockDim.x;
    for (; i < n; i += stride) out[i] = (float)samp[i];
}

extern "C" void kernel_launch(void* const* d_in, const int* in_sizes, int n_in,
                              void* d_out, int out_size, void* d_ws, size_t ws_size,
                              hipStream_t stream)
{
    const float* x   = (const float*)d_in[0];
    const int*   rows = (const int*)d_in[1];
    const int*   cols = (const int*)d_in[2];
    const float* ev  = (const float*)d_in[3];
    const int*   samp = (const int*)d_in[4];
    const float* Wq  = (const float*)d_in[5];
    const float* bq  = (const float*)d_in[6];
    const float* Wk  = (const float*)d_in[7];
    const float* bk  = (const float*)d_in[8];
    const float* Wv  = (const float*)d_in[9];
    const float* bv  = (const float*)d_in[10];
    const float* Wo  = (const float*)d_in[11];
    const float* bo  = (const float*)d_in[12];
    const float* g1  = (const float*)d_in[13];
    const float* be1 = (const float*)d_in[14];
    const float* g2  = (const float*)d_in[15];
    const float* be2 = (const float*)d_in[16];
    const float* W1  = (const float*)d_in[17];
    const float* bf1 = (const float*)d_in[18];
    const float* W2  = (const float*)d_in[19];
    const float* bf2 = (const float*)d_in[20];
    const float* Wg  = (const float*)d_in[21];
    const float* bg  = (const float*)d_in[22];
    const float* gg  = (const float*)d_in[23];
    const float* bgn = (const float*)d_in[24];
    const int E = in_sizes[1];
    const int npb = (E + PCHUNK - 1) / PCHUNK;

    // ws layout: 3 buffers of NN*D floats (76.8 MB)
    float* buf0 = (float*)d_ws;                   // [Kp8 | Vp8] fp8 -> payload (int2[E])
    float* buf1 = buf0 + (size_t)NN * D;          // [Qp_b -> hnb_b | ob -> h2b] bf16
    float* buf2 = buf1 + (size_t)NN * D;          // hb fp32 -> part (int2[E])
    unsigned char* Kp8 = (unsigned char*)buf0;                         // NN*64 bytes
    unsigned char* Vp8 = Kp8 + (size_t)NN * D;                         // NN*64 bytes
    int2* payload = (int2*)buf0;                       // overwrites Kp8/Vp8 after attn
    unsigned short* Qp_b  = (unsigned short*)buf1;     // dead after attn -> hnb slot
    unsigned short* hnb_b = (unsigned short*)buf1;
    unsigned short* ob    = (unsigned short*)(buf1 + (size_t)NN * D / 2); // dead after attno -> h2b slot
    unsigned short* h2b   = ob;
    float* hb = buf2;
    int2* part = (int2*)buf2;                          // overwrites hb after ffn

    float* out = (float*)d_out;
    // scratch in samples region of d_out (rewritten by k_samples each call; 8 MB available)
    short* S     = (short*)(out + (size_t)NN * D);   // S_TOTAL shorts
    int* offsets = (int*)(S + S_TOTAL);              // NN+1
    int* bbase   = offsets + NN + 1;                 // NB+1
    int* btot    = bbase + NB + 1;                   // NB
    int* partial = btot + NB;                        // npb*NB
    unsigned char* h2f8 = (unsigned char*)(partial + (size_t)npb * NB); // NN*64 bytes (6.4MB)

    k_prep<<<56, 256, 0, stream>>>(W1, W2, Wg, Wq, Wk, Wv, Wo, S);
    k_bhist<<<npb, 256, 0, stream>>>(rows, partial, E);
    k_pscan_a<<<NB, 256, 0, stream>>>(partial, btot, npb);
    k_pscan_b<<<1, 256, 0, stream>>>(btot, bbase, offsets);
    k_projqkv_mfma<<<1563, 256, 0, stream>>>(x, S, bq, bk, bv, Qp_b, Kp8, Vp8);
    k_attn_lite<<<4096, 256, 0, stream>>>(Qp_b, Kp8, Vp8, samp, ob);
    k_attno_mfma<<<1563, 256, 0, stream>>>(ob, x, S, bo, g1, be1, hb);
    k_ffn_mfma<<<1563, 256, 0, stream>>>(hb, S, bf1, bf2, g2, be2, h2b, h2f8);
    k_part<<<npb, 256, 0, stream>>>(rows, cols, ev, partial, bbase, part, E);
    k_fill2<<<NB, 256, 0, stream>>>(bbase, part, offsets, payload);
    k_gather<<<4096, 256, 0, stream>>>(offsets, payload, h2f8, hnb_b);
    k_gnn_mfma<<<1563, 256, 0, stream>>>(h2b, hnb_b, S, bg, gg, bgn, out);
    k_samples<<<2048, 256, 0, stream>>>(samp, out + (size_t)NN * D, NN * KS);
}

// Round 14
// 301.914 us; speedup vs baseline: 9.0729x; 1.0753x over previous
//
#include <hip/hip_runtime.h>
#include <hip/hip_bf16.h>

#define NN  100000
#define D   64
#define KS  20
#define DFF 256
#define EPS 1e-5f

// radix-partition params
#define BROWS  512
#define NB     ((NN + BROWS - 1) / BROWS)   // 196 buckets
#define PCHUNK 8192                          // edges per chunk (k_bhist & k_part)

// frag-buffer offsets (shorts)
#define OFF_W1 0
#define OFF_W2 16384
#define OFF_WG 32768
#define OFF_WQ 40960
#define OFF_WK 45056
#define OFF_WV 49152
#define OFF_WO 53248
#define S_TOTAL 57344

typedef __attribute__((ext_vector_type(8))) short bf16x8;
typedef __attribute__((ext_vector_type(4))) float f32x4;

__device__ __forceinline__ short f2b(float f) {
    return __builtin_bit_cast(short, __float2bfloat16(f));
}
__device__ __forceinline__ unsigned short f2bu(float f) {
    return __builtin_bit_cast(unsigned short, __float2bfloat16(f));
}
__device__ __forceinline__ float b2f(unsigned short u) {
    return __builtin_bit_cast(float, ((unsigned)u) << 16);
}
__device__ __forceinline__ unsigned char f2fp8(float v) {
    int p = __builtin_amdgcn_cvt_pk_fp8_f32(v, v, 0, false);
    return (unsigned char)(p & 0xFF);
}
__device__ __forceinline__ float gsum16(float v) {
    v += __shfl_xor(v, 1, 64);
    v += __shfl_xor(v, 2, 64);
    v += __shfl_xor(v, 4, 64);
    v += __shfl_xor(v, 8, 64);
    return v;
}

// ---------------- weight fragment prep (bf16, B-operand layout) ----------------
__global__ __launch_bounds__(256) void k_prep(
    const float* __restrict__ W1, const float* __restrict__ W2,
    const float* __restrict__ Wg,
    const float* __restrict__ Wq, const float* __restrict__ Wk,
    const float* __restrict__ Wv, const float* __restrict__ Wo,
    short* __restrict__ S)
{
    int idx = blockIdx.x * 256 + threadIdx.x;
    for (; idx < S_TOTAL; idx += gridDim.x * 256) {
        float v;
        if (idx < OFF_W2) {                 // W1 [64 x 256]
            int f = idx >> 9, rem = idx & 511;
            int l = rem >> 3, i = rem & 7;
            int nt = f >> 1, kt = f & 1;
            v = W1[(kt * 32 + (l >> 4) * 8 + i) * DFF + nt * 16 + (l & 15)];
        } else if (idx < OFF_WG) {          // W2 [256 x 64]
            int j = idx - OFF_W2;
            int f = j >> 9, rem = j & 511;
            int l = rem >> 3, i = rem & 7;
            int nt = f >> 3, kt = f & 7;
            v = W2[(kt * 32 + (l >> 4) * 8 + i) * D + nt * 16 + (l & 15)];
        } else if (idx < OFF_WQ) {          // Wg [128 x 64]
            int j = idx - OFF_WG;
            int f = j >> 9, rem = j & 511;
            int l = rem >> 3, i = rem & 7;
            int nt = f >> 2, kt = f & 3;
            v = Wg[(kt * 32 + (l >> 4) * 8 + i) * D + nt * 16 + (l & 15)];
        } else {                            // Wq/Wk/Wv/Wo [64 x 64]
            int j = idx - OFF_WQ;
            const float* W = (j < 4096) ? Wq : (j < 8192) ? Wk : (j < 12288) ? Wv : Wo;
            j &= 4095;
            int f = j >> 9, rem = j & 511;
            int l = rem >> 3, i = rem & 7;
            int nt = f >> 1, kt = f & 1;
            v = W[(kt * 32 + (l >> 4) * 8 + i) * D + nt * 16 + (l & 15)];
        }
        S[idx] = f2b(v);
    }
}

// ---------------- per-chunk bucket histogram (dense write, NO global atomics) ----------------
__global__ __launch_bounds__(256) void k_bhist(
    const int* __restrict__ rows, int* __restrict__ partial, int E)
{
    __shared__ int h[NB];
    for (int t = threadIdx.x; t < NB; t += 256) h[t] = 0;
    __syncthreads();
    const int i0 = blockIdx.x * PCHUNK;
    const int n = min(PCHUNK, E - i0);
    for (int t = threadIdx.x; t < n; t += 256)
        atomicAdd(&h[__builtin_nontemporal_load(rows + i0 + t) >> 9], 1);
    __syncthreads();
    for (int t = threadIdx.x; t < NB; t += 256)
        partial[blockIdx.x * NB + t] = h[t];
}

// ---------------- parallel 2D prefix, stage A: per-bucket scan over chunks ----------------
__global__ __launch_bounds__(256) void k_pscan_a(
    int* __restrict__ partial, int* __restrict__ btot, int npb)
{
    __shared__ int wsum[4];
    __shared__ int s_carry;
    const int b = blockIdx.x;
    const int tid = threadIdx.x;
    const int lane = tid & 63, wv = tid >> 6;
    if (tid == 0) s_carry = 0;
    __syncthreads();
    for (int base = 0; base < npb; base += 512) {
        int p0 = base + 2 * tid, p1 = p0 + 1;
        int c0 = (p0 < npb) ? partial[p0 * NB + b] : 0;
        int c1 = (p1 < npb) ? partial[p1 * NB + b] : 0;
        int s = c0 + c1;
        int sv = s;
        #pragma unroll
        for (int off = 1; off < 64; off <<= 1) {
            int u = __shfl_up(sv, off, 64);
            if (lane >= off) sv += u;
        }
        if (lane == 63) wsum[wv] = sv;
        __syncthreads();
        int wofs = 0;
        for (int k = 0; k < wv; ++k) wofs += wsum[k];
        int o0 = s_carry + wofs + sv - s;
        int o1 = o0 + c0;
        if (p0 < npb) partial[p0 * NB + b] = o0;
        if (p1 < npb) partial[p1 * NB + b] = o1;
        __syncthreads();
        if (tid == 0) s_carry += wsum[0] + wsum[1] + wsum[2] + wsum[3];
        __syncthreads();
    }
    if (tid == 0) btot[b] = s_carry;
}

// ---------------- stage B: bucket scan of totals -> bbase; offsets[NN]=E ----------------
__global__ __launch_bounds__(256) void k_pscan_b(
    const int* __restrict__ btot, int* __restrict__ bbase,
    int* __restrict__ offsets)
{
    __shared__ int wsum[4];
    const int t = threadIdx.x;
    const int lane = t & 63, wv = t >> 6;
    int v = (t < NB) ? btot[t] : 0;
    int sv = v;
    #pragma unroll
    for (int off = 1; off < 64; off <<= 1) {
        int u = __shfl_up(sv, off, 64);
        if (lane >= off) sv += u;
    }
    if (lane == 63) wsum[wv] = sv;
    __syncthreads();
    int wofs = 0;
    for (int k = 0; k < wv; ++k) wofs += wsum[k];
    int excl = wofs + sv - v;
    if (t < NB) bbase[t] = excl;
    if (t == 0) {
        int tot = wsum[0] + wsum[1] + wsum[2] + wsum[3];
        bbase[NB] = tot;
        offsets[NN] = tot;
    }
}

// ---------------- phase 1: radix-partition edges by bucket (row>>9) ----------------
__global__ __launch_bounds__(256) void k_part(
    const int* __restrict__ rows, const int* __restrict__ cols,
    const float* __restrict__ ev, const int* __restrict__ pbase,
    const int* __restrict__ bbase,
    int2* __restrict__ part, int E)
{
    __shared__ int base[NB];
    __shared__ int lcnt[NB];
    const int tid = threadIdx.x;
    const int i0 = blockIdx.x * PCHUNK;
    const int n = min(PCHUNK, E - i0);
    for (int t = tid; t < NB; t += 256) {
        base[t] = bbase[t] + pbase[blockIdx.x * NB + t];
        lcnt[t] = 0;
    }
    __syncthreads();
    for (int t = tid; t < n; t += 256) {
        int r = __builtin_nontemporal_load(rows + i0 + t);
        int c = __builtin_nontemporal_load(cols + i0 + t);
        float w = __builtin_nontemporal_load(ev + i0 + t);
        int b = r >> 9;
        int lpos = atomicAdd(&lcnt[b], 1);
        part[base[b] + lpos] = make_int2(((r & (BROWS - 1)) << 17) | c, __float_as_int(w));
    }
}

// ---------------- phase 2: in-bucket row offsets (LDS scan) + packed placement ----------------
// payload: (col << 15) | (bf16(w) & 0x7FFF)  -- w in [0,1) so sign bit is 0
__global__ __launch_bounds__(256) void k_fill2(
    const int* __restrict__ bbase, const int2* __restrict__ part,
    int* __restrict__ offsets, unsigned int* __restrict__ payload)
{
    __shared__ int lcnt[BROWS];
    __shared__ int lcur[BROWS];
    __shared__ int wsum[4];
    const int b = blockIdx.x;
    const int row0 = b * BROWS;
    const int nrows = min(BROWS, NN - row0);
    const int tid = threadIdx.x;
    for (int t = tid; t < BROWS; t += 256) lcnt[t] = 0;
    __syncthreads();
    const int e0 = bbase[b], e1 = bbase[b + 1];
    for (int i = e0 + tid; i < e1; i += 256)
        atomicAdd(&lcnt[(unsigned)part[i].x >> 17], 1);
    __syncthreads();
    int c0 = lcnt[2 * tid], c1 = lcnt[2 * tid + 1];
    int s = c0 + c1;
    const int lane = tid & 63, wv = tid >> 6;
    int sv = s;
    #pragma unroll
    for (int off = 1; off < 64; off <<= 1) {
        int u = __shfl_up(sv, off, 64);
        if (lane >= off) sv += u;
    }
    if (lane == 63) wsum[wv] = sv;
    __syncthreads();
    int wofs = 0;
    for (int k = 0; k < wv; ++k) wofs += wsum[k];
    int o0 = e0 + wofs + sv - s;
    int o1 = o0 + c0;
    lcur[2 * tid] = o0;
    lcur[2 * tid + 1] = o1;
    if (2 * tid < nrows)     offsets[row0 + 2 * tid]     = o0;
    if (2 * tid + 1 < nrows) offsets[row0 + 2 * tid + 1] = o1;
    __syncthreads();
    for (int i = e0 + tid; i < e1; i += 256) {
        int2 rec = part[i];
        int rowoff = (unsigned)rec.x >> 17;
        int pos = atomicAdd(&lcur[rowoff], 1);
        unsigned int col = (unsigned)(rec.x & 0x1FFFF);
        unsigned int wb = (unsigned)(f2bu(__int_as_float(rec.y)) & 0x7FFF);
        payload[pos] = (col << 15) | wb;
    }
}

// ---------------- segment gather-reduce (fp8 source, packed payload) ----------------
__global__ __launch_bounds__(256) void k_gather(
    const int* __restrict__ offsets, const unsigned int* __restrict__ payload,
    const unsigned char* __restrict__ h2f8, unsigned short* __restrict__ hnb)
{
    const int lane = threadIdx.x & 63;
    const int g = lane >> 4, c0 = lane & 15;
    int w = (blockIdx.x * 256 + threadIdx.x) >> 6;
    const int nw = (gridDim.x * 256) >> 6;
    for (int row = w; row < NN; row += nw) {
        const int b = offsets[row], e = offsets[row + 1];
        float ax = 0.f, ay = 0.f, az = 0.f, aw = 0.f;
        int i = b + g;
        for (; i + 4 < e; i += 8) {
            unsigned int p0 = payload[i];
            unsigned int p1 = payload[i + 4];
            float w0 = b2f((unsigned short)((p0 & 0x7FFF)));
            float w1 = b2f((unsigned short)((p1 & 0x7FFF)));
            const int u0 = *(const int*)(h2f8 + (size_t)(p0 >> 15) * 64 + c0 * 4);
            const int u1 = *(const int*)(h2f8 + (size_t)(p1 >> 15) * 64 + c0 * 4);
            ax = fmaf(__builtin_amdgcn_cvt_f32_fp8(u0, 0), w0, ax);
            ay = fmaf(__builtin_amdgcn_cvt_f32_fp8(u0, 1), w0, ay);
            az = fmaf(__builtin_amdgcn_cvt_f32_fp8(u0, 2), w0, az);
            aw = fmaf(__builtin_amdgcn_cvt_f32_fp8(u0, 3), w0, aw);
            ax = fmaf(__builtin_amdgcn_cvt_f32_fp8(u1, 0), w1, ax);
            ay = fmaf(__builtin_amdgcn_cvt_f32_fp8(u1, 1), w1, ay);
            az = fmaf(__builtin_amdgcn_cvt_f32_fp8(u1, 2), w1, az);
            aw = fmaf(__builtin_amdgcn_cvt_f32_fp8(u1, 3), w1, aw);
        }
        if (i < e) {
            unsigned int p = payload[i];
            float wt = b2f((unsigned short)((p & 0x7FFF)));
            const int u = *(const int*)(h2f8 + (size_t)(p >> 15) * 64 + c0 * 4);
            ax = fmaf(__builtin_amdgcn_cvt_f32_fp8(u, 0), wt, ax);
            ay = fmaf(__builtin_amdgcn_cvt_f32_fp8(u, 1), wt, ay);
            az = fmaf(__builtin_amdgcn_cvt_f32_fp8(u, 2), wt, az);
            aw = fmaf(__builtin_amdgcn_cvt_f32_fp8(u, 3), wt, aw);
        }
        ax += __shfl_xor(ax, 16, 64); ax += __shfl_xor(ax, 32, 64);
        ay += __shfl_xor(ay, 16, 64); ay += __shfl_xor(ay, 32, 64);
        az += __shfl_xor(az, 16, 64); az += __shfl_xor(az, 32, 64);
        aw += __shfl_xor(aw, 16, 64); aw += __shfl_xor(aw, 32, 64);
        if (g == 0) {
            ushort4 o;
            o.x = f2bu(ax); o.y = f2bu(ay); o.z = f2bu(az); o.w = f2bu(aw);
            *(ushort4*)(hnb + (size_t)row * 64 + c0 * 4) = o;
        }
    }
}

// ---------------- Q/K/V projection via MFMA -> Q bf16, KV interleaved fp8 ----------------
// KV8 row r: bytes [0..63] = K[r][0..63], bytes [64..127] = V[r][0..63]
__global__ __launch_bounds__(256) void k_projqkv_mfma(
    const float* __restrict__ x, const short* __restrict__ S,
    const float* __restrict__ bq, const float* __restrict__ bk,
    const float* __restrict__ bv,
    unsigned short* __restrict__ Qp, unsigned char* __restrict__ KV8)
{
    const int lane = threadIdx.x & 63;
    const int c0 = lane & 15;
    const int g  = lane >> 4;
    const bf16x8* wq = (const bf16x8*)(S + OFF_WQ);
    const bf16x8* wk = (const bf16x8*)(S + OFF_WK);
    const bf16x8* wv = (const bf16x8*)(S + OFF_WV);

    float bqv[4], bkv[4], bvv[4];
    #pragma unroll
    for (int nt = 0; nt < 4; ++nt) {
        bqv[nt] = bq[nt * 16 + c0];
        bkv[nt] = bk[nt * 16 + c0];
        bvv[nt] = bv[nt * 16 + c0];
    }

    int wid = (blockIdx.x * 256 + threadIdx.x) >> 6;
    const int nwaves = (gridDim.x * 256) >> 6;
    for (int tile = wid; tile < NN / 16; tile += nwaves) {
        const int row0 = tile * 16;
        const float* ar = x + (size_t)(row0 + c0) * D + g * 8;
        bf16x8 a0, a1;
        {
            float4 f0 = *(const float4*)(ar);
            float4 f1 = *(const float4*)(ar + 4);
            float4 f2 = *(const float4*)(ar + 32);
            float4 f3 = *(const float4*)(ar + 36);
            a0[0] = f2b(f0.x); a0[1] = f2b(f0.y); a0[2] = f2b(f0.z); a0[3] = f2b(f0.w);
            a0[4] = f2b(f1.x); a0[5] = f2b(f1.y); a0[6] = f2b(f1.z); a0[7] = f2b(f1.w);
            a1[0] = f2b(f2.x); a1[1] = f2b(f2.y); a1[2] = f2b(f2.z); a1[3] = f2b(f2.w);
            a1[4] = f2b(f3.x); a1[5] = f2b(f3.y); a1[6] = f2b(f3.z); a1[7] = f2b(f3.w);
        }
        f32x4 aq[4], ak[4], av[4];
        #pragma unroll
        for (int nt = 0; nt < 4; ++nt) {
            f32x4 cq = {bqv[nt], bqv[nt], bqv[nt], bqv[nt]};
            cq = __builtin_amdgcn_mfma_f32_16x16x32_bf16(a0, wq[(nt * 2 + 0) * 64 + lane], cq, 0, 0, 0);
            cq = __builtin_amdgcn_mfma_f32_16x16x32_bf16(a1, wq[(nt * 2 + 1) * 64 + lane], cq, 0, 0, 0);
            aq[nt] = cq;
            f32x4 ck = {bkv[nt], bkv[nt], bkv[nt], bkv[nt]};
            ck = __builtin_amdgcn_mfma_f32_16x16x32_bf16(a0, wk[(nt * 2 + 0) * 64 + lane], ck, 0, 0, 0);
            ck = __builtin_amdgcn_mfma_f32_16x16x32_bf16(a1, wk[(nt * 2 + 1) * 64 + lane], ck, 0, 0, 0);
            ak[nt] = ck;
            f32x4 cv = {bvv[nt], bvv[nt], bvv[nt], bvv[nt]};
            cv = __builtin_amdgcn_mfma_f32_16x16x32_bf16(a0, wv[(nt * 2 + 0) * 64 + lane], cv, 0, 0, 0);
            cv = __builtin_amdgcn_mfma_f32_16x16x32_bf16(a1, wv[(nt * 2 + 1) * 64 + lane], cv, 0, 0, 0);
            av[nt] = cv;
        }
        const int r0 = row0 + g * 4;
        #pragma unroll
        for (int r = 0; r < 4; ++r) {
            #pragma unroll
            for (int nt = 0; nt < 4; ++nt) {
                Qp[(size_t)(r0 + r) * D + nt * 16 + c0] = f2bu(aq[nt][r]);
                KV8[(size_t)(r0 + r) * 128 + nt * 16 + c0]      = f2fp8(ak[nt][r]);
                KV8[(size_t)(r0 + r) * 128 + 64 + nt * 16 + c0] = f2fp8(av[nt][r]);
            }
        }
    }
}

// ---------------- attention core: interleaved fp8 KV gathers + per-head softmax + PV ----------------
__global__ __launch_bounds__(256) void k_attn_lite(
    const unsigned short* __restrict__ Qp,
    const unsigned char* __restrict__ KV8,
    const int* __restrict__ samp, unsigned short* __restrict__ ob)
{
    const int lane = threadIdx.x & 63;
    const int g = lane >> 4, c0 = lane & 15;
    int w = (blockIdx.x * 256 + threadIdx.x) >> 6;
    const int nw = (gridDim.x * 256) >> 6;
    for (int row = w; row < NN; row += nw) {
        int idx_reg = (lane < KS) ? samp[row * KS + lane] : 0;
        const ushort4 qv = *(const ushort4*)(Qp + (size_t)row * D + c0 * 4);
        float q0 = b2f(qv.x), q1 = b2f(qv.y), q2 = b2f(qv.z), q3 = b2f(qv.w);

        float s[5];
        int v4[5];
        #pragma unroll
        for (int t = 0; t < 5; ++t) {
            int idx = __shfl(idx_reg, g * 5 + t, 64);
            const unsigned char* base = KV8 + (size_t)idx * 128 + c0 * 4;
            const int ku = *(const int*)(base);
            v4[t] = *(const int*)(base + 64);
            float sc = q0 * __builtin_amdgcn_cvt_f32_fp8(ku, 0);
            sc = fmaf(q1, __builtin_amdgcn_cvt_f32_fp8(ku, 1), sc);
            sc = fmaf(q2, __builtin_amdgcn_cvt_f32_fp8(ku, 2), sc);
            sc = fmaf(q3, __builtin_amdgcn_cvt_f32_fp8(ku, 3), sc);
            sc += __shfl_xor(sc, 1, 64);
            sc += __shfl_xor(sc, 2, 64);
            s[t] = sc * 0.25f;   // 1/sqrt(DH=16)
        }
        float m = fmaxf(fmaxf(fmaxf(s[0], s[1]), fmaxf(s[2], s[3])), s[4]);
        m = fmaxf(m, __shfl_xor(m, 16, 64));
        m = fmaxf(m, __shfl_xor(m, 32, 64));
        float o0 = 0.f, o1 = 0.f, o2 = 0.f, o3 = 0.f, ssum = 0.f;
        #pragma unroll
        for (int t = 0; t < 5; ++t) {
            float p = __expf(s[t] - m);
            ssum += p;
            o0 = fmaf(p, __builtin_amdgcn_cvt_f32_fp8(v4[t], 0), o0);
            o1 = fmaf(p, __builtin_amdgcn_cvt_f32_fp8(v4[t], 1), o1);
            o2 = fmaf(p, __builtin_amdgcn_cvt_f32_fp8(v4[t], 2), o2);
            o3 = fmaf(p, __builtin_amdgcn_cvt_f32_fp8(v4[t], 3), o3);
        }
        ssum += __shfl_xor(ssum, 16, 64);
        ssum += __shfl_xor(ssum, 32, 64);
        float inv = 1.0f / ssum;
        o0 += __shfl_xor(o0, 16, 64); o0 += __shfl_xor(o0, 32, 64);
        o1 += __shfl_xor(o1, 16, 64); o1 += __shfl_xor(o1, 32, 64);
        o2 += __shfl_xor(o2, 16, 64); o2 += __shfl_xor(o2, 32, 64);
        o3 += __shfl_xor(o3, 16, 64); o3 += __shfl_xor(o3, 32, 64);
        if (g == 0) {
            ushort4 o;
            o.x = f2bu(o0 * inv); o.y = f2bu(o1 * inv);
            o.z = f2bu(o2 * inv); o.w = f2bu(o3 * inv);
            *(ushort4*)(ob + (size_t)row * D + c0 * 4) = o;
        }
    }
}

// ---------------- Wo projection + residual + LN1 via MFMA -> hb fp32 ----------------
__global__ __launch_bounds__(256) void k_attno_mfma(
    const unsigned short* __restrict__ ob, const float* __restrict__ x,
    const short* __restrict__ S,
    const float* __restrict__ bo, const float* __restrict__ g1,
    const float* __restrict__ be1,
    float* __restrict__ hb)
{
    const int lane = threadIdx.x & 63;
    const int c0 = lane & 15;
    const int g  = lane >> 4;
    const bf16x8* wp = (const bf16x8*)(S + OFF_WO);

    float bov[4], g1v[4], b1v[4];
    #pragma unroll
    for (int nt = 0; nt < 4; ++nt) {
        bov[nt] = bo[nt * 16 + c0];
        g1v[nt] = g1[nt * 16 + c0];
        b1v[nt] = be1[nt * 16 + c0];
    }

    int wid = (blockIdx.x * 256 + threadIdx.x) >> 6;
    const int nwaves = (gridDim.x * 256) >> 6;
    for (int tile = wid; tile < NN / 16; tile += nwaves) {
        const int row0 = tile * 16;
        bf16x8 a[2];
        #pragma unroll
        for (int kt = 0; kt < 2; ++kt)
            a[kt] = *(const bf16x8*)&ob[(size_t)(row0 + c0) * D + kt * 32 + g * 8];
        f32x4 acc[4];
        #pragma unroll
        for (int nt = 0; nt < 4; ++nt) {
            f32x4 c = {bov[nt], bov[nt], bov[nt], bov[nt]};
            #pragma unroll
            for (int kt = 0; kt < 2; ++kt)
                c = __builtin_amdgcn_mfma_f32_16x16x32_bf16(a[kt], wp[(nt * 2 + kt) * 64 + lane], c, 0, 0, 0);
            acc[nt] = c;
        }
        const int r0 = row0 + g * 4;
        #pragma unroll
        for (int r = 0; r < 4; ++r) {
            float rv[4];
            float s = 0.f;
            #pragma unroll
            for (int nt = 0; nt < 4; ++nt) {
                rv[nt] = acc[nt][r] + x[(size_t)(r0 + r) * D + nt * 16 + c0];
                s += rv[nt];
            }
            s = gsum16(s);
            float mu = s * (1.f / 64.f);
            float q = 0.f;
            #pragma unroll
            for (int nt = 0; nt < 4; ++nt) { float d = rv[nt] - mu; q += d * d; }
            q = gsum16(q);
            float inv = rsqrtf(q * (1.f / 64.f) + EPS);
            #pragma unroll
            for (int nt = 0; nt < 4; ++nt)
                hb[(size_t)(r0 + r) * D + nt * 16 + c0] = (rv[nt] - mu) * inv * g1v[nt] + b1v[nt];
        }
    }
}

// ---------------- FFN via MFMA -> bf16 h2 + fp8 copy ----------------
__global__ __launch_bounds__(256) void k_ffn_mfma(
    const float* __restrict__ hb,
    const short* __restrict__ wf,
    const float* __restrict__ bf1, const float* __restrict__ bf2,
    const float* __restrict__ g2, const float* __restrict__ be2,
    unsigned short* __restrict__ h2b, unsigned char* __restrict__ h2f8)
{
    __shared__ __align__(16) short Tl[4][16][264];
    const int lane = threadIdx.x & 63;
    const int wv   = threadIdx.x >> 6;
    const int c0   = lane & 15;
    const int g    = lane >> 4;
    const bf16x8* w1p = (const bf16x8*)(wf + OFF_W1);
    const bf16x8* w2p = (const bf16x8*)(wf + OFF_W2);

    float b1v[16];
    #pragma unroll
    for (int nt = 0; nt < 16; ++nt) b1v[nt] = bf1[nt * 16 + c0];
    float b2v[4], g2v[4], bev[4];
    #pragma unroll
    for (int nt = 0; nt < 4; ++nt) {
        b2v[nt] = bf2[nt * 16 + c0];
        g2v[nt] = g2[nt * 16 + c0];
        bev[nt] = be2[nt * 16 + c0];
    }

    int wid = (blockIdx.x * 256 + threadIdx.x) >> 6;
    const int nwaves = (gridDim.x * 256) >> 6;
    for (int tile = wid; tile < NN / 16; tile += nwaves) {
        const int row0 = tile * 16;
        const float* ar = hb + (size_t)(row0 + c0) * D + g * 8;
        bf16x8 a0, a1;
        {
            float4 f0 = *(const float4*)(ar);
            float4 f1 = *(const float4*)(ar + 4);
            float4 f2 = *(const float4*)(ar + 32);
            float4 f3 = *(const float4*)(ar + 36);
            a0[0] = f2b(f0.x); a0[1] = f2b(f0.y); a0[2] = f2b(f0.z); a0[3] = f2b(f0.w);
            a0[4] = f2b(f1.x); a0[5] = f2b(f1.y); a0[6] = f2b(f1.z); a0[7] = f2b(f1.w);
            a1[0] = f2b(f2.x); a1[1] = f2b(f2.y); a1[2] = f2b(f2.z); a1[3] = f2b(f2.w);
            a1[4] = f2b(f3.x); a1[5] = f2b(f3.y); a1[6] = f2b(f3.z); a1[7] = f2b(f3.w);
        }
        f32x4 acc1[16];
        #pragma unroll
        for (int nt = 0; nt < 16; ++nt) {
            float b = b1v[nt];
            f32x4 c = {b, b, b, b};
            c = __builtin_amdgcn_mfma_f32_16x16x32_bf16(a0, w1p[(nt * 2 + 0) * 64 + lane], c, 0, 0, 0);
            c = __builtin_amdgcn_mfma_f32_16x16x32_bf16(a1, w1p[(nt * 2 + 1) * 64 + lane], c, 0, 0, 0);
            acc1[nt] = c;
        }
        #pragma unroll
        for (int nt = 0; nt < 16; ++nt) {
            #pragma unroll
            for (int r = 0; r < 4; ++r)
                Tl[wv][g * 4 + r][nt * 16 + c0] = f2b(fmaxf(acc1[nt][r], 0.f));
        }
        bf16x8 a2[8];
        #pragma unroll
        for (int kt = 0; kt < 8; ++kt)
            a2[kt] = *(const bf16x8*)&Tl[wv][c0][kt * 32 + g * 8];
        f32x4 acc2[4];
        #pragma unroll
        for (int nt = 0; nt < 4; ++nt) {
            float b = b2v[nt];
            f32x4 c = {b, b, b, b};
            #pragma unroll
            for (int kt = 0; kt < 8; ++kt)
                c = __builtin_amdgcn_mfma_f32_16x16x32_bf16(a2[kt], w2p[(nt * 8 + kt) * 64 + lane], c, 0, 0, 0);
            acc2[nt] = c;
        }
        const int r0 = row0 + g * 4;
        #pragma unroll
        for (int r = 0; r < 4; ++r) {
            float rv[4];
            float s = 0.f;
            #pragma unroll
            for (int nt = 0; nt < 4; ++nt) {
                rv[nt] = acc2[nt][r] + hb[(size_t)(r0 + r) * D + nt * 16 + c0];
                s += rv[nt];
            }
            s = gsum16(s);
            float mu = s * (1.f / 64.f);
            float q = 0.f;
            #pragma unroll
            for (int nt = 0; nt < 4; ++nt) { float d = rv[nt] - mu; q += d * d; }
            q = gsum16(q);
            float inv = rsqrtf(q * (1.f / 64.f) + EPS);
            #pragma unroll
            for (int nt = 0; nt < 4; ++nt) {
                float hv = (rv[nt] - mu) * inv * g2v[nt] + bev[nt];
                h2b[(size_t)(r0 + r) * D + nt * 16 + c0] = f2bu(hv);
                h2f8[(size_t)(r0 + r) * D + nt * 16 + c0] = f2fp8(hv);
            }
        }
    }
}

// ---------------- GNN linear (MFMA, bf16 inputs) + relu + residual + LN -> fp32 out ----------------
__global__ __launch_bounds__(256) void k_gnn_mfma(
    const unsigned short* __restrict__ h2b, const unsigned short* __restrict__ hnb,
    const short* __restrict__ S,
    const float* __restrict__ bg, const float* __restrict__ gg,
    const float* __restrict__ bgn,
    float* __restrict__ out)
{
    const int lane = threadIdx.x & 63;
    const int c0 = lane & 15;
    const int g  = lane >> 4;
    const bf16x8* wp = (const bf16x8*)(S + OFF_WG);

    float bgv[4], ggv[4], bnv[4];
    #pragma unroll
    for (int nt = 0; nt < 4; ++nt) {
        bgv[nt] = bg[nt * 16 + c0];
        ggv[nt] = gg[nt * 16 + c0];
        bnv[nt] = bgn[nt * 16 + c0];
    }

    int wid = (blockIdx.x * 256 + threadIdx.x) >> 6;
    const int nwaves = (gridDim.x * 256) >> 6;
    for (int tile = wid; tile < NN / 16; tile += nwaves) {
        const int row0 = tile * 16;
        bf16x8 a[4];
        #pragma unroll
        for (int kt = 0; kt < 2; ++kt) {
            a[kt]     = *(const bf16x8*)&h2b[(size_t)(row0 + c0) * 64 + kt * 32 + g * 8];
            a[2 + kt] = *(const bf16x8*)&hnb[(size_t)(row0 + c0) * 64 + kt * 32 + g * 8];
        }
        f32x4 acc[4];
        #pragma unroll
        for (int nt = 0; nt < 4; ++nt) {
            float b = bgv[nt];
            f32x4 c = {b, b, b, b};
            #pragma unroll
            for (int kt = 0; kt < 4; ++kt)
                c = __builtin_amdgcn_mfma_f32_16x16x32_bf16(a[kt], wp[(nt * 4 + kt) * 64 + lane], c, 0, 0, 0);
            acc[nt] = c;
        }
        const int r0 = row0 + g * 4;
        #pragma unroll
        for (int r = 0; r < 4; ++r) {
            float rv[4];
            float s = 0.f;
            #pragma unroll
            for (int nt = 0; nt < 4; ++nt) {
                float hn = fmaxf(acc[nt][r], 0.f);
                rv[nt] = hn + b2f(h2b[(size_t)(r0 + r) * 64 + nt * 16 + c0]);
                s += rv[nt];
            }
            s = gsum16(s);
            float mu = s * (1.f / 64.f);
            float q = 0.f;
            #pragma unroll
            for (int nt = 0; nt < 4; ++nt) { float d = rv[nt] - mu; q += d * d; }
            q = gsum16(q);
            float inv = rsqrtf(q * (1.f / 64.f) + EPS);
            #pragma unroll
            for (int nt = 0; nt < 4; ++nt)
                out[(size_t)(r0 + r) * D + nt * 16 + c0] = (rv[nt] - mu) * inv * ggv[nt] + bnv[nt];
        }
    }
}

// ---------------- attention_samples passthrough (as fp32) ----------------
__global__ __launch_bounds__(256) void k_samples(
    const int* __restrict__ samp, float* __restrict__ out, int n)
{
    int i = blockIdx.x * blockDim.x + threadIdx.x;
    const int stride = gridDim.x * blockDim.x;
    for (; i < n; i += stride) out[i] = (float)samp[i];
}

extern "C" void kernel_launch(void* const* d_in, const int* in_sizes, int n_in,
                              void* d_out, int out_size, void* d_ws, size_t ws_size,
                              hipStream_t stream)
{
    const float* x   = (const float*)d_in[0];
    const int*   rows = (const int*)d_in[1];
    const int*   cols = (const int*)d_in[2];
    const float* ev  = (const float*)d_in[3];
    const int*   samp = (const int*)d_in[4];
    const float* Wq  = (const float*)d_in[5];
    const float* bq  = (const float*)d_in[6];
    const float* Wk  = (const float*)d_in[7];
    const float* bk  = (const float*)d_in[8];
    const float* Wv  = (const float*)d_in[9];
    const float* bv  = (const float*)d_in[10];
    const float* Wo  = (const float*)d_in[11];
    const float* bo  = (const float*)d_in[12];
    const float* g1  = (const float*)d_in[13];
    const float* be1 = (const float*)d_in[14];
    const float* g2  = (const float*)d_in[15];
    const float* be2 = (const float*)d_in[16];
    const float* W1  = (const float*)d_in[17];
    const float* bf1 = (const float*)d_in[18];
    const float* W2  = (const float*)d_in[19];
    const float* bf2 = (const float*)d_in[20];
    const float* Wg  = (const float*)d_in[21];
    const float* bg  = (const float*)d_in[22];
    const float* gg  = (const float*)d_in[23];
    const float* bgn = (const float*)d_in[24];
    const int E = in_sizes[1];
    const int npb = (E + PCHUNK - 1) / PCHUNK;

    // ws layout: 3 buffers of NN*D floats (76.8 MB)
    float* buf0 = (float*)d_ws;                   // KV8 (NN*128B) -> payload (uint[E])
    float* buf1 = buf0 + (size_t)NN * D;          // [Qp_b -> hnb_b | ob -> h2b] bf16
    float* buf2 = buf1 + (size_t)NN * D;          // hb fp32 -> part (int2[E])
    unsigned char* KV8 = (unsigned char*)buf0;                         // NN*128 bytes
    unsigned int* payload = (unsigned int*)buf0;       // overwrites KV8 after attn
    unsigned short* Qp_b  = (unsigned short*)buf1;     // dead after attn -> hnb slot
    unsigned short* hnb_b = (unsigned short*)buf1;
    unsigned short* ob    = (unsigned short*)(buf1 + (size_t)NN * D / 2); // dead after attno -> h2b slot
    unsigned short* h2b   = ob;
    float* hb = buf2;
    int2* part = (int2*)buf2;                          // overwrites hb after ffn

    float* out = (float*)d_out;
    // scratch in samples region of d_out (rewritten by k_samples each call; 8 MB available)
    short* S     = (short*)(out + (size_t)NN * D);   // S_TOTAL shorts
    int* offsets = (int*)(S + S_TOTAL);              // NN+1
    int* bbase   = offsets + NN + 1;                 // NB+1
    int* btot    = bbase + NB + 1;                   // NB
    int* partial = btot + NB;                        // npb*NB
    unsigned char* h2f8 = (unsigned char*)(partial + (size_t)npb * NB); // NN*64 bytes (6.4MB)

    k_prep<<<56, 256, 0, stream>>>(W1, W2, Wg, Wq, Wk, Wv, Wo, S);
    k_bhist<<<npb, 256, 0, stream>>>(rows, partial, E);
    k_pscan_a<<<NB, 256, 0, stream>>>(partial, btot, npb);
    k_pscan_b<<<1, 256, 0, stream>>>(btot, bbase, offsets);
    k_projqkv_mfma<<<1563, 256, 0, stream>>>(x, S, bq, bk, bv, Qp_b, KV8);
    k_attn_lite<<<4096, 256, 0, stream>>>(Qp_b, KV8, samp, ob);
    k_attno_mfma<<<1563, 256, 0, stream>>>(ob, x, S, bo, g1, be1, hb);
    k_ffn_mfma<<<1563, 256, 0, stream>>>(hb, S, bf1, bf2, g2, be2, h2b, h2f8);
    k_part<<<npb, 256, 0, stream>>>(rows, cols, ev, partial, bbase, part, E);
    k_fill2<<<NB, 256, 0, stream>>>(bbase, part, offsets, payload);
    k_gather<<<4096, 256, 0, stream>>>(offsets, payload, h2f8, hnb_b);
    k_gnn_mfma<<<1563, 256, 0, stream>>>(h2b, hnb_b, S, bg, gg, bgn, out);
    k_samples<<<2048, 256, 0, stream>>>(samp, out + (size_t)NN * D, NN * KS);
}